// Round 23
// baseline (656.287 us; speedup 1.0000x reference)
//
#include <hip/hip_runtime.h>
#include <hip/hip_bf16.h>
#include <cstdint>

#define B_ 2
#define S_ 2048
#define D_ 1024
#define H_ 16
#define HKV_ 4
#define HD_ 64
#define E_ 8
#define HIDDEN_ 684
#define NT_ (B_*S_)
#define NEGBIG (-1e30f)

using bf16 = __hip_bfloat16;
typedef __attribute__((ext_vector_type(8))) short short8v;
typedef __attribute__((ext_vector_type(4))) short short4v;
typedef __attribute__((ext_vector_type(4))) float f32x4;

static __device__ __forceinline__ float b2f(bf16 v){ return __bfloat162float(v); }
static __device__ __forceinline__ bf16 f2b(float v){ return __float2bfloat16(v); }
static __device__ __forceinline__ short f2bs(float v){ bf16 h = f2b(v); return *reinterpret_cast<short*>(&h); }
static __device__ __forceinline__ float dload(const void* p, size_t i, int isbf){
  return isbf ? b2f(((const bf16*)p)[i]) : ((const float*)p)[i];
}

__global__ void k_detect(const uint32_t* __restrict__ g, int* __restrict__ flag, int* __restrict__ cnt){
  if(threadIdx.x == 0 && blockIdx.x == 0){
    uint32_t w0 = g[0], w1 = g[1], w2 = g[2], w3 = g[3];
    int bf;
    if(w0==0x3F803F80u && w1==0x3F803F80u && w2==0x3F803F80u && w3==0x3F803F80u) bf = 1;
    else if(w0==0x3F800000u && w1==0x3F800000u && w2==0x3F800000u && w3==0x3F800000u) bf = 0;
    else bf = 1;
    flag[0] = bf;
  }
  if(threadIdx.x < E_ && blockIdx.x == 0) cnt[threadIdx.x] = 0;
}

// ---------------- RMSNorm -> bf16 out (+ optional f32 copy for router) ----------------
__global__ __launch_bounds__(256) void k_rms(const void* __restrict__ X, const void* __restrict__ g,
                                             bf16* __restrict__ outb, float* __restrict__ outf,
                                             const int* __restrict__ flag, int xdyn){
  int isbf = flag[0]; int xb = xdyn ? isbf : 0;
  int t = blockIdx.x; int tid = threadIdx.x;
  float v[4]; float ss = 0.f;
  #pragma unroll
  for(int i=0;i<4;i++){ v[i] = dload(X, (size_t)t*D_ + tid + i*256, xb); ss += v[i]*v[i]; }
  __shared__ float red[256];
  red[tid] = ss; __syncthreads();
  for(int st=128; st>0; st>>=1){ if(tid<st) red[tid] += red[tid+st]; __syncthreads(); }
  float r = rsqrtf(red[0]*(1.f/(float)D_) + 1e-5f);
  #pragma unroll
  for(int i=0;i<4;i++){
    int d = tid + i*256;
    float val = v[i]*r*dload(g, d, isbf);
    outb[(size_t)t*D_ + d] = f2b(val);
    if(outf) outf[(size_t)t*D_ + d] = val;
  }
}

// ============ GEMM scaffolding (BM=128 BN=64 BK=32, proven) ============
#define ASTRIDE 40

static __device__ __forceinline__ f32x4 mfma16(short8v a, short8v b, f32x4 c){
  return __builtin_amdgcn_mfma_f32_16x16x32_bf16(a, b, c, 0, 0, 0);
}

// ---------------- generic GEMM (used for wo) ----------------
template<int AMAP, int OMODE>
__global__ __launch_bounds__(256) void k_mgemm(
    const bf16* __restrict__ A, const void* __restrict__ Bw, void* __restrict__ Cout,
    const void* __restrict__ resid,
    int M, int N, int K, int ldc,
    const int* __restrict__ cnt, const int* __restrict__ offs, const int* __restrict__ list,
    const int* __restrict__ flag)
{
  int isbf = flag[0];
  int e, ct, rt;
  int base = 0; size_t eoff = 0;
  if(cnt){
    e = blockIdx.x;
    int nc = (N+63)>>6;
    ct = blockIdx.y % nc; rt = blockIdx.y / nc;
    M = cnt[e]; if(M<0) M=0; if(M>NT_) M=NT_;
    base = offs[e];
    eoff = (size_t)e*(size_t)K*(size_t)N;
  } else {
    e = 0; ct = blockIdx.x; rt = blockIdx.y;
  }
  int m0 = rt*128; if(m0 >= M) return;
  int n0 = ct*64;

  __shared__ short As[2][128*ASTRIDE];
  __shared__ short Bs[2][64*ASTRIDE];
  __shared__ int rowA[128];

  int tid = threadIdx.x;
  int w = tid>>6, l = tid&63, lr = l&15, lg = l>>4;

  if(tid < 128){
    int rloc = m0 + tid;
    int ar = -1;
    if(rloc < M) ar = (AMAP==2) ? (list[e*NT_ + rloc]>>1) : (base + rloc);
    rowA[tid] = ar;
  }
  __syncthreads();

  int srow = tid>>1, skh = (tid&1)*16;
  int keya = (srow>>4)&3, kb0 = skh>>3;
  int bk = tid>>3, bnc = (tid&7)*8;
  int keyb = ((tid&7)>>1)&3;
  int bcol = (((bk>>3)^keyb)<<3) + (bk&7);
  int arow = rowA[srow];

  short8v rA0, rA1, rB;

  auto loadAB = [&](int kt){
    int k0 = kt*32;
    {
      short tmp[16];
      if(arow >= 0 && k0+skh+16 <= K){
        const short4v* src = (const short4v*)(A + (size_t)arow*K + k0 + skh);
        #pragma unroll
        for(int c=0;c<4;c++) *(short4v*)&tmp[c*4] = src[c];
      } else {
        #pragma unroll
        for(int i=0;i<16;i++){
          int gk = k0+skh+i;
          short v = 0;
          if(arow>=0 && gk<K) v = *(const short*)&A[(size_t)arow*K+gk];
          tmp[i] = v;
        }
      }
      #pragma unroll
      for(int i=0;i<8;i++){ rA0[i]=tmp[i]; rA1[i]=tmp[8+i]; }
    }
    {
      int gk = k0 + bk;
      short tmp[8];
      if(gk < K && n0+bnc+8 <= N){
        size_t bb = eoff + (size_t)gk*N + n0 + bnc;
        if(isbf){
          const short4v* src = (const short4v*)((const bf16*)Bw + bb);
          *(short4v*)&tmp[0] = src[0];
          *(short4v*)&tmp[4] = src[1];
        } else {
          const f32x4* src = (const f32x4*)((const float*)Bw + bb);
          f32x4 f0 = src[0], f1 = src[1];
          #pragma unroll
          for(int i=0;i<4;i++){ tmp[i]=f2bs(f0[i]); tmp[4+i]=f2bs(f1[i]); }
        }
      } else {
        #pragma unroll
        for(int i=0;i<8;i++){
          int gn = n0+bnc+i;
          float v = 0.f;
          if(gk<K && gn<N) v = dload(Bw, eoff + (size_t)gk*N + gn, isbf);
          tmp[i] = f2bs(v);
        }
      }
      #pragma unroll
      for(int i=0;i<8;i++) rB[i]=tmp[i];
    }
  };
  auto writeAB = [&](int buf){
    *(short8v*)&As[buf][srow*ASTRIDE + ((kb0^keya)<<3)]     = rA0;
    *(short8v*)&As[buf][srow*ASTRIDE + (((kb0+1)^keya)<<3)] = rA1;
    #pragma unroll
    for(int i=0;i<8;i++) Bs[buf][(bnc+i)*ASTRIDE + bcol] = rB[i];
  };

  f32x4 acc[2][4] = {};
  int KT = (K+31)>>5;

  loadAB(0); writeAB(0);
  __syncthreads();
  int cur = 0;
  for(int kt=0; kt<KT; ++kt){
    bool more = (kt+1 < KT);
    if(more) loadAB(kt+1);
    short8v a[2], b[4];
    #pragma unroll
    for(int fi=0;fi<2;fi++)
      a[fi] = *(const short8v*)&As[cur][(w*32+fi*16+lr)*ASTRIDE + ((lg^((w*2+fi)&3))<<3)];
    #pragma unroll
    for(int fj=0;fj<4;fj++)
      b[fj] = *(const short8v*)&Bs[cur][(fj*16+lr)*ASTRIDE + ((lg^fj)<<3)];
    #pragma unroll
    for(int fi=0;fi<2;fi++)
      #pragma unroll
      for(int fj=0;fj<4;fj++)
        acc[fi][fj] = mfma16(a[fi], b[fj], acc[fi][fj]);
    if(more){ writeAB(cur^1); cur ^= 1; }
    __syncthreads();
  }

  #pragma unroll
  for(int fi=0;fi<2;fi++){
    #pragma unroll
    for(int r=0;r<4;r++){
      int rl = m0 + w*32 + fi*16 + lg*4 + r;
      if(rl >= M) continue;
      int orow;
      if(OMODE==2){ orow = list[e*NT_ + rl]; if(orow<0||orow>=2*NT_) continue; }
      else orow = base + rl;
      #pragma unroll
      for(int fj=0;fj<4;fj++){
        int gcol = n0 + fj*16 + lr;
        if(gcol >= N) continue;
        float v = acc[fi][fj][r];
        size_t o = (size_t)orow*ldc + gcol;
        if(OMODE==1)      ((float*)Cout)[o] = v + dload(resid, o, isbf);
        else if(OMODE==2) ((bf16*)Cout)[o] = f2b(v);
        else if(OMODE==3) ((float*)Cout)[o] = ((float*)Cout)[o] + v;
        else              ((bf16*)Cout)[o] = f2b(v);
      }
    }
  }
}

// ---------------- merged QKV GEMM with fused RoPE epilogue ----------------
// Epilogue lane layout: col = n0+fj*16+lr, parity(col)=parity(lane); lanes l,l^1 hold
// the (even,odd) column pair of the SAME row -> rotate via __shfl_xor(v,1).
__global__ __launch_bounds__(256) void k_qkv(
    const bf16* __restrict__ A, const void* __restrict__ Wq, const void* __restrict__ Wk,
    const void* __restrict__ Wv, bf16* __restrict__ Oq, bf16* __restrict__ Ok, bf16* __restrict__ Ov,
    const void* __restrict__ fc, const void* __restrict__ fs,
    const int* __restrict__ flag)
{
  int isbf = flag[0];
  int ct = blockIdx.x, rt = blockIdx.y;
  const void* Bw; bf16* Cout; int N, n0;
  if(ct < 16){ Bw = Wq; Cout = Oq; N = D_;  n0 = ct*64; }
  else if(ct < 20){ Bw = Wk; Cout = Ok; N = 256; n0 = (ct-16)*64; }
  else { Bw = Wv; Cout = Ov; N = 256; n0 = (ct-20)*64; }
  const int K = D_, M = NT_;
  int m0 = rt*128;
  int dorope = (ct < 20);

  __shared__ short As[2][128*ASTRIDE];
  __shared__ short Bs[2][64*ASTRIDE];

  int tid = threadIdx.x;
  int w = tid>>6, l = tid&63, lr = l&15, lg = l>>4;

  int srow = tid>>1, skh = (tid&1)*16;
  int keya = (srow>>4)&3, kb0 = skh>>3;
  int bk = tid>>3, bnc = (tid&7)*8;
  int keyb = ((tid&7)>>1)&3;
  int bcol = (((bk>>3)^keyb)<<3) + (bk&7);
  int arow = m0 + srow;

  short8v rA0, rA1, rB;

  auto loadAB = [&](int kt){
    int k0 = kt*32;
    {
      short tmp[16];
      const short4v* src = (const short4v*)(A + (size_t)arow*K + k0 + skh);
      #pragma unroll
      for(int c=0;c<4;c++) *(short4v*)&tmp[c*4] = src[c];
      #pragma unroll
      for(int i=0;i<8;i++){ rA0[i]=tmp[i]; rA1[i]=tmp[8+i]; }
    }
    {
      int gk = k0 + bk;
      short tmp[8];
      size_t bb = (size_t)gk*N + n0 + bnc;
      if(isbf){
        const short4v* src = (const short4v*)((const bf16*)Bw + bb);
        *(short4v*)&tmp[0] = src[0];
        *(short4v*)&tmp[4] = src[1];
      } else {
        const f32x4* src = (const f32x4*)((const float*)Bw + bb);
        f32x4 f0 = src[0], f1 = src[1];
        #pragma unroll
        for(int i=0;i<4;i++){ tmp[i]=f2bs(f0[i]); tmp[4+i]=f2bs(f1[i]); }
      }
      #pragma unroll
      for(int i=0;i<8;i++) rB[i]=tmp[i];
    }
  };
  auto writeAB = [&](int buf){
    *(short8v*)&As[buf][srow*ASTRIDE + ((kb0^keya)<<3)]     = rA0;
    *(short8v*)&As[buf][srow*ASTRIDE + (((kb0+1)^keya)<<3)] = rA1;
    #pragma unroll
    for(int i=0;i<8;i++) Bs[buf][(bnc+i)*ASTRIDE + bcol] = rB[i];
  };

  f32x4 acc[2][4] = {};
  int KT = K>>5;

  loadAB(0); writeAB(0);
  __syncthreads();
  int cur = 0;
  for(int kt=0; kt<KT; ++kt){
    bool more = (kt+1 < KT);
    if(more) loadAB(kt+1);
    short8v a[2], b[4];
    #pragma unroll
    for(int fi=0;fi<2;fi++)
      a[fi] = *(const short8v*)&As[cur][(w*32+fi*16+lr)*ASTRIDE + ((lg^((w*2+fi)&3))<<3)];
    #pragma unroll
    for(int fj=0;fj<4;fj++)
      b[fj] = *(const short8v*)&Bs[cur][(fj*16+lr)*ASTRIDE + ((lg^fj)<<3)];
    #pragma unroll
    for(int fi=0;fi<2;fi++)
      #pragma unroll
      for(int fj=0;fj<4;fj++)
        acc[fi][fj] = mfma16(a[fi], b[fj], acc[fi][fj]);
    if(more){ writeAB(cur^1); cur ^= 1; }
    __syncthreads();
  }

  // epilogue (+ fused RoPE). No guards fire (exact tiling) -> all 64 lanes active at shfl.
  #pragma unroll
  for(int fi=0;fi<2;fi++){
    #pragma unroll
    for(int r=0;r<4;r++){
      int rl = m0 + w*32 + fi*16 + lg*4 + r;
      int s = rl & (S_-1);
      #pragma unroll
      for(int fj=0;fj<4;fj++){
        int gcol = n0 + fj*16 + lr;
        float v = acc[fi][fj][r];
        if(dorope){
          float partner = __shfl_xor(v, 1, 64);
          int p = (gcol & 63) >> 1;
          float c = dload(fc, s*32 + p, isbf);
          float sn = dload(fs, s*32 + p, isbf);
          if((l & 1) == 0) v = v*c - partner*sn;
          else             v = partner*sn + v*c;
        }
        Cout[(size_t)rl*N + gcol] = f2b(v);
      }
    }
  }
}

// ---------------- merged FFN1 (ct-inner, fused silu) ----------------
__global__ __launch_bounds__(256) void k_ffn1m(
    const bf16* __restrict__ A, const void* __restrict__ W1e, const void* __restrict__ W3e,
    const void* __restrict__ W1s, const void* __restrict__ W3s,
    bf16* __restrict__ OutE, bf16* __restrict__ OutS,
    const int* __restrict__ cnt, const int* __restrict__ offs, const int* __restrict__ list,
    const int* __restrict__ flag)
{
  int isbf = flag[0];
  const int K = D_, N = HIDDEN_;
  int e = blockIdx.x, y = blockIdx.y;
  int ct, rt, M, base, gat;
  const void* W1; const void* W3; bf16* Out;
  size_t eoff;
  if(y < 352){
    ct = y % 11; rt = y / 11;
    M = cnt[e]; if(M<0) M=0; if(M>NT_) M=NT_;
    base = offs[e]; gat = 1;
    W1 = W1e; W3 = W3e; Out = OutE;
    eoff = (size_t)e*(size_t)K*(size_t)N;
  } else {
    int ys = (y-352)*8 + e;
    ct = ys % 11; rt = ys / 11;
    M = NT_; base = 0; gat = 0;
    W1 = W1s; W3 = W3s; Out = OutS;
    eoff = 0;
  }
  int m0 = rt*128; if(m0 >= M) return;
  int n0 = ct*64;

  __shared__ short As[2][128*ASTRIDE];
  __shared__ short B1s[2][64*ASTRIDE];
  __shared__ short B3s[2][64*ASTRIDE];
  __shared__ int rowA[128];

  int tid = threadIdx.x;
  int w = tid>>6, l = tid&63, lr = l&15, lg = l>>4;

  if(tid < 128){
    int rloc = m0 + tid;
    int ar = -1;
    if(rloc < M) ar = gat ? (list[e*NT_ + rloc]>>1) : rloc;
    rowA[tid] = ar;
  }
  __syncthreads();

  int srow = tid>>1, skh = (tid&1)*16;
  int keya = (srow>>4)&3, kb0 = skh>>3;
  int bk = tid>>3, bnc = (tid&7)*8;
  int keyb = ((tid&7)>>1)&3;
  int bcol = (((bk>>3)^keyb)<<3) + (bk&7);
  int arow = rowA[srow];

  short8v rA0, rA1, rB1, rB3;

  auto loadB = [&](const void* Bw, int kt, short8v& rB){
    int k0 = kt*32;
    int gk = k0 + bk;
    short tmp[8];
    if(gk < K && n0+bnc+8 <= N){
      size_t bb = eoff + (size_t)gk*N + n0 + bnc;
      if(isbf){
        const short4v* src = (const short4v*)((const bf16*)Bw + bb);
        *(short4v*)&tmp[0] = src[0];
        *(short4v*)&tmp[4] = src[1];
      } else {
        const f32x4* src = (const f32x4*)((const float*)Bw + bb);
        f32x4 f0 = src[0], f1 = src[1];
        #pragma unroll
        for(int i=0;i<4;i++){ tmp[i]=f2bs(f0[i]); tmp[4+i]=f2bs(f1[i]); }
      }
    } else {
      #pragma unroll
      for(int i=0;i<8;i++){
        int gn = n0+bnc+i;
        float v = 0.f;
        if(gk<K && gn<N) v = dload(Bw, eoff + (size_t)gk*N + gn, isbf);
        tmp[i] = f2bs(v);
      }
    }
    #pragma unroll
    for(int i=0;i<8;i++) rB[i]=tmp[i];
  };
  auto loadA = [&](int kt){
    int k0 = kt*32;
    short tmp[16];
    if(arow >= 0 && k0+skh+16 <= K){
      const short4v* src = (const short4v*)(A + (size_t)arow*K + k0 + skh);
      #pragma unroll
      for(int c=0;c<4;c++) *(short4v*)&tmp[c*4] = src[c];
    } else {
      #pragma unroll
      for(int i=0;i<16;i++){
        int gk = k0+skh+i;
        short v = 0;
        if(arow>=0 && gk<K) v = *(const short*)&A[(size_t)arow*K+gk];
        tmp[i] = v;
      }
    }
    #pragma unroll
    for(int i=0;i<8;i++){ rA0[i]=tmp[i]; rA1[i]=tmp[8+i]; }
  };
  auto writeAll = [&](int buf){
    *(short8v*)&As[buf][srow*ASTRIDE + ((kb0^keya)<<3)]     = rA0;
    *(short8v*)&As[buf][srow*ASTRIDE + (((kb0+1)^keya)<<3)] = rA1;
    #pragma unroll
    for(int i=0;i<8;i++){
      B1s[buf][(bnc+i)*ASTRIDE + bcol] = rB1[i];
      B3s[buf][(bnc+i)*ASTRIDE + bcol] = rB3[i];
    }
  };

  f32x4 a1[2][4] = {}, a3[2][4] = {};
  int KT = (K+31)>>5;

  loadA(0); loadB(W1, 0, rB1); loadB(W3, 0, rB3); writeAll(0);
  __syncthreads();
  int cur = 0;
  for(int kt=0; kt<KT; ++kt){
    bool more = (kt+1 < KT);
    if(more){ loadA(kt+1); loadB(W1, kt+1, rB1); loadB(W3, kt+1, rB3); }
    short8v a[2], b1[4], b3[4];
    #pragma unroll
    for(int fi=0;fi<2;fi++)
      a[fi] = *(const short8v*)&As[cur][(w*32+fi*16+lr)*ASTRIDE + ((lg^((w*2+fi)&3))<<3)];
    #pragma unroll
    for(int fj=0;fj<4;fj++){
      b1[fj] = *(const short8v*)&B1s[cur][(fj*16+lr)*ASTRIDE + ((lg^fj)<<3)];
      b3[fj] = *(const short8v*)&B3s[cur][(fj*16+lr)*ASTRIDE + ((lg^fj)<<3)];
    }
    #pragma unroll
    for(int fi=0;fi<2;fi++)
      #pragma unroll
      for(int fj=0;fj<4;fj++){
        a1[fi][fj] = mfma16(a[fi], b1[fj], a1[fi][fj]);
        a3[fi][fj] = mfma16(a[fi], b3[fj], a3[fi][fj]);
      }
    if(more){ writeAll(cur^1); cur ^= 1; }
    __syncthreads();
  }

  #pragma unroll
  for(int fi=0;fi<2;fi++){
    #pragma unroll
    for(int r=0;r<4;r++){
      int rl = m0 + w*32 + fi*16 + lg*4 + r;
      if(rl >= M) continue;
      int orow = base + rl;
      #pragma unroll
      for(int fj=0;fj<4;fj++){
        int gcol = n0 + fj*16 + lr;
        if(gcol >= N) continue;
        float sg = a1[fi][fj][r];
        float v = (sg/(1.f+__expf(-sg))) * a3[fi][fj][r];
        Out[(size_t)orow*N + gcol] = f2b(v);
      }
    }
  }
}

// ---------------- merged FFN2: BN=128, SINGLE buffer (20.5 KB LDS, 16 MFMA/wave/step) ----------------
__global__ __launch_bounds__(256) void k_ffn2m(
    const bf16* __restrict__ Ae, const bf16* __restrict__ Ash,
    const void* __restrict__ W2e, const void* __restrict__ W2s,
    bf16* __restrict__ OutE, float* __restrict__ OutS,
    const int* __restrict__ cnt, const int* __restrict__ offs, const int* __restrict__ list,
    const int* __restrict__ flag)
{
  int isbf = flag[0];
  const int K = HIDDEN_, N = D_;
  int e = blockIdx.x, y = blockIdx.y;
  int ct, rt, M, base, exm;
  const bf16* A; const void* Bw;
  size_t eoff;
  if(y < 256){            // expert: 8 ct x 32 rt (ct-inner like r13)
    ct = y % 8; rt = y / 8;
    M = cnt[e]; if(M<0) M=0; if(M>NT_) M=NT_;
    base = offs[e]; exm = 1;
    A = Ae; Bw = W2e;
    eoff = (size_t)e*(size_t)K*(size_t)N;
  } else {                // shared: 256 tiles over 8 x-lanes
    int ys = (y-256)*8 + e;
    ct = ys % 8; rt = ys / 8;
    M = NT_; base = 0; exm = 0;
    A = Ash; Bw = W2s;
    eoff = 0;
  }
  int m0 = rt*128; if(m0 >= M) return;
  int n0 = ct*128;

  __shared__ short As[128*ASTRIDE];
  __shared__ short Bs[128*ASTRIDE];   // [col][k], 128 cols

  int tid = threadIdx.x;
  int w = tid>>6, l = tid&63, lr = l&15, lg = l>>4;

  int srow = tid>>1, skh = (tid&1)*16;
  int keya = (srow>>4)&3, kb0 = skh>>3;
  int bk = tid>>3, bnc = (tid&7)*16;        // 16 cols per thread
  int keyb = (tid&7)&3;                     // = ((bnc+i)>>4)&3 for i<16
  int bcol = (((bk>>3)^keyb)<<3) + (bk&7);
  int arow = (m0 + srow < M) ? (base + m0 + srow) : -1;

  short8v rA0, rA1, rB0v, rB1v;

  auto loadAB = [&](int kt){
    int k0 = kt*32;
    { // A (bf16), 16 k-values
      short tmp[16];
      if(arow >= 0 && k0+skh+16 <= K){
        const short4v* src = (const short4v*)(A + (size_t)arow*K + k0 + skh);
        #pragma unroll
        for(int c=0;c<4;c++) *(short4v*)&tmp[c*4] = src[c];
      } else {
        #pragma unroll
        for(int i=0;i<16;i++){
          int gk = k0+skh+i;
          short v = 0;
          if(arow>=0 && gk<K) v = *(const short*)&A[(size_t)arow*K+gk];
          tmp[i] = v;
        }
      }
      #pragma unroll
      for(int i=0;i<8;i++){ rA0[i]=tmp[i]; rA1[i]=tmp[8+i]; }
    }
    { // B: 16 cols at one k  (n0+bnc+16 <= 1024 always; guard only gk)
      int gk = k0 + bk;
      short tmp[16];
      if(gk < K){
        size_t bb = eoff + (size_t)gk*N + n0 + bnc;
        if(isbf){
          const short4v* src = (const short4v*)((const bf16*)Bw + bb);
          #pragma unroll
          for(int c=0;c<4;c++) *(short4v*)&tmp[c*4] = src[c];
        } else {
          const f32x4* src = (const f32x4*)((const float*)Bw + bb);
          #pragma unroll
          for(int c=0;c<4;c++){
            f32x4 f = src[c];
            #pragma unroll
            for(int i=0;i<4;i++) tmp[c*4+i] = f2bs(f[i]);
          }
        }
      } else {
        #pragma unroll
        for(int i=0;i<16;i++) tmp[i] = 0;
      }
      #pragma unroll
      for(int i=0;i<8;i++){ rB0v[i]=tmp[i]; rB1v[i]=tmp[8+i]; }
    }
  };
  auto writeAB = [&](){
    *(short8v*)&As[srow*ASTRIDE + ((kb0^keya)<<3)]     = rA0;
    *(short8v*)&As[srow*ASTRIDE + (((kb0+1)^keya)<<3)] = rA1;
    #pragma unroll
    for(int i=0;i<8;i++) Bs[(bnc+i)*ASTRIDE + bcol]   = rB0v[i];
    #pragma unroll
    for(int i=0;i<8;i++) Bs[(bnc+8+i)*ASTRIDE + bcol] = rB1v[i];
  };

  f32x4 acc[2][8] = {};
  int KT = (K+31)>>5;

  loadAB(0); writeAB();
  __syncthreads();
  for(int kt=0; kt<KT; ++kt){
    bool more = (kt+1 < KT);
    if(more) loadAB(kt+1);
    short8v a[2], b[8];
    #pragma unroll
    for(int fi=0;fi<2;fi++)
      a[fi] = *(const short8v*)&As[(w*32+fi*16+lr)*ASTRIDE + ((lg^((w*2+fi)&3))<<3)];
    #pragma unroll
    for(int fj=0;fj<8;fj++)
      b[fj] = *(const short8v*)&Bs[(fj*16+lr)*ASTRIDE + ((lg^(fj&3))<<3)];   // key=(col>>4)&3=fj&3 matches write
    #pragma unroll
    for(int fi=0;fi<2;fi++)
      #pragma unroll
      for(int fj=0;fj<8;fj++)
        acc[fi][fj] = mfma16(a[fi], b[fj], acc[fi][fj]);
    __syncthreads();
    if(more){ writeAB(); __syncthreads(); }
  }

  #pragma unroll
  for(int fi=0;fi<2;fi++){
    #pragma unroll
    for(int r=0;r<4;r++){
      int rl = m0 + w*32 + fi*16 + lg*4 + r;
      if(rl >= M) continue;
      if(exm){
        int orow = list[e*NT_ + rl];
        if(orow<0||orow>=2*NT_) continue;
        #pragma unroll
        for(int fj=0;fj<8;fj++){
          int gcol = n0 + fj*16 + lr;
          OutE[(size_t)orow*N + gcol] = f2b(acc[fi][fj][r]);
        }
      } else {
        #pragma unroll
        for(int fj=0;fj<8;fj++){
          int gcol = n0 + fj*16 + lr;
          size_t o = (size_t)rl*N + gcol;
          OutS[o] = OutS[o] + acc[fi][fj][r];
        }
      }
    }
  }
}

#define TST 72

// K read directly from global (L2-resident, unswizzled layout identical to old Ks staging).
// V keeps transpose staging in LDS; both barriers retained for Vt.
__global__ __launch_bounds__(256) void k_attn(const bf16* __restrict__ Q, const bf16* __restrict__ Kg,
                                              const bf16* __restrict__ V, bf16* __restrict__ Out){
  int qt_ = (S_/64 - 1) - blockIdx.x;
  int h = blockIdx.y, b = blockIdx.z;
  int kvh = h>>2;
  const bf16* qb = Q + (size_t)b*S_*D_ + h*HD_;
  const bf16* kb = Kg + (size_t)b*S_*256 + kvh*HD_;
  const bf16* vb = V  + (size_t)b*S_*256 + kvh*HD_;
  __shared__ short Qs[64*TST];
  __shared__ short Vt[64*TST];
  __shared__ short Ps[4][16*TST];
  int tid = threadIdx.x;
  int w = tid>>6, l = tid&63, lr = l&15, lg = l>>4;
  int sr = tid>>2, sc0 = (tid&3)*16;
  int vc = (((sr>>3)^(tid&3))<<3) + (sr&7);

  {
    const short8v* src = (const short8v*)(qb + (size_t)(qt_*64 + sr)*D_ + sc0);
    *(short8v*)&Qs[sr*TST + sc0]     = src[0];
    *(short8v*)&Qs[sr*TST + sc0 + 8] = src[1];
  }
  __syncthreads();
  short8v aQ0 = *(const short8v*)&Qs[(w*16+lr)*TST + lg*8];
  short8v aQ1 = *(const short8v*)&Qs[(w*16+lr)*TST + lg*8 + 32];

  float mreg[4], lreg[4];
  f32x4 accO[4] = {};
  #pragma unroll
  for(int r=0;r<4;r++){ mreg[r] = NEGBIG; lreg[r] = 0.f; }

  for(int kt=0; kt<=qt_; ++kt){
    __syncthreads();
    {
      const short8v* vsrc = (const short8v*)(vb + (size_t)(kt*64 + sr)*256 + sc0);
      short8v v0 = vsrc[0], v1 = vsrc[1];
      #pragma unroll
      for(int i=0;i<8;i++){
        Vt[(sc0+i)*TST + vc]   = v0[i];
        Vt[(sc0+8+i)*TST + vc] = v1[i];
      }
    }
    __syncthreads();
    // QK^T: K fragments straight from global (identical elements to old Ks reads)
    const bf16* krow = kb + (size_t)(kt*64)*256;
    f32x4 s[4];
    #pragma unroll
    for(int fj=0; fj<4; fj++){
      short8v b0 = *(const short8v*)(krow + (size_t)(fj*16+lr)*256 + lg*8);
      short8v b1 = *(const short8v*)(krow + (size_t)(fj*16+lr)*256 + lg*8 + 32);
      f32x4 z = {};
      z = mfma16(aQ0, b0, z);
      z = mfma16(aQ1, b1, z);
      s[fj] = z;
    }
    #pragma unroll
    for(int fj=0; fj<4; fj++)
      #pragma unroll
      for(int r=0;r<4;r++){
        float v = s[fj][r]*0.125f;
        if(kt==qt_ && (fj*16+lr) > (w*16+lg*4+r)) v = NEGBIG;
        s[fj][r] = v;
      }
    float p[4][4], sc[4];
    #pragma unroll
    for(int r=0;r<4;r++){
      float mx = fmaxf(fmaxf(s[0][r],s[1][r]), fmaxf(s[2][r],s[3][r]));
      mx = fmaxf(mx, __shfl_xor(mx,1,64));
      mx = fmaxf(mx, __shfl_xor(mx,2,64));
      mx = fmaxf(mx, __shfl_xor(mx,4,64));
      mx = fmaxf(mx, __shfl_xor(mx,8,64));
      float mn = fmaxf(mreg[r], mx);
      sc[r] = __expf(mreg[r]-mn);
      float ps = 0.f;
      #pragma unroll
      for(int fj=0;fj<4;fj++){ float pv = __expf(s[fj][r]-mn); p[fj][r] = pv; ps += pv; }
      ps += __shfl_xor(ps,1,64); ps += __shfl_xor(ps,2,64);
      ps += __shfl_xor(ps,4,64); ps += __shfl_xor(ps,8,64);
      lreg[r] = lreg[r]*sc[r] + ps;
      mreg[r] = mn;
    }
    #pragma unroll
    for(int fj=0;fj<4;fj++)
      #pragma unroll
      for(int r=0;r<4;r++)
        accO[fj][r] *= sc[r];
    #pragma unroll
    for(int fj=0;fj<4;fj++)
      #pragma unroll
      for(int r=0;r<4;r++)
        Ps[w][(lg*4+r)*TST + fj*16+lr] = f2bs(p[fj][r]);
    short8v a0 = *(const short8v*)&Ps[w][lr*TST + lg*8];
    short8v a1 = *(const short8v*)&Ps[w][lr*TST + lg*8 + 32];
    #pragma unroll
    for(int fj=0;fj<4;fj++){
      int row = fj*16+lr;
      short8v b0 = *(const short8v*)&Vt[row*TST + ((lg^fj)<<3)];
      short8v b1 = *(const short8v*)&Vt[row*TST + (((lg^fj)+4)<<3)];
      accO[fj] = mfma16(a0, b0, accO[fj]);
      accO[fj] = mfma16(a1, b1, accO[fj]);
    }
  }
  #pragma unroll
  for(int r=0;r<4;r++){
    int qr = qt_*64 + w*16 + lg*4 + r;
    float inv = (lreg[r] > 0.f) ? 1.f/lreg[r] : 0.f;
    #pragma unroll
    for(int fj=0;fj<4;fj++)
      Out[((size_t)(b*S_+qr))*D_ + h*HD_ + fj*16+lr] = f2b(accO[fj][r]*inv);
  }
}

__global__ __launch_bounds__(64) void k_router(const float* __restrict__ X, const void* __restrict__ W,
                                               float* __restrict__ probs, float* __restrict__ p01,
                                               int* __restrict__ idx0buf, int* __restrict__ list,
                                               int* __restrict__ cnt, const int* __restrict__ flag){
  int isbf = flag[0];
  int t = blockIdx.x; int lane = threadIdx.x;
  float pe[8] = {};
  if(isbf){
    const bf16* Wb = (const bf16*)W;
    for(int d = lane; d < D_; d += 64){
      float xv = X[(size_t)t*D_ + d];
      #pragma unroll
      for(int e=0;e<8;e++) pe[e] += xv*b2f(Wb[(size_t)d*E_+e]);
    }
  } else {
    const float* Wf = (const float*)W;
    for(int d = lane; d < D_; d += 64){
      float xv = X[(size_t)t*D_ + d];
      #pragma unroll
      for(int e=0;e<8;e++) pe[e] += xv*Wf[(size_t)d*E_+e];
    }
  }
  for(int msk=1;msk<64;msk<<=1)
    #pragma unroll
    for(int e=0;e<8;e++) pe[e] += __shfl_xor(pe[e], msk, 64);
  if(lane == 0){
    float mx = pe[0];
    #pragma unroll
    for(int e=1;e<8;e++) mx = fmaxf(mx, pe[e]);
    float pr[8], sum = 0.f;
    #pragma unroll
    for(int e=0;e<8;e++){ pr[e] = __expf(pe[e]-mx); sum += pr[e]; }
    #pragma unroll
    for(int e=0;e<8;e++){ pr[e] /= sum; probs[t*8+e] = pr[e]; }
    int i0 = 0;
    #pragma unroll
    for(int e=1;e<8;e++) if(pe[e] > pe[i0]) i0 = e;
    int i1 = -1;
    #pragma unroll
    for(int e=0;e<8;e++){ if(e==i0) continue; if(i1<0 || pe[e] > pe[i1]) i1 = e; }
    p01[t*2]   = pr[i0];
    p01[t*2+1] = pr[i1];
    idx0buf[t] = i0;
    int pos = atomicAdd(&cnt[i0], 1);
    if(pos >= 0 && pos < NT_) list[i0*NT_ + pos] = t*2;
    pos     = atomicAdd(&cnt[i1], 1);
    if(pos >= 0 && pos < NT_) list[i1*NT_ + pos] = t*2 + 1;
  }
}

__global__ __launch_bounds__(256) void k_stats(const float* __restrict__ probs, const int* __restrict__ idx0buf,
                                               float* __restrict__ cnt0f, float* __restrict__ psum){
  int e = blockIdx.x; int tid = threadIdx.x;
  float sp = 0.f, sc = 0.f;
  for(int n = tid; n < NT_; n += 256){ sp += probs[n*8+e]; sc += (idx0buf[n]==e) ? 1.f : 0.f; }
  __shared__ float r1[256], r2[256];
  r1[tid] = sp; r2[tid] = sc; __syncthreads();
  for(int st=128; st>0; st>>=1){ if(tid<st){ r1[tid]+=r1[tid+st]; r2[tid]+=r2[tid+st]; } __syncthreads(); }
  if(tid==0){ psum[e] = r1[0]; cnt0f[e] = r2[0]; }
}

__global__ void k_finish(const float* __restrict__ cnt0f, const float* __restrict__ psum,
                         const int* __restrict__ cnt, int* __restrict__ offs,
                         bf16* __restrict__ auxb, float* __restrict__ auxf, const int* __restrict__ flag){
  if(threadIdx.x==0 && blockIdx.x==0){
    int o = 0;
    for(int e=0;e<8;e++){ offs[e] = o; int c = cnt[e]; if(c < 0) c = 0; if(c > NT_) c = NT_; o += c; }
    float aux = 0.f;
    for(int e=0;e<8;e++) aux += (cnt0f[e]*(1.f/(float)NT_))*(psum[e]*(1.f/(float)NT_));
    float v = aux*0.01f*8.f;
    if(flag[0]) auxb[0] = f2b(v); else auxf[0] = v;
  }
}

__global__ __launch_bounds__(256) void k_combine(const float* __restrict__ hbuf, const bf16* __restrict__ eosl,
                                                 const float* __restrict__ p01,
                                                 bf16* __restrict__ outb, float* __restrict__ outf,
                                                 const int* __restrict__ flag){
  int t = blockIdx.x; int tid = threadIdx.x;
  int isbf = flag[0];
  float p0 = p01[t*2], p1 = p01[t*2+1];
  #pragma unroll
  for(int i=0;i<4;i++){
    int d = tid + i*256;
    float v = hbuf[(size_t)t*D_ + d]
            + p0*b2f(eosl[((size_t)(t*2))*D_ + d])
            + p1*b2f(eosl[((size_t)(t*2+1))*D_ + d]);
    size_t o = (size_t)t*D_ + d;
    if(isbf) outb[o] = f2b(v); else outf[o] = v;
  }
}

// ---------------- workspace (bytes), peak ~63.3 MB ----------------
static const size_t O_HBUF = 0;
static const size_t O_XNB  = 16777216;
static const size_t O_QLIN = 25165824;
static const size_t O_KLIN = 33554432;
static const size_t O_VLIN = 35651584;
static const size_t O_AOUT = 37748736;
static const size_t O_XN2B = 16777216;
static const size_t O_XN2F = 25165824;
static const size_t O_HEXP = 46137344;
static const size_t O_SHH  = 57344000;
static const size_t O_EOSL = 16777216;
static const size_t O_PROBS= 62947328;
static const size_t O_P01  = 63078400;
static const size_t O_IDX0 = 63111168;
static const size_t O_LIST = 63127552;
static const size_t O_CNT  = 63258624;
static const size_t O_CNT0 = 63258656;
static const size_t O_PSUM = 63258688;
static const size_t O_OFFS = 63258720;
static const size_t O_FLAG = 63258752;

extern "C" void kernel_launch(void* const* d_in, const int* in_sizes, int n_in,
                              void* d_out, int out_size, void* d_ws, size_t ws_size,
                              hipStream_t stream){
  (void)in_sizes; (void)n_in; (void)out_size; (void)ws_size;
  char* ws = (char*)d_ws;
  float* hbuf = (float*)(ws + O_HBUF);
  bf16* xnb   = (bf16*)(ws + O_XNB);
  bf16* qlin  = (bf16*)(ws + O_QLIN);
  bf16* klin  = (bf16*)(ws + O_KLIN);
  bf16* vlin  = (bf16*)(ws + O_VLIN);
  bf16* aout  = (bf16*)(ws + O_AOUT);
  bf16* xn2b  = (bf16*)(ws + O_XN2B);
  float* xn2f = (float*)(ws + O_XN2F);
  bf16* hexp  = (bf16*)(ws + O_HEXP);
  bf16* shh   = (bf16*)(ws + O_SHH);
  bf16* eosl  = (bf16*)(ws + O_EOSL);
  float* probs=(float*)(ws + O_PROBS);
  float* p01 = (float*)(ws + O_P01);
  int*  idx0 = (int*)(ws + O_IDX0);
  int*  list = (int*)(ws + O_LIST);
  int*  cnt  = (int*)(ws + O_CNT);
  float* cnt0f=(float*)(ws + O_CNT0);
  float* psum= (float*)(ws + O_PSUM);
  int*  offs = (int*)(ws + O_OFFS);
  int*  flg  = (int*)(ws + O_FLAG);

  bf16* outb = (bf16*)d_out;
  float* outf = (float*)d_out;
  bf16* auxb = outb + (size_t)NT_*D_;
  float* auxf = outf + (size_t)NT_*D_;

  k_detect<<<1, 64, 0, stream>>>((const uint32_t*)d_in[14], flg, cnt);

  // ---- attention block ----
  k_rms<<<NT_, 256, 0, stream>>>(d_in[0], d_in[14], xnb, nullptr, flg, 1);

  // merged QKV with fused RoPE (q: ct 0..15, k: 16..19, v: 20..23)
  k_qkv<<<dim3(24,32), 256, 0, stream>>>(xnb, d_in[3], d_in[4], d_in[5], qlin, klin, vlin,
                                         d_in[1], d_in[2], flg);

  k_attn<<<dim3(S_/64, H_, B_), 256, 0, stream>>>(qlin, klin, vlin, aout);

  k_mgemm<0,1><<<dim3(16,32), 256, 0, stream>>>(aout, d_in[6], hbuf, d_in[0], NT_, D_, D_, D_, nullptr, nullptr, nullptr, flg);

  // ---- MoE block ----
  k_rms<<<NT_, 256, 0, stream>>>(hbuf, d_in[15], xn2b, xn2f, flg, 0);

  k_router<<<NT_, 64, 0, stream>>>(xn2f, d_in[7], probs, p01, idx0, list, cnt, flg);
  k_stats<<<E_, 256, 0, stream>>>(probs, idx0, cnt0f, psum);
  k_finish<<<1, 64, 0, stream>>>(cnt0f, psum, cnt, offs, auxb, auxf, flg);

  // merged FFN1: expert tiles (y<352, XCD affinity on x) + shared tiles (y>=352)
  k_ffn1m<<<dim3(E_, 352+44), 256, 0, stream>>>(xn2b, d_in[8], d_in[10], d_in[11], d_in[13],
                                                hexp, shh, cnt, offs, list, flg);

  // merged FFN2 (BN=128, single-buffer): expert tiles (y<256) + shared tiles (y>=256)
  k_ffn2m<<<dim3(E_, 256+32), 256, 0, stream>>>(hexp, shh, d_in[9], d_in[12],
                                                eosl, hbuf, cnt, offs, list, flg);

  k_combine<<<NT_, 256, 0, stream>>>(hbuf, eosl, p01, outb, outf, flg);
}

// Round 24
// 617.571 us; speedup vs baseline: 1.0627x; 1.0627x over previous
//
#include <hip/hip_runtime.h>
#include <hip/hip_bf16.h>
#include <cstdint>

#define B_ 2
#define S_ 2048
#define D_ 1024
#define H_ 16
#define HKV_ 4
#define HD_ 64
#define E_ 8
#define HIDDEN_ 684
#define NT_ (B_*S_)
#define NEGBIG (-1e30f)

using bf16 = __hip_bfloat16;
typedef __attribute__((ext_vector_type(8))) short short8v;
typedef __attribute__((ext_vector_type(4))) short short4v;
typedef __attribute__((ext_vector_type(4))) float f32x4;

static __device__ __forceinline__ float b2f(bf16 v){ return __bfloat162float(v); }
static __device__ __forceinline__ bf16 f2b(float v){ return __float2bfloat16(v); }
static __device__ __forceinline__ short f2bs(float v){ bf16 h = f2b(v); return *reinterpret_cast<short*>(&h); }
static __device__ __forceinline__ float dload(const void* p, size_t i, int isbf){
  return isbf ? b2f(((const bf16*)p)[i]) : ((const float*)p)[i];
}

__global__ void k_detect(const uint32_t* __restrict__ g, int* __restrict__ flag, int* __restrict__ cnt){
  if(threadIdx.x == 0 && blockIdx.x == 0){
    uint32_t w0 = g[0], w1 = g[1], w2 = g[2], w3 = g[3];
    int bf;
    if(w0==0x3F803F80u && w1==0x3F803F80u && w2==0x3F803F80u && w3==0x3F803F80u) bf = 1;
    else if(w0==0x3F800000u && w1==0x3F800000u && w2==0x3F800000u && w3==0x3F800000u) bf = 0;
    else bf = 1;
    flag[0] = bf;
  }
  if(threadIdx.x < E_ && blockIdx.x == 0) cnt[threadIdx.x] = 0;
}

// ---------------- RMSNorm -> bf16 out (+ optional f32 copy for router) ----------------
__global__ __launch_bounds__(256) void k_rms(const void* __restrict__ X, const void* __restrict__ g,
                                             bf16* __restrict__ outb, float* __restrict__ outf,
                                             const int* __restrict__ flag, int xdyn){
  int isbf = flag[0]; int xb = xdyn ? isbf : 0;
  int t = blockIdx.x; int tid = threadIdx.x;
  float v[4]; float ss = 0.f;
  #pragma unroll
  for(int i=0;i<4;i++){ v[i] = dload(X, (size_t)t*D_ + tid + i*256, xb); ss += v[i]*v[i]; }
  __shared__ float red[256];
  red[tid] = ss; __syncthreads();
  for(int st=128; st>0; st>>=1){ if(tid<st) red[tid] += red[tid+st]; __syncthreads(); }
  float r = rsqrtf(red[0]*(1.f/(float)D_) + 1e-5f);
  #pragma unroll
  for(int i=0;i<4;i++){
    int d = tid + i*256;
    float val = v[i]*r*dload(g, d, isbf);
    outb[(size_t)t*D_ + d] = f2b(val);
    if(outf) outf[(size_t)t*D_ + d] = val;
  }
}

// ============ GEMM scaffolding (BM=128 BN=64 BK=32, proven) ============
#define ASTRIDE 40

static __device__ __forceinline__ f32x4 mfma16(short8v a, short8v b, f32x4 c){
  return __builtin_amdgcn_mfma_f32_16x16x32_bf16(a, b, c, 0, 0, 0);
}

// ---------------- generic GEMM (used for wo) ----------------
template<int AMAP, int OMODE>
__global__ __launch_bounds__(256) void k_mgemm(
    const bf16* __restrict__ A, const void* __restrict__ Bw, void* __restrict__ Cout,
    const void* __restrict__ resid,
    int M, int N, int K, int ldc,
    const int* __restrict__ cnt, const int* __restrict__ offs, const int* __restrict__ list,
    const int* __restrict__ flag)
{
  int isbf = flag[0];
  int e, ct, rt;
  int base = 0; size_t eoff = 0;
  if(cnt){
    e = blockIdx.x;
    int nc = (N+63)>>6;
    ct = blockIdx.y % nc; rt = blockIdx.y / nc;
    M = cnt[e]; if(M<0) M=0; if(M>NT_) M=NT_;
    base = offs[e];
    eoff = (size_t)e*(size_t)K*(size_t)N;
  } else {
    e = 0; ct = blockIdx.x; rt = blockIdx.y;
  }
  int m0 = rt*128; if(m0 >= M) return;
  int n0 = ct*64;

  __shared__ short As[2][128*ASTRIDE];
  __shared__ short Bs[2][64*ASTRIDE];
  __shared__ int rowA[128];

  int tid = threadIdx.x;
  int w = tid>>6, l = tid&63, lr = l&15, lg = l>>4;

  if(tid < 128){
    int rloc = m0 + tid;
    int ar = -1;
    if(rloc < M) ar = (AMAP==2) ? (list[e*NT_ + rloc]>>1) : (base + rloc);
    rowA[tid] = ar;
  }
  __syncthreads();

  int srow = tid>>1, skh = (tid&1)*16;
  int keya = (srow>>4)&3, kb0 = skh>>3;
  int bk = tid>>3, bnc = (tid&7)*8;
  int keyb = ((tid&7)>>1)&3;
  int bcol = (((bk>>3)^keyb)<<3) + (bk&7);
  int arow = rowA[srow];

  short8v rA0, rA1, rB;

  auto loadAB = [&](int kt){
    int k0 = kt*32;
    {
      short tmp[16];
      if(arow >= 0 && k0+skh+16 <= K){
        const short4v* src = (const short4v*)(A + (size_t)arow*K + k0 + skh);
        #pragma unroll
        for(int c=0;c<4;c++) *(short4v*)&tmp[c*4] = src[c];
      } else {
        #pragma unroll
        for(int i=0;i<16;i++){
          int gk = k0+skh+i;
          short v = 0;
          if(arow>=0 && gk<K) v = *(const short*)&A[(size_t)arow*K+gk];
          tmp[i] = v;
        }
      }
      #pragma unroll
      for(int i=0;i<8;i++){ rA0[i]=tmp[i]; rA1[i]=tmp[8+i]; }
    }
    {
      int gk = k0 + bk;
      short tmp[8];
      if(gk < K && n0+bnc+8 <= N){
        size_t bb = eoff + (size_t)gk*N + n0 + bnc;
        if(isbf){
          const short4v* src = (const short4v*)((const bf16*)Bw + bb);
          *(short4v*)&tmp[0] = src[0];
          *(short4v*)&tmp[4] = src[1];
        } else {
          const f32x4* src = (const f32x4*)((const float*)Bw + bb);
          f32x4 f0 = src[0], f1 = src[1];
          #pragma unroll
          for(int i=0;i<4;i++){ tmp[i]=f2bs(f0[i]); tmp[4+i]=f2bs(f1[i]); }
        }
      } else {
        #pragma unroll
        for(int i=0;i<8;i++){
          int gn = n0+bnc+i;
          float v = 0.f;
          if(gk<K && gn<N) v = dload(Bw, eoff + (size_t)gk*N + gn, isbf);
          tmp[i] = f2bs(v);
        }
      }
      #pragma unroll
      for(int i=0;i<8;i++) rB[i]=tmp[i];
    }
  };
  auto writeAB = [&](int buf){
    *(short8v*)&As[buf][srow*ASTRIDE + ((kb0^keya)<<3)]     = rA0;
    *(short8v*)&As[buf][srow*ASTRIDE + (((kb0+1)^keya)<<3)] = rA1;
    #pragma unroll
    for(int i=0;i<8;i++) Bs[buf][(bnc+i)*ASTRIDE + bcol] = rB[i];
  };

  f32x4 acc[2][4] = {};
  int KT = (K+31)>>5;

  loadAB(0); writeAB(0);
  __syncthreads();
  int cur = 0;
  for(int kt=0; kt<KT; ++kt){
    bool more = (kt+1 < KT);
    if(more) loadAB(kt+1);
    short8v a[2], b[4];
    #pragma unroll
    for(int fi=0;fi<2;fi++)
      a[fi] = *(const short8v*)&As[cur][(w*32+fi*16+lr)*ASTRIDE + ((lg^((w*2+fi)&3))<<3)];
    #pragma unroll
    for(int fj=0;fj<4;fj++)
      b[fj] = *(const short8v*)&Bs[cur][(fj*16+lr)*ASTRIDE + ((lg^fj)<<3)];
    #pragma unroll
    for(int fi=0;fi<2;fi++)
      #pragma unroll
      for(int fj=0;fj<4;fj++)
        acc[fi][fj] = mfma16(a[fi], b[fj], acc[fi][fj]);
    if(more){ writeAB(cur^1); cur ^= 1; }
    __syncthreads();
  }

  #pragma unroll
  for(int fi=0;fi<2;fi++){
    #pragma unroll
    for(int r=0;r<4;r++){
      int rl = m0 + w*32 + fi*16 + lg*4 + r;
      if(rl >= M) continue;
      int orow;
      if(OMODE==2){ orow = list[e*NT_ + rl]; if(orow<0||orow>=2*NT_) continue; }
      else orow = base + rl;
      #pragma unroll
      for(int fj=0;fj<4;fj++){
        int gcol = n0 + fj*16 + lr;
        if(gcol >= N) continue;
        float v = acc[fi][fj][r];
        size_t o = (size_t)orow*ldc + gcol;
        if(OMODE==1)      ((float*)Cout)[o] = v + dload(resid, o, isbf);
        else if(OMODE==2) ((bf16*)Cout)[o] = f2b(v);
        else if(OMODE==3) ((float*)Cout)[o] = ((float*)Cout)[o] + v;
        else              ((bf16*)Cout)[o] = f2b(v);
      }
    }
  }
}

// ---------------- merged QKV GEMM with fused RoPE epilogue ----------------
// Epilogue lane layout: col = n0+fj*16+lr, parity(col)=parity(lane); lanes l,l^1 hold
// the (even,odd) column pair of the SAME row -> rotate via __shfl_xor(v,1).
__global__ __launch_bounds__(256) void k_qkv(
    const bf16* __restrict__ A, const void* __restrict__ Wq, const void* __restrict__ Wk,
    const void* __restrict__ Wv, bf16* __restrict__ Oq, bf16* __restrict__ Ok, bf16* __restrict__ Ov,
    const void* __restrict__ fc, const void* __restrict__ fs,
    const int* __restrict__ flag)
{
  int isbf = flag[0];
  int ct = blockIdx.x, rt = blockIdx.y;
  const void* Bw; bf16* Cout; int N, n0;
  if(ct < 16){ Bw = Wq; Cout = Oq; N = D_;  n0 = ct*64; }
  else if(ct < 20){ Bw = Wk; Cout = Ok; N = 256; n0 = (ct-16)*64; }
  else { Bw = Wv; Cout = Ov; N = 256; n0 = (ct-20)*64; }
  const int K = D_, M = NT_;
  int m0 = rt*128;
  int dorope = (ct < 20);

  __shared__ short As[2][128*ASTRIDE];
  __shared__ short Bs[2][64*ASTRIDE];

  int tid = threadIdx.x;
  int w = tid>>6, l = tid&63, lr = l&15, lg = l>>4;

  int srow = tid>>1, skh = (tid&1)*16;
  int keya = (srow>>4)&3, kb0 = skh>>3;
  int bk = tid>>3, bnc = (tid&7)*8;
  int keyb = ((tid&7)>>1)&3;
  int bcol = (((bk>>3)^keyb)<<3) + (bk&7);
  int arow = m0 + srow;

  short8v rA0, rA1, rB;

  auto loadAB = [&](int kt){
    int k0 = kt*32;
    {
      short tmp[16];
      const short4v* src = (const short4v*)(A + (size_t)arow*K + k0 + skh);
      #pragma unroll
      for(int c=0;c<4;c++) *(short4v*)&tmp[c*4] = src[c];
      #pragma unroll
      for(int i=0;i<8;i++){ rA0[i]=tmp[i]; rA1[i]=tmp[8+i]; }
    }
    {
      int gk = k0 + bk;
      short tmp[8];
      size_t bb = (size_t)gk*N + n0 + bnc;
      if(isbf){
        const short4v* src = (const short4v*)((const bf16*)Bw + bb);
        *(short4v*)&tmp[0] = src[0];
        *(short4v*)&tmp[4] = src[1];
      } else {
        const f32x4* src = (const f32x4*)((const float*)Bw + bb);
        f32x4 f0 = src[0], f1 = src[1];
        #pragma unroll
        for(int i=0;i<4;i++){ tmp[i]=f2bs(f0[i]); tmp[4+i]=f2bs(f1[i]); }
      }
      #pragma unroll
      for(int i=0;i<8;i++) rB[i]=tmp[i];
    }
  };
  auto writeAB = [&](int buf){
    *(short8v*)&As[buf][srow*ASTRIDE + ((kb0^keya)<<3)]     = rA0;
    *(short8v*)&As[buf][srow*ASTRIDE + (((kb0+1)^keya)<<3)] = rA1;
    #pragma unroll
    for(int i=0;i<8;i++) Bs[buf][(bnc+i)*ASTRIDE + bcol] = rB[i];
  };

  f32x4 acc[2][4] = {};
  int KT = K>>5;

  loadAB(0); writeAB(0);
  __syncthreads();
  int cur = 0;
  for(int kt=0; kt<KT; ++kt){
    bool more = (kt+1 < KT);
    if(more) loadAB(kt+1);
    short8v a[2], b[4];
    #pragma unroll
    for(int fi=0;fi<2;fi++)
      a[fi] = *(const short8v*)&As[cur][(w*32+fi*16+lr)*ASTRIDE + ((lg^((w*2+fi)&3))<<3)];
    #pragma unroll
    for(int fj=0;fj<4;fj++)
      b[fj] = *(const short8v*)&Bs[cur][(fj*16+lr)*ASTRIDE + ((lg^fj)<<3)];
    #pragma unroll
    for(int fi=0;fi<2;fi++)
      #pragma unroll
      for(int fj=0;fj<4;fj++)
        acc[fi][fj] = mfma16(a[fi], b[fj], acc[fi][fj]);
    if(more){ writeAB(cur^1); cur ^= 1; }
    __syncthreads();
  }

  // epilogue (+ fused RoPE). No guards fire (exact tiling) -> all 64 lanes active at shfl.
  #pragma unroll
  for(int fi=0;fi<2;fi++){
    #pragma unroll
    for(int r=0;r<4;r++){
      int rl = m0 + w*32 + fi*16 + lg*4 + r;
      int s = rl & (S_-1);
      #pragma unroll
      for(int fj=0;fj<4;fj++){
        int gcol = n0 + fj*16 + lr;
        float v = acc[fi][fj][r];
        if(dorope){
          float partner = __shfl_xor(v, 1, 64);
          int p = (gcol & 63) >> 1;
          float c = dload(fc, s*32 + p, isbf);
          float sn = dload(fs, s*32 + p, isbf);
          if((l & 1) == 0) v = v*c - partner*sn;
          else             v = partner*sn + v*c;
        }
        Cout[(size_t)rl*N + gcol] = f2b(v);
      }
    }
  }
}

// ---------------- merged FFN1 (ct-inner, fused silu) ----------------
__global__ __launch_bounds__(256) void k_ffn1m(
    const bf16* __restrict__ A, const void* __restrict__ W1e, const void* __restrict__ W3e,
    const void* __restrict__ W1s, const void* __restrict__ W3s,
    bf16* __restrict__ OutE, bf16* __restrict__ OutS,
    const int* __restrict__ cnt, const int* __restrict__ offs, const int* __restrict__ list,
    const int* __restrict__ flag)
{
  int isbf = flag[0];
  const int K = D_, N = HIDDEN_;
  int e = blockIdx.x, y = blockIdx.y;
  int ct, rt, M, base, gat;
  const void* W1; const void* W3; bf16* Out;
  size_t eoff;
  if(y < 352){
    ct = y % 11; rt = y / 11;
    M = cnt[e]; if(M<0) M=0; if(M>NT_) M=NT_;
    base = offs[e]; gat = 1;
    W1 = W1e; W3 = W3e; Out = OutE;
    eoff = (size_t)e*(size_t)K*(size_t)N;
  } else {
    int ys = (y-352)*8 + e;
    ct = ys % 11; rt = ys / 11;
    M = NT_; base = 0; gat = 0;
    W1 = W1s; W3 = W3s; Out = OutS;
    eoff = 0;
  }
  int m0 = rt*128; if(m0 >= M) return;
  int n0 = ct*64;

  __shared__ short As[2][128*ASTRIDE];
  __shared__ short B1s[2][64*ASTRIDE];
  __shared__ short B3s[2][64*ASTRIDE];
  __shared__ int rowA[128];

  int tid = threadIdx.x;
  int w = tid>>6, l = tid&63, lr = l&15, lg = l>>4;

  if(tid < 128){
    int rloc = m0 + tid;
    int ar = -1;
    if(rloc < M) ar = gat ? (list[e*NT_ + rloc]>>1) : rloc;
    rowA[tid] = ar;
  }
  __syncthreads();

  int srow = tid>>1, skh = (tid&1)*16;
  int keya = (srow>>4)&3, kb0 = skh>>3;
  int bk = tid>>3, bnc = (tid&7)*8;
  int keyb = ((tid&7)>>1)&3;
  int bcol = (((bk>>3)^keyb)<<3) + (bk&7);
  int arow = rowA[srow];

  short8v rA0, rA1, rB1, rB3;

  auto loadB = [&](const void* Bw, int kt, short8v& rB){
    int k0 = kt*32;
    int gk = k0 + bk;
    short tmp[8];
    if(gk < K && n0+bnc+8 <= N){
      size_t bb = eoff + (size_t)gk*N + n0 + bnc;
      if(isbf){
        const short4v* src = (const short4v*)((const bf16*)Bw + bb);
        *(short4v*)&tmp[0] = src[0];
        *(short4v*)&tmp[4] = src[1];
      } else {
        const f32x4* src = (const f32x4*)((const float*)Bw + bb);
        f32x4 f0 = src[0], f1 = src[1];
        #pragma unroll
        for(int i=0;i<4;i++){ tmp[i]=f2bs(f0[i]); tmp[4+i]=f2bs(f1[i]); }
      }
    } else {
      #pragma unroll
      for(int i=0;i<8;i++){
        int gn = n0+bnc+i;
        float v = 0.f;
        if(gk<K && gn<N) v = dload(Bw, eoff + (size_t)gk*N + gn, isbf);
        tmp[i] = f2bs(v);
      }
    }
    #pragma unroll
    for(int i=0;i<8;i++) rB[i]=tmp[i];
  };
  auto loadA = [&](int kt){
    int k0 = kt*32;
    short tmp[16];
    if(arow >= 0 && k0+skh+16 <= K){
      const short4v* src = (const short4v*)(A + (size_t)arow*K + k0 + skh);
      #pragma unroll
      for(int c=0;c<4;c++) *(short4v*)&tmp[c*4] = src[c];
    } else {
      #pragma unroll
      for(int i=0;i<16;i++){
        int gk = k0+skh+i;
        short v = 0;
        if(arow>=0 && gk<K) v = *(const short*)&A[(size_t)arow*K+gk];
        tmp[i] = v;
      }
    }
    #pragma unroll
    for(int i=0;i<8;i++){ rA0[i]=tmp[i]; rA1[i]=tmp[8+i]; }
  };
  auto writeAll = [&](int buf){
    *(short8v*)&As[buf][srow*ASTRIDE + ((kb0^keya)<<3)]     = rA0;
    *(short8v*)&As[buf][srow*ASTRIDE + (((kb0+1)^keya)<<3)] = rA1;
    #pragma unroll
    for(int i=0;i<8;i++){
      B1s[buf][(bnc+i)*ASTRIDE + bcol] = rB1[i];
      B3s[buf][(bnc+i)*ASTRIDE + bcol] = rB3[i];
    }
  };

  f32x4 a1[2][4] = {}, a3[2][4] = {};
  int KT = (K+31)>>5;

  loadA(0); loadB(W1, 0, rB1); loadB(W3, 0, rB3); writeAll(0);
  __syncthreads();
  int cur = 0;
  for(int kt=0; kt<KT; ++kt){
    bool more = (kt+1 < KT);
    if(more){ loadA(kt+1); loadB(W1, kt+1, rB1); loadB(W3, kt+1, rB3); }
    short8v a[2], b1[4], b3[4];
    #pragma unroll
    for(int fi=0;fi<2;fi++)
      a[fi] = *(const short8v*)&As[cur][(w*32+fi*16+lr)*ASTRIDE + ((lg^((w*2+fi)&3))<<3)];
    #pragma unroll
    for(int fj=0;fj<4;fj++){
      b1[fj] = *(const short8v*)&B1s[cur][(fj*16+lr)*ASTRIDE + ((lg^fj)<<3)];
      b3[fj] = *(const short8v*)&B3s[cur][(fj*16+lr)*ASTRIDE + ((lg^fj)<<3)];
    }
    #pragma unroll
    for(int fi=0;fi<2;fi++)
      #pragma unroll
      for(int fj=0;fj<4;fj++){
        a1[fi][fj] = mfma16(a[fi], b1[fj], a1[fi][fj]);
        a3[fi][fj] = mfma16(a[fi], b3[fj], a3[fi][fj]);
      }
    if(more){ writeAll(cur^1); cur ^= 1; }
    __syncthreads();
  }

  #pragma unroll
  for(int fi=0;fi<2;fi++){
    #pragma unroll
    for(int r=0;r<4;r++){
      int rl = m0 + w*32 + fi*16 + lg*4 + r;
      if(rl >= M) continue;
      int orow = base + rl;
      #pragma unroll
      for(int fj=0;fj<4;fj++){
        int gcol = n0 + fj*16 + lr;
        if(gcol >= N) continue;
        float sg = a1[fi][fj][r];
        float v = (sg/(1.f+__expf(-sg))) * a3[fi][fj][r];
        Out[(size_t)orow*N + gcol] = f2b(v);
      }
    }
  }
}

// ---------------- merged FFN2: BN=128, SINGLE buffer (20.5 KB LDS, 16 MFMA/wave/step) ----------------
__global__ __launch_bounds__(256) void k_ffn2m(
    const bf16* __restrict__ Ae, const bf16* __restrict__ Ash,
    const void* __restrict__ W2e, const void* __restrict__ W2s,
    bf16* __restrict__ OutE, float* __restrict__ OutS,
    const int* __restrict__ cnt, const int* __restrict__ offs, const int* __restrict__ list,
    const int* __restrict__ flag)
{
  int isbf = flag[0];
  const int K = HIDDEN_, N = D_;
  int e = blockIdx.x, y = blockIdx.y;
  int ct, rt, M, base, exm;
  const bf16* A; const void* Bw;
  size_t eoff;
  if(y < 256){            // expert: 8 ct x 32 rt (ct-inner like r13)
    ct = y % 8; rt = y / 8;
    M = cnt[e]; if(M<0) M=0; if(M>NT_) M=NT_;
    base = offs[e]; exm = 1;
    A = Ae; Bw = W2e;
    eoff = (size_t)e*(size_t)K*(size_t)N;
  } else {                // shared: 256 tiles over 8 x-lanes
    int ys = (y-256)*8 + e;
    ct = ys % 8; rt = ys / 8;
    M = NT_; base = 0; exm = 0;
    A = Ash; Bw = W2s;
    eoff = 0;
  }
  int m0 = rt*128; if(m0 >= M) return;
  int n0 = ct*128;

  __shared__ short As[128*ASTRIDE];
  __shared__ short Bs[128*ASTRIDE];   // [col][k], 128 cols

  int tid = threadIdx.x;
  int w = tid>>6, l = tid&63, lr = l&15, lg = l>>4;

  int srow = tid>>1, skh = (tid&1)*16;
  int keya = (srow>>4)&3, kb0 = skh>>3;
  int bk = tid>>3, bnc = (tid&7)*16;        // 16 cols per thread
  int keyb = (tid&7)&3;                     // = ((bnc+i)>>4)&3 for i<16
  int bcol = (((bk>>3)^keyb)<<3) + (bk&7);
  int arow = (m0 + srow < M) ? (base + m0 + srow) : -1;

  short8v rA0, rA1, rB0v, rB1v;

  auto loadAB = [&](int kt){
    int k0 = kt*32;
    { // A (bf16), 16 k-values
      short tmp[16];
      if(arow >= 0 && k0+skh+16 <= K){
        const short4v* src = (const short4v*)(A + (size_t)arow*K + k0 + skh);
        #pragma unroll
        for(int c=0;c<4;c++) *(short4v*)&tmp[c*4] = src[c];
      } else {
        #pragma unroll
        for(int i=0;i<16;i++){
          int gk = k0+skh+i;
          short v = 0;
          if(arow>=0 && gk<K) v = *(const short*)&A[(size_t)arow*K+gk];
          tmp[i] = v;
        }
      }
      #pragma unroll
      for(int i=0;i<8;i++){ rA0[i]=tmp[i]; rA1[i]=tmp[8+i]; }
    }
    { // B: 16 cols at one k  (n0+bnc+16 <= 1024 always; guard only gk)
      int gk = k0 + bk;
      short tmp[16];
      if(gk < K){
        size_t bb = eoff + (size_t)gk*N + n0 + bnc;
        if(isbf){
          const short4v* src = (const short4v*)((const bf16*)Bw + bb);
          #pragma unroll
          for(int c=0;c<4;c++) *(short4v*)&tmp[c*4] = src[c];
        } else {
          const f32x4* src = (const f32x4*)((const float*)Bw + bb);
          #pragma unroll
          for(int c=0;c<4;c++){
            f32x4 f = src[c];
            #pragma unroll
            for(int i=0;i<4;i++) tmp[c*4+i] = f2bs(f[i]);
          }
        }
      } else {
        #pragma unroll
        for(int i=0;i<16;i++) tmp[i] = 0;
      }
      #pragma unroll
      for(int i=0;i<8;i++){ rB0v[i]=tmp[i]; rB1v[i]=tmp[8+i]; }
    }
  };
  auto writeAB = [&](){
    *(short8v*)&As[srow*ASTRIDE + ((kb0^keya)<<3)]     = rA0;
    *(short8v*)&As[srow*ASTRIDE + (((kb0+1)^keya)<<3)] = rA1;
    #pragma unroll
    for(int i=0;i<8;i++) Bs[(bnc+i)*ASTRIDE + bcol]   = rB0v[i];
    #pragma unroll
    for(int i=0;i<8;i++) Bs[(bnc+8+i)*ASTRIDE + bcol] = rB1v[i];
  };

  f32x4 acc[2][8] = {};
  int KT = (K+31)>>5;

  loadAB(0); writeAB();
  __syncthreads();
  for(int kt=0; kt<KT; ++kt){
    bool more = (kt+1 < KT);
    if(more) loadAB(kt+1);
    short8v a[2], b[8];
    #pragma unroll
    for(int fi=0;fi<2;fi++)
      a[fi] = *(const short8v*)&As[(w*32+fi*16+lr)*ASTRIDE + ((lg^((w*2+fi)&3))<<3)];
    #pragma unroll
    for(int fj=0;fj<8;fj++)
      b[fj] = *(const short8v*)&Bs[(fj*16+lr)*ASTRIDE + ((lg^(fj&3))<<3)];   // key=(col>>4)&3=fj&3 matches write
    #pragma unroll
    for(int fi=0;fi<2;fi++)
      #pragma unroll
      for(int fj=0;fj<8;fj++)
        acc[fi][fj] = mfma16(a[fi], b[fj], acc[fi][fj]);
    __syncthreads();
    if(more){ writeAB(); __syncthreads(); }
  }

  #pragma unroll
  for(int fi=0;fi<2;fi++){
    #pragma unroll
    for(int r=0;r<4;r++){
      int rl = m0 + w*32 + fi*16 + lg*4 + r;
      if(rl >= M) continue;
      if(exm){
        int orow = list[e*NT_ + rl];
        if(orow<0||orow>=2*NT_) continue;
        #pragma unroll
        for(int fj=0;fj<8;fj++){
          int gcol = n0 + fj*16 + lr;
          OutE[(size_t)orow*N + gcol] = f2b(acc[fi][fj][r]);
        }
      } else {
        #pragma unroll
        for(int fj=0;fj<8;fj++){
          int gcol = n0 + fj*16 + lr;
          size_t o = (size_t)rl*N + gcol;
          OutS[o] = OutS[o] + acc[fi][fj][r];
        }
      }
    }
  }
}

#define TST 72

__global__ __launch_bounds__(256) void k_attn(const bf16* __restrict__ Q, const bf16* __restrict__ Kg,
                                              const bf16* __restrict__ V, bf16* __restrict__ Out){
  int qt_ = (S_/64 - 1) - blockIdx.x;
  int h = blockIdx.y, b = blockIdx.z;
  int kvh = h>>2;
  const bf16* qb = Q + (size_t)b*S_*D_ + h*HD_;
  const bf16* kb = Kg + (size_t)b*S_*256 + kvh*HD_;
  const bf16* vb = V  + (size_t)b*S_*256 + kvh*HD_;
  __shared__ short Qs[64*TST];
  __shared__ short Ks[64*TST];
  __shared__ short Vt[64*TST];
  __shared__ short Ps[4][16*TST];
  int tid = threadIdx.x;
  int w = tid>>6, l = tid&63, lr = l&15, lg = l>>4;
  int sr = tid>>2, sc0 = (tid&3)*16;
  int vc = (((sr>>3)^(tid&3))<<3) + (sr&7);

  {
    const short8v* src = (const short8v*)(qb + (size_t)(qt_*64 + sr)*D_ + sc0);
    *(short8v*)&Qs[sr*TST + sc0]     = src[0];
    *(short8v*)&Qs[sr*TST + sc0 + 8] = src[1];
  }
  __syncthreads();
  short8v aQ0 = *(const short8v*)&Qs[(w*16+lr)*TST + lg*8];
  short8v aQ1 = *(const short8v*)&Qs[(w*16+lr)*TST + lg*8 + 32];

  float mreg[4], lreg[4];
  f32x4 accO[4] = {};
  #pragma unroll
  for(int r=0;r<4;r++){ mreg[r] = NEGBIG; lreg[r] = 0.f; }

  for(int kt=0; kt<=qt_; ++kt){
    __syncthreads();
    {
      const short8v* ksrc = (const short8v*)(kb + (size_t)(kt*64 + sr)*256 + sc0);
      *(short8v*)&Ks[sr*TST + sc0]     = ksrc[0];
      *(short8v*)&Ks[sr*TST + sc0 + 8] = ksrc[1];
      const short8v* vsrc = (const short8v*)(vb + (size_t)(kt*64 + sr)*256 + sc0);
      short8v v0 = vsrc[0], v1 = vsrc[1];
      #pragma unroll
      for(int i=0;i<8;i++){
        Vt[(sc0+i)*TST + vc]   = v0[i];
        Vt[(sc0+8+i)*TST + vc] = v1[i];
      }
    }
    __syncthreads();
    f32x4 s[4];
    #pragma unroll
    for(int fj=0; fj<4; fj++){
      short8v b0 = *(const short8v*)&Ks[(fj*16+lr)*TST + lg*8];
      short8v b1 = *(const short8v*)&Ks[(fj*16+lr)*TST + lg*8 + 32];
      f32x4 z = {};
      z = mfma16(aQ0, b0, z);
      z = mfma16(aQ1, b1, z);
      s[fj] = z;
    }
    #pragma unroll
    for(int fj=0; fj<4; fj++)
      #pragma unroll
      for(int r=0;r<4;r++){
        float v = s[fj][r]*0.125f;
        if(kt==qt_ && (fj*16+lr) > (w*16+lg*4+r)) v = NEGBIG;
        s[fj][r] = v;
      }
    float p[4][4], sc[4];
    #pragma unroll
    for(int r=0;r<4;r++){
      float mx = fmaxf(fmaxf(s[0][r],s[1][r]), fmaxf(s[2][r],s[3][r]));
      mx = fmaxf(mx, __shfl_xor(mx,1,64));
      mx = fmaxf(mx, __shfl_xor(mx,2,64));
      mx = fmaxf(mx, __shfl_xor(mx,4,64));
      mx = fmaxf(mx, __shfl_xor(mx,8,64));
      float mn = fmaxf(mreg[r], mx);
      sc[r] = __expf(mreg[r]-mn);
      float ps = 0.f;
      #pragma unroll
      for(int fj=0;fj<4;fj++){ float pv = __expf(s[fj][r]-mn); p[fj][r] = pv; ps += pv; }
      ps += __shfl_xor(ps,1,64); ps += __shfl_xor(ps,2,64);
      ps += __shfl_xor(ps,4,64); ps += __shfl_xor(ps,8,64);
      lreg[r] = lreg[r]*sc[r] + ps;
      mreg[r] = mn;
    }
    #pragma unroll
    for(int fj=0;fj<4;fj++)
      #pragma unroll
      for(int r=0;r<4;r++)
        accO[fj][r] *= sc[r];
    #pragma unroll
    for(int fj=0;fj<4;fj++)
      #pragma unroll
      for(int r=0;r<4;r++)
        Ps[w][(lg*4+r)*TST + fj*16+lr] = f2bs(p[fj][r]);
    short8v a0 = *(const short8v*)&Ps[w][lr*TST + lg*8];
    short8v a1 = *(const short8v*)&Ps[w][lr*TST + lg*8 + 32];
    #pragma unroll
    for(int fj=0;fj<4;fj++){
      int row = fj*16+lr;
      short8v b0 = *(const short8v*)&Vt[row*TST + ((lg^fj)<<3)];
      short8v b1 = *(const short8v*)&Vt[row*TST + (((lg^fj)+4)<<3)];
      accO[fj] = mfma16(a0, b0, accO[fj]);
      accO[fj] = mfma16(a1, b1, accO[fj]);
    }
  }
  #pragma unroll
  for(int r=0;r<4;r++){
    int qr = qt_*64 + w*16 + lg*4 + r;
    float inv = (lreg[r] > 0.f) ? 1.f/lreg[r] : 0.f;
    #pragma unroll
    for(int fj=0;fj<4;fj++)
      Out[((size_t)(b*S_+qr))*D_ + h*HD_ + fj*16+lr] = f2b(accO[fj][r]*inv);
  }
}

__global__ __launch_bounds__(64) void k_router(const float* __restrict__ X, const void* __restrict__ W,
                                               float* __restrict__ probs, float* __restrict__ p01,
                                               int* __restrict__ idx0buf, int* __restrict__ list,
                                               int* __restrict__ cnt, const int* __restrict__ flag){
  int isbf = flag[0];
  int t = blockIdx.x; int lane = threadIdx.x;
  float pe[8] = {};
  if(isbf){
    const bf16* Wb = (const bf16*)W;
    for(int d = lane; d < D_; d += 64){
      float xv = X[(size_t)t*D_ + d];
      #pragma unroll
      for(int e=0;e<8;e++) pe[e] += xv*b2f(Wb[(size_t)d*E_+e]);
    }
  } else {
    const float* Wf = (const float*)W;
    for(int d = lane; d < D_; d += 64){
      float xv = X[(size_t)t*D_ + d];
      #pragma unroll
      for(int e=0;e<8;e++) pe[e] += xv*Wf[(size_t)d*E_+e];
    }
  }
  for(int msk=1;msk<64;msk<<=1)
    #pragma unroll
    for(int e=0;e<8;e++) pe[e] += __shfl_xor(pe[e], msk, 64);
  if(lane == 0){
    float mx = pe[0];
    #pragma unroll
    for(int e=1;e<8;e++) mx = fmaxf(mx, pe[e]);
    float pr[8], sum = 0.f;
    #pragma unroll
    for(int e=0;e<8;e++){ pr[e] = __expf(pe[e]-mx); sum += pr[e]; }
    #pragma unroll
    for(int e=0;e<8;e++){ pr[e] /= sum; probs[t*8+e] = pr[e]; }
    int i0 = 0;
    #pragma unroll
    for(int e=1;e<8;e++) if(pe[e] > pe[i0]) i0 = e;
    int i1 = -1;
    #pragma unroll
    for(int e=0;e<8;e++){ if(e==i0) continue; if(i1<0 || pe[e] > pe[i1]) i1 = e; }
    p01[t*2]   = pr[i0];
    p01[t*2+1] = pr[i1];
    idx0buf[t] = i0;
    int pos = atomicAdd(&cnt[i0], 1);
    if(pos >= 0 && pos < NT_) list[i0*NT_ + pos] = t*2;
    pos     = atomicAdd(&cnt[i1], 1);
    if(pos >= 0 && pos < NT_) list[i1*NT_ + pos] = t*2 + 1;
  }
}

__global__ __launch_bounds__(256) void k_stats(const float* __restrict__ probs, const int* __restrict__ idx0buf,
                                               float* __restrict__ cnt0f, float* __restrict__ psum){
  int e = blockIdx.x; int tid = threadIdx.x;
  float sp = 0.f, sc = 0.f;
  for(int n = tid; n < NT_; n += 256){ sp += probs[n*8+e]; sc += (idx0buf[n]==e) ? 1.f : 0.f; }
  __shared__ float r1[256], r2[256];
  r1[tid] = sp; r2[tid] = sc; __syncthreads();
  for(int st=128; st>0; st>>=1){ if(tid<st){ r1[tid]+=r1[tid+st]; r2[tid]+=r2[tid+st]; } __syncthreads(); }
  if(tid==0){ psum[e] = r1[0]; cnt0f[e] = r2[0]; }
}

__global__ void k_finish(const float* __restrict__ cnt0f, const float* __restrict__ psum,
                         const int* __restrict__ cnt, int* __restrict__ offs,
                         bf16* __restrict__ auxb, float* __restrict__ auxf, const int* __restrict__ flag){
  if(threadIdx.x==0 && blockIdx.x==0){
    int o = 0;
    for(int e=0;e<8;e++){ offs[e] = o; int c = cnt[e]; if(c < 0) c = 0; if(c > NT_) c = NT_; o += c; }
    float aux = 0.f;
    for(int e=0;e<8;e++) aux += (cnt0f[e]*(1.f/(float)NT_))*(psum[e]*(1.f/(float)NT_));
    float v = aux*0.01f*8.f;
    if(flag[0]) auxb[0] = f2b(v); else auxf[0] = v;
  }
}

__global__ __launch_bounds__(256) void k_combine(const float* __restrict__ hbuf, const bf16* __restrict__ eosl,
                                                 const float* __restrict__ p01,
                                                 bf16* __restrict__ outb, float* __restrict__ outf,
                                                 const int* __restrict__ flag){
  int t = blockIdx.x; int tid = threadIdx.x;
  int isbf = flag[0];
  float p0 = p01[t*2], p1 = p01[t*2+1];
  #pragma unroll
  for(int i=0;i<4;i++){
    int d = tid + i*256;
    float v = hbuf[(size_t)t*D_ + d]
            + p0*b2f(eosl[((size_t)(t*2))*D_ + d])
            + p1*b2f(eosl[((size_t)(t*2+1))*D_ + d]);
    size_t o = (size_t)t*D_ + d;
    if(isbf) outb[o] = f2b(v); else outf[o] = v;
  }
}

// ---------------- workspace (bytes), peak ~63.3 MB ----------------
static const size_t O_HBUF = 0;
static const size_t O_XNB  = 16777216;
static const size_t O_QLIN = 25165824;
static const size_t O_KLIN = 33554432;
static const size_t O_VLIN = 35651584;
static const size_t O_AOUT = 37748736;
static const size_t O_XN2B = 16777216;
static const size_t O_XN2F = 25165824;
static const size_t O_HEXP = 46137344;
static const size_t O_SHH  = 57344000;
static const size_t O_EOSL = 16777216;
static const size_t O_PROBS= 62947328;
static const size_t O_P01  = 63078400;
static const size_t O_IDX0 = 63111168;
static const size_t O_LIST = 63127552;
static const size_t O_CNT  = 63258624;
static const size_t O_CNT0 = 63258656;
static const size_t O_PSUM = 63258688;
static const size_t O_OFFS = 63258720;
static const size_t O_FLAG = 63258752;

extern "C" void kernel_launch(void* const* d_in, const int* in_sizes, int n_in,
                              void* d_out, int out_size, void* d_ws, size_t ws_size,
                              hipStream_t stream){
  (void)in_sizes; (void)n_in; (void)out_size; (void)ws_size;
  char* ws = (char*)d_ws;
  float* hbuf = (float*)(ws + O_HBUF);
  bf16* xnb   = (bf16*)(ws + O_XNB);
  bf16* qlin  = (bf16*)(ws + O_QLIN);
  bf16* klin  = (bf16*)(ws + O_KLIN);
  bf16* vlin  = (bf16*)(ws + O_VLIN);
  bf16* aout  = (bf16*)(ws + O_AOUT);
  bf16* xn2b  = (bf16*)(ws + O_XN2B);
  float* xn2f = (float*)(ws + O_XN2F);
  bf16* hexp  = (bf16*)(ws + O_HEXP);
  bf16* shh   = (bf16*)(ws + O_SHH);
  bf16* eosl  = (bf16*)(ws + O_EOSL);
  float* probs=(float*)(ws + O_PROBS);
  float* p01 = (float*)(ws + O_P01);
  int*  idx0 = (int*)(ws + O_IDX0);
  int*  list = (int*)(ws + O_LIST);
  int*  cnt  = (int*)(ws + O_CNT);
  float* cnt0f=(float*)(ws + O_CNT0);
  float* psum= (float*)(ws + O_PSUM);
  int*  offs = (int*)(ws + O_OFFS);
  int*  flg  = (int*)(ws + O_FLAG);

  bf16* outb = (bf16*)d_out;
  float* outf = (float*)d_out;
  bf16* auxb = outb + (size_t)NT_*D_;
  float* auxf = outf + (size_t)NT_*D_;

  k_detect<<<1, 64, 0, stream>>>((const uint32_t*)d_in[14], flg, cnt);

  // ---- attention block ----
  k_rms<<<NT_, 256, 0, stream>>>(d_in[0], d_in[14], xnb, nullptr, flg, 1);

  // merged QKV with fused RoPE (q: ct 0..15, k: 16..19, v: 20..23)
  k_qkv<<<dim3(24,32), 256, 0, stream>>>(xnb, d_in[3], d_in[4], d_in[5], qlin, klin, vlin,
                                         d_in[1], d_in[2], flg);

  k_attn<<<dim3(S_/64, H_, B_), 256, 0, stream>>>(qlin, klin, vlin, aout);

  k_mgemm<0,1><<<dim3(16,32), 256, 0, stream>>>(aout, d_in[6], hbuf, d_in[0], NT_, D_, D_, D_, nullptr, nullptr, nullptr, flg);

  // ---- MoE block ----
  k_rms<<<NT_, 256, 0, stream>>>(hbuf, d_in[15], xn2b, xn2f, flg, 0);

  k_router<<<NT_, 64, 0, stream>>>(xn2f, d_in[7], probs, p01, idx0, list, cnt, flg);
  k_stats<<<E_, 256, 0, stream>>>(probs, idx0, cnt0f, psum);
  k_finish<<<1, 64, 0, stream>>>(cnt0f, psum, cnt, offs, auxb, auxf, flg);

  // merged FFN1: expert tiles (y<352, XCD affinity on x) + shared tiles (y>=352)
  k_ffn1m<<<dim3(E_, 352+44), 256, 0, stream>>>(xn2b, d_in[8], d_in[10], d_in[11], d_in[13],
                                                hexp, shh, cnt, offs, list, flg);

  // merged FFN2 (BN=128, single-buffer): expert tiles (y<256) + shared tiles (y>=256)
  k_ffn2m<<<dim3(E_, 256+32), 256, 0, stream>>>(hexp, shh, d_in[9], d_in[12],
                                                eosl, hbuf, cnt, offs, list, flg);

  k_combine<<<NT_, 256, 0, stream>>>(hbuf, eosl, p01, outb, outf, flg);
}

// Round 25
// 585.946 us; speedup vs baseline: 1.1200x; 1.0540x over previous
//
#include <hip/hip_runtime.h>
#include <hip/hip_bf16.h>
#include <cstdint>

#define B_ 2
#define S_ 2048
#define D_ 1024
#define H_ 16
#define HKV_ 4
#define HD_ 64
#define E_ 8
#define HIDDEN_ 684
#define NT_ (B_*S_)
#define NEGBIG (-1e30f)

using bf16 = __hip_bfloat16;
typedef __attribute__((ext_vector_type(8))) short short8v;
typedef __attribute__((ext_vector_type(4))) short short4v;
typedef __attribute__((ext_vector_type(4))) float f32x4;

static __device__ __forceinline__ float b2f(bf16 v){ return __bfloat162float(v); }
static __device__ __forceinline__ bf16 f2b(float v){ return __float2bfloat16(v); }
static __device__ __forceinline__ short f2bs(float v){ bf16 h = f2b(v); return *reinterpret_cast<short*>(&h); }
static __device__ __forceinline__ float dload(const void* p, size_t i, int isbf){
  return isbf ? b2f(((const bf16*)p)[i]) : ((const float*)p)[i];
}

__global__ void k_detect(const uint32_t* __restrict__ g, int* __restrict__ flag, int* __restrict__ cnt){
  if(threadIdx.x == 0 && blockIdx.x == 0){
    uint32_t w0 = g[0], w1 = g[1], w2 = g[2], w3 = g[3];
    int bf;
    if(w0==0x3F803F80u && w1==0x3F803F80u && w2==0x3F803F80u && w3==0x3F803F80u) bf = 1;
    else if(w0==0x3F800000u && w1==0x3F800000u && w2==0x3F800000u && w3==0x3F800000u) bf = 0;
    else bf = 1;
    flag[0] = bf;
  }
  if(threadIdx.x < E_ && blockIdx.x == 0) cnt[threadIdx.x] = 0;
}

// ---------------- RMSNorm -> bf16 out (+ optional f32 copy for router) ----------------
__global__ __launch_bounds__(256) void k_rms(const void* __restrict__ X, const void* __restrict__ g,
                                             bf16* __restrict__ outb, float* __restrict__ outf,
                                             const int* __restrict__ flag, int xdyn){
  int isbf = flag[0]; int xb = xdyn ? isbf : 0;
  int t = blockIdx.x; int tid = threadIdx.x;
  float v[4]; float ss = 0.f;
  #pragma unroll
  for(int i=0;i<4;i++){ v[i] = dload(X, (size_t)t*D_ + tid + i*256, xb); ss += v[i]*v[i]; }
  __shared__ float red[256];
  red[tid] = ss; __syncthreads();
  for(int st=128; st>0; st>>=1){ if(tid<st) red[tid] += red[tid+st]; __syncthreads(); }
  float r = rsqrtf(red[0]*(1.f/(float)D_) + 1e-5f);
  #pragma unroll
  for(int i=0;i<4;i++){
    int d = tid + i*256;
    float val = v[i]*r*dload(g, d, isbf);
    outb[(size_t)t*D_ + d] = f2b(val);
    if(outf) outf[(size_t)t*D_ + d] = val;
  }
}

// ============ GEMM scaffolding (BM=128 BN=64 BK=32, proven) ============
#define ASTRIDE 40

static __device__ __forceinline__ f32x4 mfma16(short8v a, short8v b, f32x4 c){
  return __builtin_amdgcn_mfma_f32_16x16x32_bf16(a, b, c, 0, 0, 0);
}

// ---------------- generic GEMM (used for wo) ----------------
template<int AMAP, int OMODE>
__global__ __launch_bounds__(256) void k_mgemm(
    const bf16* __restrict__ A, const void* __restrict__ Bw, void* __restrict__ Cout,
    const void* __restrict__ resid,
    int M, int N, int K, int ldc,
    const int* __restrict__ cnt, const int* __restrict__ offs, const int* __restrict__ list,
    const int* __restrict__ flag)
{
  int isbf = flag[0];
  int e, ct, rt;
  int base = 0; size_t eoff = 0;
  if(cnt){
    e = blockIdx.x;
    int nc = (N+63)>>6;
    ct = blockIdx.y % nc; rt = blockIdx.y / nc;
    M = cnt[e]; if(M<0) M=0; if(M>NT_) M=NT_;
    base = offs[e];
    eoff = (size_t)e*(size_t)K*(size_t)N;
  } else {
    e = 0; ct = blockIdx.x; rt = blockIdx.y;
  }
  int m0 = rt*128; if(m0 >= M) return;
  int n0 = ct*64;

  __shared__ short As[2][128*ASTRIDE];
  __shared__ short Bs[2][64*ASTRIDE];
  __shared__ int rowA[128];

  int tid = threadIdx.x;
  int w = tid>>6, l = tid&63, lr = l&15, lg = l>>4;

  if(tid < 128){
    int rloc = m0 + tid;
    int ar = -1;
    if(rloc < M) ar = (AMAP==2) ? (list[e*NT_ + rloc]>>1) : (base + rloc);
    rowA[tid] = ar;
  }
  __syncthreads();

  int srow = tid>>1, skh = (tid&1)*16;
  int keya = (srow>>4)&3, kb0 = skh>>3;
  int bk = tid>>3, bnc = (tid&7)*8;
  int keyb = ((tid&7)>>1)&3;
  int bcol = (((bk>>3)^keyb)<<3) + (bk&7);
  int arow = rowA[srow];

  short8v rA0, rA1, rB;

  auto loadAB = [&](int kt){
    int k0 = kt*32;
    {
      short tmp[16];
      if(arow >= 0 && k0+skh+16 <= K){
        const short4v* src = (const short4v*)(A + (size_t)arow*K + k0 + skh);
        #pragma unroll
        for(int c=0;c<4;c++) *(short4v*)&tmp[c*4] = src[c];
      } else {
        #pragma unroll
        for(int i=0;i<16;i++){
          int gk = k0+skh+i;
          short v = 0;
          if(arow>=0 && gk<K) v = *(const short*)&A[(size_t)arow*K+gk];
          tmp[i] = v;
        }
      }
      #pragma unroll
      for(int i=0;i<8;i++){ rA0[i]=tmp[i]; rA1[i]=tmp[8+i]; }
    }
    {
      int gk = k0 + bk;
      short tmp[8];
      if(gk < K && n0+bnc+8 <= N){
        size_t bb = eoff + (size_t)gk*N + n0 + bnc;
        if(isbf){
          const short4v* src = (const short4v*)((const bf16*)Bw + bb);
          *(short4v*)&tmp[0] = src[0];
          *(short4v*)&tmp[4] = src[1];
        } else {
          const f32x4* src = (const f32x4*)((const float*)Bw + bb);
          f32x4 f0 = src[0], f1 = src[1];
          #pragma unroll
          for(int i=0;i<4;i++){ tmp[i]=f2bs(f0[i]); tmp[4+i]=f2bs(f1[i]); }
        }
      } else {
        #pragma unroll
        for(int i=0;i<8;i++){
          int gn = n0+bnc+i;
          float v = 0.f;
          if(gk<K && gn<N) v = dload(Bw, eoff + (size_t)gk*N + gn, isbf);
          tmp[i] = f2bs(v);
        }
      }
      #pragma unroll
      for(int i=0;i<8;i++) rB[i]=tmp[i];
    }
  };
  auto writeAB = [&](int buf){
    *(short8v*)&As[buf][srow*ASTRIDE + ((kb0^keya)<<3)]     = rA0;
    *(short8v*)&As[buf][srow*ASTRIDE + (((kb0+1)^keya)<<3)] = rA1;
    #pragma unroll
    for(int i=0;i<8;i++) Bs[buf][(bnc+i)*ASTRIDE + bcol] = rB[i];
  };

  f32x4 acc[2][4] = {};
  int KT = (K+31)>>5;

  loadAB(0); writeAB(0);
  __syncthreads();
  int cur = 0;
  for(int kt=0; kt<KT; ++kt){
    bool more = (kt+1 < KT);
    if(more) loadAB(kt+1);
    short8v a[2], b[4];
    #pragma unroll
    for(int fi=0;fi<2;fi++)
      a[fi] = *(const short8v*)&As[cur][(w*32+fi*16+lr)*ASTRIDE + ((lg^((w*2+fi)&3))<<3)];
    #pragma unroll
    for(int fj=0;fj<4;fj++)
      b[fj] = *(const short8v*)&Bs[cur][(fj*16+lr)*ASTRIDE + ((lg^fj)<<3)];
    #pragma unroll
    for(int fi=0;fi<2;fi++)
      #pragma unroll
      for(int fj=0;fj<4;fj++)
        acc[fi][fj] = mfma16(a[fi], b[fj], acc[fi][fj]);
    if(more){ writeAB(cur^1); cur ^= 1; }
    __syncthreads();
  }

  #pragma unroll
  for(int fi=0;fi<2;fi++){
    #pragma unroll
    for(int r=0;r<4;r++){
      int rl = m0 + w*32 + fi*16 + lg*4 + r;
      if(rl >= M) continue;
      int orow;
      if(OMODE==2){ orow = list[e*NT_ + rl]; if(orow<0||orow>=2*NT_) continue; }
      else orow = base + rl;
      #pragma unroll
      for(int fj=0;fj<4;fj++){
        int gcol = n0 + fj*16 + lr;
        if(gcol >= N) continue;
        float v = acc[fi][fj][r];
        size_t o = (size_t)orow*ldc + gcol;
        if(OMODE==1)      ((float*)Cout)[o] = v + dload(resid, o, isbf);
        else if(OMODE==2) ((bf16*)Cout)[o] = f2b(v);
        else if(OMODE==3) ((float*)Cout)[o] = ((float*)Cout)[o] + v;
        else              ((bf16*)Cout)[o] = f2b(v);
      }
    }
  }
}

// ---------------- merged QKV GEMM with fused RoPE epilogue ----------------
// Epilogue lane layout: col = n0+fj*16+lr, parity(col)=parity(lane); lanes l,l^1 hold
// the (even,odd) column pair of the SAME row -> rotate via __shfl_xor(v,1).
__global__ __launch_bounds__(256) void k_qkv(
    const bf16* __restrict__ A, const void* __restrict__ Wq, const void* __restrict__ Wk,
    const void* __restrict__ Wv, bf16* __restrict__ Oq, bf16* __restrict__ Ok, bf16* __restrict__ Ov,
    const void* __restrict__ fc, const void* __restrict__ fs,
    const int* __restrict__ flag)
{
  int isbf = flag[0];
  int ct = blockIdx.x, rt = blockIdx.y;
  const void* Bw; bf16* Cout; int N, n0;
  if(ct < 16){ Bw = Wq; Cout = Oq; N = D_;  n0 = ct*64; }
  else if(ct < 20){ Bw = Wk; Cout = Ok; N = 256; n0 = (ct-16)*64; }
  else { Bw = Wv; Cout = Ov; N = 256; n0 = (ct-20)*64; }
  const int K = D_, M = NT_;
  int m0 = rt*128;
  int dorope = (ct < 20);

  __shared__ short As[2][128*ASTRIDE];
  __shared__ short Bs[2][64*ASTRIDE];

  int tid = threadIdx.x;
  int w = tid>>6, l = tid&63, lr = l&15, lg = l>>4;

  int srow = tid>>1, skh = (tid&1)*16;
  int keya = (srow>>4)&3, kb0 = skh>>3;
  int bk = tid>>3, bnc = (tid&7)*8;
  int keyb = ((tid&7)>>1)&3;
  int bcol = (((bk>>3)^keyb)<<3) + (bk&7);
  int arow = m0 + srow;

  short8v rA0, rA1, rB;

  auto loadAB = [&](int kt){
    int k0 = kt*32;
    {
      short tmp[16];
      const short4v* src = (const short4v*)(A + (size_t)arow*K + k0 + skh);
      #pragma unroll
      for(int c=0;c<4;c++) *(short4v*)&tmp[c*4] = src[c];
      #pragma unroll
      for(int i=0;i<8;i++){ rA0[i]=tmp[i]; rA1[i]=tmp[8+i]; }
    }
    {
      int gk = k0 + bk;
      short tmp[8];
      size_t bb = (size_t)gk*N + n0 + bnc;
      if(isbf){
        const short4v* src = (const short4v*)((const bf16*)Bw + bb);
        *(short4v*)&tmp[0] = src[0];
        *(short4v*)&tmp[4] = src[1];
      } else {
        const f32x4* src = (const f32x4*)((const float*)Bw + bb);
        f32x4 f0 = src[0], f1 = src[1];
        #pragma unroll
        for(int i=0;i<4;i++){ tmp[i]=f2bs(f0[i]); tmp[4+i]=f2bs(f1[i]); }
      }
      #pragma unroll
      for(int i=0;i<8;i++) rB[i]=tmp[i];
    }
  };
  auto writeAB = [&](int buf){
    *(short8v*)&As[buf][srow*ASTRIDE + ((kb0^keya)<<3)]     = rA0;
    *(short8v*)&As[buf][srow*ASTRIDE + (((kb0+1)^keya)<<3)] = rA1;
    #pragma unroll
    for(int i=0;i<8;i++) Bs[buf][(bnc+i)*ASTRIDE + bcol] = rB[i];
  };

  f32x4 acc[2][4] = {};
  int KT = K>>5;

  loadAB(0); writeAB(0);
  __syncthreads();
  int cur = 0;
  for(int kt=0; kt<KT; ++kt){
    bool more = (kt+1 < KT);
    if(more) loadAB(kt+1);
    short8v a[2], b[4];
    #pragma unroll
    for(int fi=0;fi<2;fi++)
      a[fi] = *(const short8v*)&As[cur][(w*32+fi*16+lr)*ASTRIDE + ((lg^((w*2+fi)&3))<<3)];
    #pragma unroll
    for(int fj=0;fj<4;fj++)
      b[fj] = *(const short8v*)&Bs[cur][(fj*16+lr)*ASTRIDE + ((lg^fj)<<3)];
    #pragma unroll
    for(int fi=0;fi<2;fi++)
      #pragma unroll
      for(int fj=0;fj<4;fj++)
        acc[fi][fj] = mfma16(a[fi], b[fj], acc[fi][fj]);
    if(more){ writeAB(cur^1); cur ^= 1; }
    __syncthreads();
  }

  // epilogue (+ fused RoPE). No guards fire (exact tiling) -> all 64 lanes active at shfl.
  #pragma unroll
  for(int fi=0;fi<2;fi++){
    #pragma unroll
    for(int r=0;r<4;r++){
      int rl = m0 + w*32 + fi*16 + lg*4 + r;
      int s = rl & (S_-1);
      #pragma unroll
      for(int fj=0;fj<4;fj++){
        int gcol = n0 + fj*16 + lr;
        float v = acc[fi][fj][r];
        if(dorope){
          float partner = __shfl_xor(v, 1, 64);
          int p = (gcol & 63) >> 1;
          float c = dload(fc, s*32 + p, isbf);
          float sn = dload(fs, s*32 + p, isbf);
          if((l & 1) == 0) v = v*c - partner*sn;
          else             v = partner*sn + v*c;
        }
        Cout[(size_t)rl*N + gcol] = f2b(v);
      }
    }
  }
}

// ---------------- merged FFN1 (ct-inner, fused silu) ----------------
__global__ __launch_bounds__(256) void k_ffn1m(
    const bf16* __restrict__ A, const void* __restrict__ W1e, const void* __restrict__ W3e,
    const void* __restrict__ W1s, const void* __restrict__ W3s,
    bf16* __restrict__ OutE, bf16* __restrict__ OutS,
    const int* __restrict__ cnt, const int* __restrict__ offs, const int* __restrict__ list,
    const int* __restrict__ flag)
{
  int isbf = flag[0];
  const int K = D_, N = HIDDEN_;
  int e = blockIdx.x, y = blockIdx.y;
  int ct, rt, M, base, gat;
  const void* W1; const void* W3; bf16* Out;
  size_t eoff;
  if(y < 352){
    ct = y % 11; rt = y / 11;
    M = cnt[e]; if(M<0) M=0; if(M>NT_) M=NT_;
    base = offs[e]; gat = 1;
    W1 = W1e; W3 = W3e; Out = OutE;
    eoff = (size_t)e*(size_t)K*(size_t)N;
  } else {
    int ys = (y-352)*8 + e;
    ct = ys % 11; rt = ys / 11;
    M = NT_; base = 0; gat = 0;
    W1 = W1s; W3 = W3s; Out = OutS;
    eoff = 0;
  }
  int m0 = rt*128; if(m0 >= M) return;
  int n0 = ct*64;

  __shared__ short As[2][128*ASTRIDE];
  __shared__ short B1s[2][64*ASTRIDE];
  __shared__ short B3s[2][64*ASTRIDE];
  __shared__ int rowA[128];

  int tid = threadIdx.x;
  int w = tid>>6, l = tid&63, lr = l&15, lg = l>>4;

  if(tid < 128){
    int rloc = m0 + tid;
    int ar = -1;
    if(rloc < M) ar = gat ? (list[e*NT_ + rloc]>>1) : rloc;
    rowA[tid] = ar;
  }
  __syncthreads();

  int srow = tid>>1, skh = (tid&1)*16;
  int keya = (srow>>4)&3, kb0 = skh>>3;
  int bk = tid>>3, bnc = (tid&7)*8;
  int keyb = ((tid&7)>>1)&3;
  int bcol = (((bk>>3)^keyb)<<3) + (bk&7);
  int arow = rowA[srow];

  short8v rA0, rA1, rB1, rB3;

  auto loadB = [&](const void* Bw, int kt, short8v& rB){
    int k0 = kt*32;
    int gk = k0 + bk;
    short tmp[8];
    if(gk < K && n0+bnc+8 <= N){
      size_t bb = eoff + (size_t)gk*N + n0 + bnc;
      if(isbf){
        const short4v* src = (const short4v*)((const bf16*)Bw + bb);
        *(short4v*)&tmp[0] = src[0];
        *(short4v*)&tmp[4] = src[1];
      } else {
        const f32x4* src = (const f32x4*)((const float*)Bw + bb);
        f32x4 f0 = src[0], f1 = src[1];
        #pragma unroll
        for(int i=0;i<4;i++){ tmp[i]=f2bs(f0[i]); tmp[4+i]=f2bs(f1[i]); }
      }
    } else {
      #pragma unroll
      for(int i=0;i<8;i++){
        int gn = n0+bnc+i;
        float v = 0.f;
        if(gk<K && gn<N) v = dload(Bw, eoff + (size_t)gk*N + gn, isbf);
        tmp[i] = f2bs(v);
      }
    }
    #pragma unroll
    for(int i=0;i<8;i++) rB[i]=tmp[i];
  };
  auto loadA = [&](int kt){
    int k0 = kt*32;
    short tmp[16];
    if(arow >= 0 && k0+skh+16 <= K){
      const short4v* src = (const short4v*)(A + (size_t)arow*K + k0 + skh);
      #pragma unroll
      for(int c=0;c<4;c++) *(short4v*)&tmp[c*4] = src[c];
    } else {
      #pragma unroll
      for(int i=0;i<16;i++){
        int gk = k0+skh+i;
        short v = 0;
        if(arow>=0 && gk<K) v = *(const short*)&A[(size_t)arow*K+gk];
        tmp[i] = v;
      }
    }
    #pragma unroll
    for(int i=0;i<8;i++){ rA0[i]=tmp[i]; rA1[i]=tmp[8+i]; }
  };
  auto writeAll = [&](int buf){
    *(short8v*)&As[buf][srow*ASTRIDE + ((kb0^keya)<<3)]     = rA0;
    *(short8v*)&As[buf][srow*ASTRIDE + (((kb0+1)^keya)<<3)] = rA1;
    #pragma unroll
    for(int i=0;i<8;i++){
      B1s[buf][(bnc+i)*ASTRIDE + bcol] = rB1[i];
      B3s[buf][(bnc+i)*ASTRIDE + bcol] = rB3[i];
    }
  };

  f32x4 a1[2][4] = {}, a3[2][4] = {};
  int KT = (K+31)>>5;

  loadA(0); loadB(W1, 0, rB1); loadB(W3, 0, rB3); writeAll(0);
  __syncthreads();
  int cur = 0;
  for(int kt=0; kt<KT; ++kt){
    bool more = (kt+1 < KT);
    if(more){ loadA(kt+1); loadB(W1, kt+1, rB1); loadB(W3, kt+1, rB3); }
    short8v a[2], b1[4], b3[4];
    #pragma unroll
    for(int fi=0;fi<2;fi++)
      a[fi] = *(const short8v*)&As[cur][(w*32+fi*16+lr)*ASTRIDE + ((lg^((w*2+fi)&3))<<3)];
    #pragma unroll
    for(int fj=0;fj<4;fj++){
      b1[fj] = *(const short8v*)&B1s[cur][(fj*16+lr)*ASTRIDE + ((lg^fj)<<3)];
      b3[fj] = *(const short8v*)&B3s[cur][(fj*16+lr)*ASTRIDE + ((lg^fj)<<3)];
    }
    #pragma unroll
    for(int fi=0;fi<2;fi++)
      #pragma unroll
      for(int fj=0;fj<4;fj++){
        a1[fi][fj] = mfma16(a[fi], b1[fj], a1[fi][fj]);
        a3[fi][fj] = mfma16(a[fi], b3[fj], a3[fi][fj]);
      }
    if(more){ writeAll(cur^1); cur ^= 1; }
    __syncthreads();
  }

  #pragma unroll
  for(int fi=0;fi<2;fi++){
    #pragma unroll
    for(int r=0;r<4;r++){
      int rl = m0 + w*32 + fi*16 + lg*4 + r;
      if(rl >= M) continue;
      int orow = base + rl;
      #pragma unroll
      for(int fj=0;fj<4;fj++){
        int gcol = n0 + fj*16 + lr;
        if(gcol >= N) continue;
        float sg = a1[fi][fj][r];
        float v = (sg/(1.f+__expf(-sg))) * a3[fi][fj][r];
        Out[(size_t)orow*N + gcol] = f2b(v);
      }
    }
  }
}

// ---------------- merged FFN2: BN=128, SINGLE buffer (20.5 KB LDS, 16 MFMA/wave/step) ----------------
__global__ __launch_bounds__(256) void k_ffn2m(
    const bf16* __restrict__ Ae, const bf16* __restrict__ Ash,
    const void* __restrict__ W2e, const void* __restrict__ W2s,
    bf16* __restrict__ OutE, float* __restrict__ OutS,
    const int* __restrict__ cnt, const int* __restrict__ offs, const int* __restrict__ list,
    const int* __restrict__ flag)
{
  int isbf = flag[0];
  const int K = HIDDEN_, N = D_;
  int e = blockIdx.x, y = blockIdx.y;
  int ct, rt, M, base, exm;
  const bf16* A; const void* Bw;
  size_t eoff;
  if(y < 256){            // expert: 8 ct x 32 rt (ct-inner like r13)
    ct = y % 8; rt = y / 8;
    M = cnt[e]; if(M<0) M=0; if(M>NT_) M=NT_;
    base = offs[e]; exm = 1;
    A = Ae; Bw = W2e;
    eoff = (size_t)e*(size_t)K*(size_t)N;
  } else {                // shared: 256 tiles over 8 x-lanes
    int ys = (y-256)*8 + e;
    ct = ys % 8; rt = ys / 8;
    M = NT_; base = 0; exm = 0;
    A = Ash; Bw = W2s;
    eoff = 0;
  }
  int m0 = rt*128; if(m0 >= M) return;
  int n0 = ct*128;

  __shared__ short As[128*ASTRIDE];
  __shared__ short Bs[128*ASTRIDE];   // [col][k], 128 cols

  int tid = threadIdx.x;
  int w = tid>>6, l = tid&63, lr = l&15, lg = l>>4;

  int srow = tid>>1, skh = (tid&1)*16;
  int keya = (srow>>4)&3, kb0 = skh>>3;
  int bk = tid>>3, bnc = (tid&7)*16;        // 16 cols per thread
  int keyb = (tid&7)&3;                     // = ((bnc+i)>>4)&3 for i<16
  int bcol = (((bk>>3)^keyb)<<3) + (bk&7);
  int arow = (m0 + srow < M) ? (base + m0 + srow) : -1;

  short8v rA0, rA1, rB0v, rB1v;

  auto loadAB = [&](int kt){
    int k0 = kt*32;
    { // A (bf16), 16 k-values
      short tmp[16];
      if(arow >= 0 && k0+skh+16 <= K){
        const short4v* src = (const short4v*)(A + (size_t)arow*K + k0 + skh);
        #pragma unroll
        for(int c=0;c<4;c++) *(short4v*)&tmp[c*4] = src[c];
      } else {
        #pragma unroll
        for(int i=0;i<16;i++){
          int gk = k0+skh+i;
          short v = 0;
          if(arow>=0 && gk<K) v = *(const short*)&A[(size_t)arow*K+gk];
          tmp[i] = v;
        }
      }
      #pragma unroll
      for(int i=0;i<8;i++){ rA0[i]=tmp[i]; rA1[i]=tmp[8+i]; }
    }
    { // B: 16 cols at one k  (n0+bnc+16 <= 1024 always; guard only gk)
      int gk = k0 + bk;
      short tmp[16];
      if(gk < K){
        size_t bb = eoff + (size_t)gk*N + n0 + bnc;
        if(isbf){
          const short4v* src = (const short4v*)((const bf16*)Bw + bb);
          #pragma unroll
          for(int c=0;c<4;c++) *(short4v*)&tmp[c*4] = src[c];
        } else {
          const f32x4* src = (const f32x4*)((const float*)Bw + bb);
          #pragma unroll
          for(int c=0;c<4;c++){
            f32x4 f = src[c];
            #pragma unroll
            for(int i=0;i<4;i++) tmp[c*4+i] = f2bs(f[i]);
          }
        }
      } else {
        #pragma unroll
        for(int i=0;i<16;i++) tmp[i] = 0;
      }
      #pragma unroll
      for(int i=0;i<8;i++){ rB0v[i]=tmp[i]; rB1v[i]=tmp[8+i]; }
    }
  };
  auto writeAB = [&](){
    *(short8v*)&As[srow*ASTRIDE + ((kb0^keya)<<3)]     = rA0;
    *(short8v*)&As[srow*ASTRIDE + (((kb0+1)^keya)<<3)] = rA1;
    #pragma unroll
    for(int i=0;i<8;i++) Bs[(bnc+i)*ASTRIDE + bcol]   = rB0v[i];
    #pragma unroll
    for(int i=0;i<8;i++) Bs[(bnc+8+i)*ASTRIDE + bcol] = rB1v[i];
  };

  f32x4 acc[2][8] = {};
  int KT = (K+31)>>5;

  loadAB(0); writeAB();
  __syncthreads();
  for(int kt=0; kt<KT; ++kt){
    bool more = (kt+1 < KT);
    if(more) loadAB(kt+1);
    short8v a[2], b[8];
    #pragma unroll
    for(int fi=0;fi<2;fi++)
      a[fi] = *(const short8v*)&As[(w*32+fi*16+lr)*ASTRIDE + ((lg^((w*2+fi)&3))<<3)];
    #pragma unroll
    for(int fj=0;fj<8;fj++)
      b[fj] = *(const short8v*)&Bs[(fj*16+lr)*ASTRIDE + ((lg^(fj&3))<<3)];   // key=(col>>4)&3=fj&3 matches write
    #pragma unroll
    for(int fi=0;fi<2;fi++)
      #pragma unroll
      for(int fj=0;fj<8;fj++)
        acc[fi][fj] = mfma16(a[fi], b[fj], acc[fi][fj]);
    __syncthreads();
    if(more){ writeAB(); __syncthreads(); }
  }

  #pragma unroll
  for(int fi=0;fi<2;fi++){
    #pragma unroll
    for(int r=0;r<4;r++){
      int rl = m0 + w*32 + fi*16 + lg*4 + r;
      if(rl >= M) continue;
      if(exm){
        int orow = list[e*NT_ + rl];
        if(orow<0||orow>=2*NT_) continue;
        #pragma unroll
        for(int fj=0;fj<8;fj++){
          int gcol = n0 + fj*16 + lr;
          OutE[(size_t)orow*N + gcol] = f2b(acc[fi][fj][r]);
        }
      } else {
        #pragma unroll
        for(int fj=0;fj<8;fj++){
          int gcol = n0 + fj*16 + lr;
          size_t o = (size_t)rl*N + gcol;
          OutS[o] = OutS[o] + acc[fi][fj][r];
        }
      }
    }
  }
}

#define TST 72

// K/V register-prefetch: tile kt+1's global loads issue BEFORE kt's compute,
// publish to LDS after the post-compute barrier. Same 2 barriers/iter, same LDS,
// same data into same slots — only load timing changes (proven loadAB/writeAB idiom).
__global__ __launch_bounds__(256) void k_attn(const bf16* __restrict__ Q, const bf16* __restrict__ Kg,
                                              const bf16* __restrict__ V, bf16* __restrict__ Out){
  int qt_ = (S_/64 - 1) - blockIdx.x;
  int h = blockIdx.y, b = blockIdx.z;
  int kvh = h>>2;
  const bf16* qb = Q + (size_t)b*S_*D_ + h*HD_;
  const bf16* kb = Kg + (size_t)b*S_*256 + kvh*HD_;
  const bf16* vb = V  + (size_t)b*S_*256 + kvh*HD_;
  __shared__ short Qs[64*TST];
  __shared__ short Ks[64*TST];
  __shared__ short Vt[64*TST];
  __shared__ short Ps[4][16*TST];
  int tid = threadIdx.x;
  int w = tid>>6, l = tid&63, lr = l&15, lg = l>>4;
  int sr = tid>>2, sc0 = (tid&3)*16;
  int vc = (((sr>>3)^(tid&3))<<3) + (sr&7);

  {
    const short8v* src = (const short8v*)(qb + (size_t)(qt_*64 + sr)*D_ + sc0);
    *(short8v*)&Qs[sr*TST + sc0]     = src[0];
    *(short8v*)&Qs[sr*TST + sc0 + 8] = src[1];
  }
  __syncthreads();
  short8v aQ0 = *(const short8v*)&Qs[(w*16+lr)*TST + lg*8];
  short8v aQ1 = *(const short8v*)&Qs[(w*16+lr)*TST + lg*8 + 32];

  short8v rK0, rK1, rV0, rV1;
  auto loadKV = [&](int kt){
    const short8v* ksrc = (const short8v*)(kb + (size_t)(kt*64 + sr)*256 + sc0);
    rK0 = ksrc[0]; rK1 = ksrc[1];
    const short8v* vsrc = (const short8v*)(vb + (size_t)(kt*64 + sr)*256 + sc0);
    rV0 = vsrc[0]; rV1 = vsrc[1];
  };
  auto writeKV = [&](){
    *(short8v*)&Ks[sr*TST + sc0]     = rK0;
    *(short8v*)&Ks[sr*TST + sc0 + 8] = rK1;
    #pragma unroll
    for(int i=0;i<8;i++){
      Vt[(sc0+i)*TST + vc]   = rV0[i];
      Vt[(sc0+8+i)*TST + vc] = rV1[i];
    }
  };

  float mreg[4], lreg[4];
  f32x4 accO[4] = {};
  #pragma unroll
  for(int r=0;r<4;r++){ mreg[r] = NEGBIG; lreg[r] = 0.f; }

  loadKV(0); writeKV();
  __syncthreads();
  for(int kt=0; kt<=qt_; ++kt){
    bool more = (kt < qt_);
    if(more) loadKV(kt+1);        // global latency hides under compute below
    f32x4 s[4];
    #pragma unroll
    for(int fj=0; fj<4; fj++){
      short8v b0 = *(const short8v*)&Ks[(fj*16+lr)*TST + lg*8];
      short8v b1 = *(const short8v*)&Ks[(fj*16+lr)*TST + lg*8 + 32];
      f32x4 z = {};
      z = mfma16(aQ0, b0, z);
      z = mfma16(aQ1, b1, z);
      s[fj] = z;
    }
    #pragma unroll
    for(int fj=0; fj<4; fj++)
      #pragma unroll
      for(int r=0;r<4;r++){
        float v = s[fj][r]*0.125f;
        if(kt==qt_ && (fj*16+lr) > (w*16+lg*4+r)) v = NEGBIG;
        s[fj][r] = v;
      }
    float p[4][4], sc[4];
    #pragma unroll
    for(int r=0;r<4;r++){
      float mx = fmaxf(fmaxf(s[0][r],s[1][r]), fmaxf(s[2][r],s[3][r]));
      mx = fmaxf(mx, __shfl_xor(mx,1,64));
      mx = fmaxf(mx, __shfl_xor(mx,2,64));
      mx = fmaxf(mx, __shfl_xor(mx,4,64));
      mx = fmaxf(mx, __shfl_xor(mx,8,64));
      float mn = fmaxf(mreg[r], mx);
      sc[r] = __expf(mreg[r]-mn);
      float ps = 0.f;
      #pragma unroll
      for(int fj=0;fj<4;fj++){ float pv = __expf(s[fj][r]-mn); p[fj][r] = pv; ps += pv; }
      ps += __shfl_xor(ps,1,64); ps += __shfl_xor(ps,2,64);
      ps += __shfl_xor(ps,4,64); ps += __shfl_xor(ps,8,64);
      lreg[r] = lreg[r]*sc[r] + ps;
      mreg[r] = mn;
    }
    #pragma unroll
    for(int fj=0;fj<4;fj++)
      #pragma unroll
      for(int r=0;r<4;r++)
        accO[fj][r] *= sc[r];
    #pragma unroll
    for(int fj=0;fj<4;fj++)
      #pragma unroll
      for(int r=0;r<4;r++)
        Ps[w][(lg*4+r)*TST + fj*16+lr] = f2bs(p[fj][r]);
    short8v a0 = *(const short8v*)&Ps[w][lr*TST + lg*8];
    short8v a1 = *(const short8v*)&Ps[w][lr*TST + lg*8 + 32];
    #pragma unroll
    for(int fj=0;fj<4;fj++){
      int row = fj*16+lr;
      short8v b0 = *(const short8v*)&Vt[row*TST + ((lg^fj)<<3)];
      short8v b1 = *(const short8v*)&Vt[row*TST + (((lg^fj)+4)<<3)];
      accO[fj] = mfma16(a0, b0, accO[fj]);
      accO[fj] = mfma16(a1, b1, accO[fj]);
    }
    __syncthreads();                 // all reads of Ks/Vt done
    if(more){ writeKV(); __syncthreads(); }   // publish tile kt+1
  }
  #pragma unroll
  for(int r=0;r<4;r++){
    int qr = qt_*64 + w*16 + lg*4 + r;
    float inv = (lreg[r] > 0.f) ? 1.f/lreg[r] : 0.f;
    #pragma unroll
    for(int fj=0;fj<4;fj++)
      Out[((size_t)(b*S_+qr))*D_ + h*HD_ + fj*16+lr] = f2b(accO[fj][r]*inv);
  }
}

__global__ __launch_bounds__(64) void k_router(const float* __restrict__ X, const void* __restrict__ W,
                                               float* __restrict__ probs, float* __restrict__ p01,
                                               int* __restrict__ idx0buf, int* __restrict__ list,
                                               int* __restrict__ cnt, const int* __restrict__ flag){
  int isbf = flag[0];
  int t = blockIdx.x; int lane = threadIdx.x;
  float pe[8] = {};
  if(isbf){
    const bf16* Wb = (const bf16*)W;
    for(int d = lane; d < D_; d += 64){
      float xv = X[(size_t)t*D_ + d];
      #pragma unroll
      for(int e=0;e<8;e++) pe[e] += xv*b2f(Wb[(size_t)d*E_+e]);
    }
  } else {
    const float* Wf = (const float*)W;
    for(int d = lane; d < D_; d += 64){
      float xv = X[(size_t)t*D_ + d];
      #pragma unroll
      for(int e=0;e<8;e++) pe[e] += xv*Wf[(size_t)d*E_+e];
    }
  }
  for(int msk=1;msk<64;msk<<=1)
    #pragma unroll
    for(int e=0;e<8;e++) pe[e] += __shfl_xor(pe[e], msk, 64);
  if(lane == 0){
    float mx = pe[0];
    #pragma unroll
    for(int e=1;e<8;e++) mx = fmaxf(mx, pe[e]);
    float pr[8], sum = 0.f;
    #pragma unroll
    for(int e=0;e<8;e++){ pr[e] = __expf(pe[e]-mx); sum += pr[e]; }
    #pragma unroll
    for(int e=0;e<8;e++){ pr[e] /= sum; probs[t*8+e] = pr[e]; }
    int i0 = 0;
    #pragma unroll
    for(int e=1;e<8;e++) if(pe[e] > pe[i0]) i0 = e;
    int i1 = -1;
    #pragma unroll
    for(int e=0;e<8;e++){ if(e==i0) continue; if(i1<0 || pe[e] > pe[i1]) i1 = e; }
    p01[t*2]   = pr[i0];
    p01[t*2+1] = pr[i1];
    idx0buf[t] = i0;
    int pos = atomicAdd(&cnt[i0], 1);
    if(pos >= 0 && pos < NT_) list[i0*NT_ + pos] = t*2;
    pos     = atomicAdd(&cnt[i1], 1);
    if(pos >= 0 && pos < NT_) list[i1*NT_ + pos] = t*2 + 1;
  }
}

__global__ __launch_bounds__(256) void k_stats(const float* __restrict__ probs, const int* __restrict__ idx0buf,
                                               float* __restrict__ cnt0f, float* __restrict__ psum){
  int e = blockIdx.x; int tid = threadIdx.x;
  float sp = 0.f, sc = 0.f;
  for(int n = tid; n < NT_; n += 256){ sp += probs[n*8+e]; sc += (idx0buf[n]==e) ? 1.f : 0.f; }
  __shared__ float r1[256], r2[256];
  r1[tid] = sp; r2[tid] = sc; __syncthreads();
  for(int st=128; st>0; st>>=1){ if(tid<st){ r1[tid]+=r1[tid+st]; r2[tid]+=r2[tid+st]; } __syncthreads(); }
  if(tid==0){ psum[e] = r1[0]; cnt0f[e] = r2[0]; }
}

__global__ void k_finish(const float* __restrict__ cnt0f, const float* __restrict__ psum,
                         const int* __restrict__ cnt, int* __restrict__ offs,
                         bf16* __restrict__ auxb, float* __restrict__ auxf, const int* __restrict__ flag){
  if(threadIdx.x==0 && blockIdx.x==0){
    int o = 0;
    for(int e=0;e<8;e++){ offs[e] = o; int c = cnt[e]; if(c < 0) c = 0; if(c > NT_) c = NT_; o += c; }
    float aux = 0.f;
    for(int e=0;e<8;e++) aux += (cnt0f[e]*(1.f/(float)NT_))*(psum[e]*(1.f/(float)NT_));
    float v = aux*0.01f*8.f;
    if(flag[0]) auxb[0] = f2b(v); else auxf[0] = v;
  }
}

__global__ __launch_bounds__(256) void k_combine(const float* __restrict__ hbuf, const bf16* __restrict__ eosl,
                                                 const float* __restrict__ p01,
                                                 bf16* __restrict__ outb, float* __restrict__ outf,
                                                 const int* __restrict__ flag){
  int t = blockIdx.x; int tid = threadIdx.x;
  int isbf = flag[0];
  float p0 = p01[t*2], p1 = p01[t*2+1];
  #pragma unroll
  for(int i=0;i<4;i++){
    int d = tid + i*256;
    float v = hbuf[(size_t)t*D_ + d]
            + p0*b2f(eosl[((size_t)(t*2))*D_ + d])
            + p1*b2f(eosl[((size_t)(t*2+1))*D_ + d]);
    size_t o = (size_t)t*D_ + d;
    if(isbf) outb[o] = f2b(v); else outf[o] = v;
  }
}

// ---------------- workspace (bytes), peak ~63.3 MB ----------------
static const size_t O_HBUF = 0;
static const size_t O_XNB  = 16777216;
static const size_t O_QLIN = 25165824;
static const size_t O_KLIN = 33554432;
static const size_t O_VLIN = 35651584;
static const size_t O_AOUT = 37748736;
static const size_t O_XN2B = 16777216;
static const size_t O_XN2F = 25165824;
static const size_t O_HEXP = 46137344;
static const size_t O_SHH  = 57344000;
static const size_t O_EOSL = 16777216;
static const size_t O_PROBS= 62947328;
static const size_t O_P01  = 63078400;
static const size_t O_IDX0 = 63111168;
static const size_t O_LIST = 63127552;
static const size_t O_CNT  = 63258624;
static const size_t O_CNT0 = 63258656;
static const size_t O_PSUM = 63258688;
static const size_t O_OFFS = 63258720;
static const size_t O_FLAG = 63258752;

extern "C" void kernel_launch(void* const* d_in, const int* in_sizes, int n_in,
                              void* d_out, int out_size, void* d_ws, size_t ws_size,
                              hipStream_t stream){
  (void)in_sizes; (void)n_in; (void)out_size; (void)ws_size;
  char* ws = (char*)d_ws;
  float* hbuf = (float*)(ws + O_HBUF);
  bf16* xnb   = (bf16*)(ws + O_XNB);
  bf16* qlin  = (bf16*)(ws + O_QLIN);
  bf16* klin  = (bf16*)(ws + O_KLIN);
  bf16* vlin  = (bf16*)(ws + O_VLIN);
  bf16* aout  = (bf16*)(ws + O_AOUT);
  bf16* xn2b  = (bf16*)(ws + O_XN2B);
  float* xn2f = (float*)(ws + O_XN2F);
  bf16* hexp  = (bf16*)(ws + O_HEXP);
  bf16* shh   = (bf16*)(ws + O_SHH);
  bf16* eosl  = (bf16*)(ws + O_EOSL);
  float* probs=(float*)(ws + O_PROBS);
  float* p01 = (float*)(ws + O_P01);
  int*  idx0 = (int*)(ws + O_IDX0);
  int*  list = (int*)(ws + O_LIST);
  int*  cnt  = (int*)(ws + O_CNT);
  float* cnt0f=(float*)(ws + O_CNT0);
  float* psum= (float*)(ws + O_PSUM);
  int*  offs = (int*)(ws + O_OFFS);
  int*  flg  = (int*)(ws + O_FLAG);

  bf16* outb = (bf16*)d_out;
  float* outf = (float*)d_out;
  bf16* auxb = outb + (size_t)NT_*D_;
  float* auxf = outf + (size_t)NT_*D_;

  k_detect<<<1, 64, 0, stream>>>((const uint32_t*)d_in[14], flg, cnt);

  // ---- attention block ----
  k_rms<<<NT_, 256, 0, stream>>>(d_in[0], d_in[14], xnb, nullptr, flg, 1);

  // merged QKV with fused RoPE (q: ct 0..15, k: 16..19, v: 20..23)
  k_qkv<<<dim3(24,32), 256, 0, stream>>>(xnb, d_in[3], d_in[4], d_in[5], qlin, klin, vlin,
                                         d_in[1], d_in[2], flg);

  k_attn<<<dim3(S_/64, H_, B_), 256, 0, stream>>>(qlin, klin, vlin, aout);

  k_mgemm<0,1><<<dim3(16,32), 256, 0, stream>>>(aout, d_in[6], hbuf, d_in[0], NT_, D_, D_, D_, nullptr, nullptr, nullptr, flg);

  // ---- MoE block ----
  k_rms<<<NT_, 256, 0, stream>>>(hbuf, d_in[15], xn2b, xn2f, flg, 0);

  k_router<<<NT_, 64, 0, stream>>>(xn2f, d_in[7], probs, p01, idx0, list, cnt, flg);
  k_stats<<<E_, 256, 0, stream>>>(probs, idx0, cnt0f, psum);
  k_finish<<<1, 64, 0, stream>>>(cnt0f, psum, cnt, offs, auxb, auxf, flg);

  // merged FFN1: expert tiles (y<352, XCD affinity on x) + shared tiles (y>=352)
  k_ffn1m<<<dim3(E_, 352+44), 256, 0, stream>>>(xn2b, d_in[8], d_in[10], d_in[11], d_in[13],
                                                hexp, shh, cnt, offs, list, flg);

  // merged FFN2 (BN=128, single-buffer): expert tiles (y<256) + shared tiles (y>=256)
  k_ffn2m<<<dim3(E_, 256+32), 256, 0, stream>>>(hexp, shh, d_in[9], d_in[12],
                                                eosl, hbuf, cnt, offs, list, flg);

  k_combine<<<NT_, 256, 0, stream>>>(hbuf, eosl, p01, outb, outf, flg);
}

// Round 26
// 539.014 us; speedup vs baseline: 1.2176x; 1.0871x over previous
//
#include <hip/hip_runtime.h>
#include <hip/hip_bf16.h>
#include <cstdint>

#define B_ 2
#define S_ 2048
#define D_ 1024
#define H_ 16
#define HKV_ 4
#define HD_ 64
#define E_ 8
#define HIDDEN_ 684
#define NT_ (B_*S_)
#define NEGBIG (-1e30f)

using bf16 = __hip_bfloat16;
typedef __attribute__((ext_vector_type(8))) short short8v;
typedef __attribute__((ext_vector_type(4))) short short4v;
typedef __attribute__((ext_vector_type(4))) float f32x4;

static __device__ __forceinline__ float b2f(bf16 v){ return __bfloat162float(v); }
static __device__ __forceinline__ bf16 f2b(float v){ return __float2bfloat16(v); }
static __device__ __forceinline__ short f2bs(float v){ bf16 h = f2b(v); return *reinterpret_cast<short*>(&h); }
static __device__ __forceinline__ float dload(const void* p, size_t i, int isbf){
  return isbf ? b2f(((const bf16*)p)[i]) : ((const float*)p)[i];
}

__global__ void k_detect(const uint32_t* __restrict__ g, int* __restrict__ flag, int* __restrict__ cnt){
  if(threadIdx.x == 0 && blockIdx.x == 0){
    uint32_t w0 = g[0], w1 = g[1], w2 = g[2], w3 = g[3];
    int bf;
    if(w0==0x3F803F80u && w1==0x3F803F80u && w2==0x3F803F80u && w3==0x3F803F80u) bf = 1;
    else if(w0==0x3F800000u && w1==0x3F800000u && w2==0x3F800000u && w3==0x3F800000u) bf = 0;
    else bf = 1;
    flag[0] = bf;
  }
  if(threadIdx.x < E_ && blockIdx.x == 0) cnt[threadIdx.x] = 0;
}

// ---------------- RMSNorm -> bf16 out (+ optional f32 copy for router) ----------------
__global__ __launch_bounds__(256) void k_rms(const void* __restrict__ X, const void* __restrict__ g,
                                             bf16* __restrict__ outb, float* __restrict__ outf,
                                             const int* __restrict__ flag, int xdyn){
  int isbf = flag[0]; int xb = xdyn ? isbf : 0;
  int t = blockIdx.x; int tid = threadIdx.x;
  float v[4]; float ss = 0.f;
  #pragma unroll
  for(int i=0;i<4;i++){ v[i] = dload(X, (size_t)t*D_ + tid + i*256, xb); ss += v[i]*v[i]; }
  __shared__ float red[256];
  red[tid] = ss; __syncthreads();
  for(int st=128; st>0; st>>=1){ if(tid<st) red[tid] += red[tid+st]; __syncthreads(); }
  float r = rsqrtf(red[0]*(1.f/(float)D_) + 1e-5f);
  #pragma unroll
  for(int i=0;i<4;i++){
    int d = tid + i*256;
    float val = v[i]*r*dload(g, d, isbf);
    outb[(size_t)t*D_ + d] = f2b(val);
    if(outf) outf[(size_t)t*D_ + d] = val;
  }
}

// ============ GEMM scaffolding (BM=128 BN=64 BK=32, proven) ============
#define ASTRIDE 40

static __device__ __forceinline__ f32x4 mfma16(short8v a, short8v b, f32x4 c){
  return __builtin_amdgcn_mfma_f32_16x16x32_bf16(a, b, c, 0, 0, 0);
}

// ---------------- generic GEMM (used for wo) ----------------
template<int AMAP, int OMODE>
__global__ __launch_bounds__(256) void k_mgemm(
    const bf16* __restrict__ A, const void* __restrict__ Bw, void* __restrict__ Cout,
    const void* __restrict__ resid,
    int M, int N, int K, int ldc,
    const int* __restrict__ cnt, const int* __restrict__ offs, const int* __restrict__ list,
    const int* __restrict__ flag)
{
  int isbf = flag[0];
  int e, ct, rt;
  int base = 0; size_t eoff = 0;
  if(cnt){
    e = blockIdx.x;
    int nc = (N+63)>>6;
    ct = blockIdx.y % nc; rt = blockIdx.y / nc;
    M = cnt[e]; if(M<0) M=0; if(M>NT_) M=NT_;
    base = offs[e];
    eoff = (size_t)e*(size_t)K*(size_t)N;
  } else {
    e = 0; ct = blockIdx.x; rt = blockIdx.y;
  }
  int m0 = rt*128; if(m0 >= M) return;
  int n0 = ct*64;

  __shared__ short As[2][128*ASTRIDE];
  __shared__ short Bs[2][64*ASTRIDE];
  __shared__ int rowA[128];

  int tid = threadIdx.x;
  int w = tid>>6, l = tid&63, lr = l&15, lg = l>>4;

  if(tid < 128){
    int rloc = m0 + tid;
    int ar = -1;
    if(rloc < M) ar = (AMAP==2) ? (list[e*NT_ + rloc]>>1) : (base + rloc);
    rowA[tid] = ar;
  }
  __syncthreads();

  int srow = tid>>1, skh = (tid&1)*16;
  int keya = (srow>>4)&3, kb0 = skh>>3;
  int bk = tid>>3, bnc = (tid&7)*8;
  int keyb = ((tid&7)>>1)&3;
  int bcol = (((bk>>3)^keyb)<<3) + (bk&7);
  int arow = rowA[srow];

  short8v rA0, rA1, rB;

  auto loadAB = [&](int kt){
    int k0 = kt*32;
    {
      short tmp[16];
      if(arow >= 0 && k0+skh+16 <= K){
        const short4v* src = (const short4v*)(A + (size_t)arow*K + k0 + skh);
        #pragma unroll
        for(int c=0;c<4;c++) *(short4v*)&tmp[c*4] = src[c];
      } else {
        #pragma unroll
        for(int i=0;i<16;i++){
          int gk = k0+skh+i;
          short v = 0;
          if(arow>=0 && gk<K) v = *(const short*)&A[(size_t)arow*K+gk];
          tmp[i] = v;
        }
      }
      #pragma unroll
      for(int i=0;i<8;i++){ rA0[i]=tmp[i]; rA1[i]=tmp[8+i]; }
    }
    {
      int gk = k0 + bk;
      short tmp[8];
      if(gk < K && n0+bnc+8 <= N){
        size_t bb = eoff + (size_t)gk*N + n0 + bnc;
        if(isbf){
          const short4v* src = (const short4v*)((const bf16*)Bw + bb);
          *(short4v*)&tmp[0] = src[0];
          *(short4v*)&tmp[4] = src[1];
        } else {
          const f32x4* src = (const f32x4*)((const float*)Bw + bb);
          f32x4 f0 = src[0], f1 = src[1];
          #pragma unroll
          for(int i=0;i<4;i++){ tmp[i]=f2bs(f0[i]); tmp[4+i]=f2bs(f1[i]); }
        }
      } else {
        #pragma unroll
        for(int i=0;i<8;i++){
          int gn = n0+bnc+i;
          float v = 0.f;
          if(gk<K && gn<N) v = dload(Bw, eoff + (size_t)gk*N + gn, isbf);
          tmp[i] = f2bs(v);
        }
      }
      #pragma unroll
      for(int i=0;i<8;i++) rB[i]=tmp[i];
    }
  };
  auto writeAB = [&](int buf){
    *(short8v*)&As[buf][srow*ASTRIDE + ((kb0^keya)<<3)]     = rA0;
    *(short8v*)&As[buf][srow*ASTRIDE + (((kb0+1)^keya)<<3)] = rA1;
    #pragma unroll
    for(int i=0;i<8;i++) Bs[buf][(bnc+i)*ASTRIDE + bcol] = rB[i];
  };

  f32x4 acc[2][4] = {};
  int KT = (K+31)>>5;

  loadAB(0); writeAB(0);
  __syncthreads();
  int cur = 0;
  for(int kt=0; kt<KT; ++kt){
    bool more = (kt+1 < KT);
    if(more) loadAB(kt+1);
    short8v a[2], b[4];
    #pragma unroll
    for(int fi=0;fi<2;fi++)
      a[fi] = *(const short8v*)&As[cur][(w*32+fi*16+lr)*ASTRIDE + ((lg^((w*2+fi)&3))<<3)];
    #pragma unroll
    for(int fj=0;fj<4;fj++)
      b[fj] = *(const short8v*)&Bs[cur][(fj*16+lr)*ASTRIDE + ((lg^fj)<<3)];
    #pragma unroll
    for(int fi=0;fi<2;fi++)
      #pragma unroll
      for(int fj=0;fj<4;fj++)
        acc[fi][fj] = mfma16(a[fi], b[fj], acc[fi][fj]);
    if(more){ writeAB(cur^1); cur ^= 1; }
    __syncthreads();
  }

  #pragma unroll
  for(int fi=0;fi<2;fi++){
    #pragma unroll
    for(int r=0;r<4;r++){
      int rl = m0 + w*32 + fi*16 + lg*4 + r;
      if(rl >= M) continue;
      int orow;
      if(OMODE==2){ orow = list[e*NT_ + rl]; if(orow<0||orow>=2*NT_) continue; }
      else orow = base + rl;
      #pragma unroll
      for(int fj=0;fj<4;fj++){
        int gcol = n0 + fj*16 + lr;
        if(gcol >= N) continue;
        float v = acc[fi][fj][r];
        size_t o = (size_t)orow*ldc + gcol;
        if(OMODE==1)      ((float*)Cout)[o] = v + dload(resid, o, isbf);
        else if(OMODE==2) ((bf16*)Cout)[o] = f2b(v);
        else if(OMODE==3) ((float*)Cout)[o] = ((float*)Cout)[o] + v;
        else              ((bf16*)Cout)[o] = f2b(v);
      }
    }
  }
}

// ---------------- merged QKV GEMM with fused RoPE epilogue ----------------
// Epilogue lane layout: col = n0+fj*16+lr, parity(col)=parity(lane); lanes l,l^1 hold
// the (even,odd) column pair of the SAME row -> rotate via __shfl_xor(v,1).
__global__ __launch_bounds__(256) void k_qkv(
    const bf16* __restrict__ A, const void* __restrict__ Wq, const void* __restrict__ Wk,
    const void* __restrict__ Wv, bf16* __restrict__ Oq, bf16* __restrict__ Ok, bf16* __restrict__ Ov,
    const void* __restrict__ fc, const void* __restrict__ fs,
    const int* __restrict__ flag)
{
  int isbf = flag[0];
  int ct = blockIdx.x, rt = blockIdx.y;
  const void* Bw; bf16* Cout; int N, n0;
  if(ct < 16){ Bw = Wq; Cout = Oq; N = D_;  n0 = ct*64; }
  else if(ct < 20){ Bw = Wk; Cout = Ok; N = 256; n0 = (ct-16)*64; }
  else { Bw = Wv; Cout = Ov; N = 256; n0 = (ct-20)*64; }
  const int K = D_, M = NT_;
  int m0 = rt*128;
  int dorope = (ct < 20);

  __shared__ short As[2][128*ASTRIDE];
  __shared__ short Bs[2][64*ASTRIDE];

  int tid = threadIdx.x;
  int w = tid>>6, l = tid&63, lr = l&15, lg = l>>4;

  int srow = tid>>1, skh = (tid&1)*16;
  int keya = (srow>>4)&3, kb0 = skh>>3;
  int bk = tid>>3, bnc = (tid&7)*8;
  int keyb = ((tid&7)>>1)&3;
  int bcol = (((bk>>3)^keyb)<<3) + (bk&7);
  int arow = m0 + srow;

  short8v rA0, rA1, rB;

  auto loadAB = [&](int kt){
    int k0 = kt*32;
    {
      short tmp[16];
      const short4v* src = (const short4v*)(A + (size_t)arow*K + k0 + skh);
      #pragma unroll
      for(int c=0;c<4;c++) *(short4v*)&tmp[c*4] = src[c];
      #pragma unroll
      for(int i=0;i<8;i++){ rA0[i]=tmp[i]; rA1[i]=tmp[8+i]; }
    }
    {
      int gk = k0 + bk;
      short tmp[8];
      size_t bb = (size_t)gk*N + n0 + bnc;
      if(isbf){
        const short4v* src = (const short4v*)((const bf16*)Bw + bb);
        *(short4v*)&tmp[0] = src[0];
        *(short4v*)&tmp[4] = src[1];
      } else {
        const f32x4* src = (const f32x4*)((const float*)Bw + bb);
        f32x4 f0 = src[0], f1 = src[1];
        #pragma unroll
        for(int i=0;i<4;i++){ tmp[i]=f2bs(f0[i]); tmp[4+i]=f2bs(f1[i]); }
      }
      #pragma unroll
      for(int i=0;i<8;i++) rB[i]=tmp[i];
    }
  };
  auto writeAB = [&](int buf){
    *(short8v*)&As[buf][srow*ASTRIDE + ((kb0^keya)<<3)]     = rA0;
    *(short8v*)&As[buf][srow*ASTRIDE + (((kb0+1)^keya)<<3)] = rA1;
    #pragma unroll
    for(int i=0;i<8;i++) Bs[buf][(bnc+i)*ASTRIDE + bcol] = rB[i];
  };

  f32x4 acc[2][4] = {};
  int KT = K>>5;

  loadAB(0); writeAB(0);
  __syncthreads();
  int cur = 0;
  for(int kt=0; kt<KT; ++kt){
    bool more = (kt+1 < KT);
    if(more) loadAB(kt+1);
    short8v a[2], b[4];
    #pragma unroll
    for(int fi=0;fi<2;fi++)
      a[fi] = *(const short8v*)&As[cur][(w*32+fi*16+lr)*ASTRIDE + ((lg^((w*2+fi)&3))<<3)];
    #pragma unroll
    for(int fj=0;fj<4;fj++)
      b[fj] = *(const short8v*)&Bs[cur][(fj*16+lr)*ASTRIDE + ((lg^fj)<<3)];
    #pragma unroll
    for(int fi=0;fi<2;fi++)
      #pragma unroll
      for(int fj=0;fj<4;fj++)
        acc[fi][fj] = mfma16(a[fi], b[fj], acc[fi][fj]);
    if(more){ writeAB(cur^1); cur ^= 1; }
    __syncthreads();
  }

  // epilogue (+ fused RoPE). No guards fire (exact tiling) -> all 64 lanes active at shfl.
  #pragma unroll
  for(int fi=0;fi<2;fi++){
    #pragma unroll
    for(int r=0;r<4;r++){
      int rl = m0 + w*32 + fi*16 + lg*4 + r;
      int s = rl & (S_-1);
      #pragma unroll
      for(int fj=0;fj<4;fj++){
        int gcol = n0 + fj*16 + lr;
        float v = acc[fi][fj][r];
        if(dorope){
          float partner = __shfl_xor(v, 1, 64);
          int p = (gcol & 63) >> 1;
          float c = dload(fc, s*32 + p, isbf);
          float sn = dload(fs, s*32 + p, isbf);
          if((l & 1) == 0) v = v*c - partner*sn;
          else             v = partner*sn + v*c;
        }
        Cout[(size_t)rl*N + gcol] = f2b(v);
      }
    }
  }
}

// ---------------- merged FFN1 (ct-inner, fused silu) ----------------
__global__ __launch_bounds__(256) void k_ffn1m(
    const bf16* __restrict__ A, const void* __restrict__ W1e, const void* __restrict__ W3e,
    const void* __restrict__ W1s, const void* __restrict__ W3s,
    bf16* __restrict__ OutE, bf16* __restrict__ OutS,
    const int* __restrict__ cnt, const int* __restrict__ offs, const int* __restrict__ list,
    const int* __restrict__ flag)
{
  int isbf = flag[0];
  const int K = D_, N = HIDDEN_;
  int e = blockIdx.x, y = blockIdx.y;
  int ct, rt, M, base, gat;
  const void* W1; const void* W3; bf16* Out;
  size_t eoff;
  if(y < 352){
    ct = y % 11; rt = y / 11;
    M = cnt[e]; if(M<0) M=0; if(M>NT_) M=NT_;
    base = offs[e]; gat = 1;
    W1 = W1e; W3 = W3e; Out = OutE;
    eoff = (size_t)e*(size_t)K*(size_t)N;
  } else {
    int ys = (y-352)*8 + e;
    ct = ys % 11; rt = ys / 11;
    M = NT_; base = 0; gat = 0;
    W1 = W1s; W3 = W3s; Out = OutS;
    eoff = 0;
  }
  int m0 = rt*128; if(m0 >= M) return;
  int n0 = ct*64;

  __shared__ short As[2][128*ASTRIDE];
  __shared__ short B1s[2][64*ASTRIDE];
  __shared__ short B3s[2][64*ASTRIDE];
  __shared__ int rowA[128];

  int tid = threadIdx.x;
  int w = tid>>6, l = tid&63, lr = l&15, lg = l>>4;

  if(tid < 128){
    int rloc = m0 + tid;
    int ar = -1;
    if(rloc < M) ar = gat ? (list[e*NT_ + rloc]>>1) : rloc;
    rowA[tid] = ar;
  }
  __syncthreads();

  int srow = tid>>1, skh = (tid&1)*16;
  int keya = (srow>>4)&3, kb0 = skh>>3;
  int bk = tid>>3, bnc = (tid&7)*8;
  int keyb = ((tid&7)>>1)&3;
  int bcol = (((bk>>3)^keyb)<<3) + (bk&7);
  int arow = rowA[srow];

  short8v rA0, rA1, rB1, rB3;

  auto loadB = [&](const void* Bw, int kt, short8v& rB){
    int k0 = kt*32;
    int gk = k0 + bk;
    short tmp[8];
    if(gk < K && n0+bnc+8 <= N){
      size_t bb = eoff + (size_t)gk*N + n0 + bnc;
      if(isbf){
        const short4v* src = (const short4v*)((const bf16*)Bw + bb);
        *(short4v*)&tmp[0] = src[0];
        *(short4v*)&tmp[4] = src[1];
      } else {
        const f32x4* src = (const f32x4*)((const float*)Bw + bb);
        f32x4 f0 = src[0], f1 = src[1];
        #pragma unroll
        for(int i=0;i<4;i++){ tmp[i]=f2bs(f0[i]); tmp[4+i]=f2bs(f1[i]); }
      }
    } else {
      #pragma unroll
      for(int i=0;i<8;i++){
        int gn = n0+bnc+i;
        float v = 0.f;
        if(gk<K && gn<N) v = dload(Bw, eoff + (size_t)gk*N + gn, isbf);
        tmp[i] = f2bs(v);
      }
    }
    #pragma unroll
    for(int i=0;i<8;i++) rB[i]=tmp[i];
  };
  auto loadA = [&](int kt){
    int k0 = kt*32;
    short tmp[16];
    if(arow >= 0 && k0+skh+16 <= K){
      const short4v* src = (const short4v*)(A + (size_t)arow*K + k0 + skh);
      #pragma unroll
      for(int c=0;c<4;c++) *(short4v*)&tmp[c*4] = src[c];
    } else {
      #pragma unroll
      for(int i=0;i<16;i++){
        int gk = k0+skh+i;
        short v = 0;
        if(arow>=0 && gk<K) v = *(const short*)&A[(size_t)arow*K+gk];
        tmp[i] = v;
      }
    }
    #pragma unroll
    for(int i=0;i<8;i++){ rA0[i]=tmp[i]; rA1[i]=tmp[8+i]; }
  };
  auto writeAll = [&](int buf){
    *(short8v*)&As[buf][srow*ASTRIDE + ((kb0^keya)<<3)]     = rA0;
    *(short8v*)&As[buf][srow*ASTRIDE + (((kb0+1)^keya)<<3)] = rA1;
    #pragma unroll
    for(int i=0;i<8;i++){
      B1s[buf][(bnc+i)*ASTRIDE + bcol] = rB1[i];
      B3s[buf][(bnc+i)*ASTRIDE + bcol] = rB3[i];
    }
  };

  f32x4 a1[2][4] = {}, a3[2][4] = {};
  int KT = (K+31)>>5;

  loadA(0); loadB(W1, 0, rB1); loadB(W3, 0, rB3); writeAll(0);
  __syncthreads();
  int cur = 0;
  for(int kt=0; kt<KT; ++kt){
    bool more = (kt+1 < KT);
    if(more){ loadA(kt+1); loadB(W1, kt+1, rB1); loadB(W3, kt+1, rB3); }
    short8v a[2], b1[4], b3[4];
    #pragma unroll
    for(int fi=0;fi<2;fi++)
      a[fi] = *(const short8v*)&As[cur][(w*32+fi*16+lr)*ASTRIDE + ((lg^((w*2+fi)&3))<<3)];
    #pragma unroll
    for(int fj=0;fj<4;fj++){
      b1[fj] = *(const short8v*)&B1s[cur][(fj*16+lr)*ASTRIDE + ((lg^fj)<<3)];
      b3[fj] = *(const short8v*)&B3s[cur][(fj*16+lr)*ASTRIDE + ((lg^fj)<<3)];
    }
    #pragma unroll
    for(int fi=0;fi<2;fi++)
      #pragma unroll
      for(int fj=0;fj<4;fj++){
        a1[fi][fj] = mfma16(a[fi], b1[fj], a1[fi][fj]);
        a3[fi][fj] = mfma16(a[fi], b3[fj], a3[fi][fj]);
      }
    if(more){ writeAll(cur^1); cur ^= 1; }
    __syncthreads();
  }

  #pragma unroll
  for(int fi=0;fi<2;fi++){
    #pragma unroll
    for(int r=0;r<4;r++){
      int rl = m0 + w*32 + fi*16 + lg*4 + r;
      if(rl >= M) continue;
      int orow = base + rl;
      #pragma unroll
      for(int fj=0;fj<4;fj++){
        int gcol = n0 + fj*16 + lr;
        if(gcol >= N) continue;
        float sg = a1[fi][fj][r];
        float v = (sg/(1.f+__expf(-sg))) * a3[fi][fj][r];
        Out[(size_t)orow*N + gcol] = f2b(v);
      }
    }
  }
}

// ---------------- merged FFN2: BN=128, SINGLE buffer (20.5 KB LDS, 16 MFMA/wave/step) ----------------
__global__ __launch_bounds__(256) void k_ffn2m(
    const bf16* __restrict__ Ae, const bf16* __restrict__ Ash,
    const void* __restrict__ W2e, const void* __restrict__ W2s,
    bf16* __restrict__ OutE, float* __restrict__ OutS,
    const int* __restrict__ cnt, const int* __restrict__ offs, const int* __restrict__ list,
    const int* __restrict__ flag)
{
  int isbf = flag[0];
  const int K = HIDDEN_, N = D_;
  int e = blockIdx.x, y = blockIdx.y;
  int ct, rt, M, base, exm;
  const bf16* A; const void* Bw;
  size_t eoff;
  if(y < 256){            // expert: 8 ct x 32 rt (ct-inner like r13)
    ct = y % 8; rt = y / 8;
    M = cnt[e]; if(M<0) M=0; if(M>NT_) M=NT_;
    base = offs[e]; exm = 1;
    A = Ae; Bw = W2e;
    eoff = (size_t)e*(size_t)K*(size_t)N;
  } else {                // shared: 256 tiles over 8 x-lanes
    int ys = (y-256)*8 + e;
    ct = ys % 8; rt = ys / 8;
    M = NT_; base = 0; exm = 0;
    A = Ash; Bw = W2s;
    eoff = 0;
  }
  int m0 = rt*128; if(m0 >= M) return;
  int n0 = ct*128;

  __shared__ short As[128*ASTRIDE];
  __shared__ short Bs[128*ASTRIDE];   // [col][k], 128 cols

  int tid = threadIdx.x;
  int w = tid>>6, l = tid&63, lr = l&15, lg = l>>4;

  int srow = tid>>1, skh = (tid&1)*16;
  int keya = (srow>>4)&3, kb0 = skh>>3;
  int bk = tid>>3, bnc = (tid&7)*16;        // 16 cols per thread
  int keyb = (tid&7)&3;                     // = ((bnc+i)>>4)&3 for i<16
  int bcol = (((bk>>3)^keyb)<<3) + (bk&7);
  int arow = (m0 + srow < M) ? (base + m0 + srow) : -1;

  short8v rA0, rA1, rB0v, rB1v;

  auto loadAB = [&](int kt){
    int k0 = kt*32;
    { // A (bf16), 16 k-values
      short tmp[16];
      if(arow >= 0 && k0+skh+16 <= K){
        const short4v* src = (const short4v*)(A + (size_t)arow*K + k0 + skh);
        #pragma unroll
        for(int c=0;c<4;c++) *(short4v*)&tmp[c*4] = src[c];
      } else {
        #pragma unroll
        for(int i=0;i<16;i++){
          int gk = k0+skh+i;
          short v = 0;
          if(arow>=0 && gk<K) v = *(const short*)&A[(size_t)arow*K+gk];
          tmp[i] = v;
        }
      }
      #pragma unroll
      for(int i=0;i<8;i++){ rA0[i]=tmp[i]; rA1[i]=tmp[8+i]; }
    }
    { // B: 16 cols at one k  (n0+bnc+16 <= 1024 always; guard only gk)
      int gk = k0 + bk;
      short tmp[16];
      if(gk < K){
        size_t bb = eoff + (size_t)gk*N + n0 + bnc;
        if(isbf){
          const short4v* src = (const short4v*)((const bf16*)Bw + bb);
          #pragma unroll
          for(int c=0;c<4;c++) *(short4v*)&tmp[c*4] = src[c];
        } else {
          const f32x4* src = (const f32x4*)((const float*)Bw + bb);
          #pragma unroll
          for(int c=0;c<4;c++){
            f32x4 f = src[c];
            #pragma unroll
            for(int i=0;i<4;i++) tmp[c*4+i] = f2bs(f[i]);
          }
        }
      } else {
        #pragma unroll
        for(int i=0;i<16;i++) tmp[i] = 0;
      }
      #pragma unroll
      for(int i=0;i<8;i++){ rB0v[i]=tmp[i]; rB1v[i]=tmp[8+i]; }
    }
  };
  auto writeAB = [&](){
    *(short8v*)&As[srow*ASTRIDE + ((kb0^keya)<<3)]     = rA0;
    *(short8v*)&As[srow*ASTRIDE + (((kb0+1)^keya)<<3)] = rA1;
    #pragma unroll
    for(int i=0;i<8;i++) Bs[(bnc+i)*ASTRIDE + bcol]   = rB0v[i];
    #pragma unroll
    for(int i=0;i<8;i++) Bs[(bnc+8+i)*ASTRIDE + bcol] = rB1v[i];
  };

  f32x4 acc[2][8] = {};
  int KT = (K+31)>>5;

  loadAB(0); writeAB();
  __syncthreads();
  for(int kt=0; kt<KT; ++kt){
    bool more = (kt+1 < KT);
    if(more) loadAB(kt+1);
    short8v a[2], b[8];
    #pragma unroll
    for(int fi=0;fi<2;fi++)
      a[fi] = *(const short8v*)&As[(w*32+fi*16+lr)*ASTRIDE + ((lg^((w*2+fi)&3))<<3)];
    #pragma unroll
    for(int fj=0;fj<8;fj++)
      b[fj] = *(const short8v*)&Bs[(fj*16+lr)*ASTRIDE + ((lg^(fj&3))<<3)];   // key=(col>>4)&3=fj&3 matches write
    #pragma unroll
    for(int fi=0;fi<2;fi++)
      #pragma unroll
      for(int fj=0;fj<8;fj++)
        acc[fi][fj] = mfma16(a[fi], b[fj], acc[fi][fj]);
    __syncthreads();
    if(more){ writeAB(); __syncthreads(); }
  }

  #pragma unroll
  for(int fi=0;fi<2;fi++){
    #pragma unroll
    for(int r=0;r<4;r++){
      int rl = m0 + w*32 + fi*16 + lg*4 + r;
      if(rl >= M) continue;
      if(exm){
        int orow = list[e*NT_ + rl];
        if(orow<0||orow>=2*NT_) continue;
        #pragma unroll
        for(int fj=0;fj<8;fj++){
          int gcol = n0 + fj*16 + lr;
          OutE[(size_t)orow*N + gcol] = f2b(acc[fi][fj][r]);
        }
      } else {
        #pragma unroll
        for(int fj=0;fj<8;fj++){
          int gcol = n0 + fj*16 + lr;
          size_t o = (size_t)rl*N + gcol;
          OutS[o] = OutS[o] + acc[fi][fj][r];
        }
      }
    }
  }
}

#define TST 72

// K/V register-prefetch (r25 winner) + XCD-aware block remap:
// 1D grid of 1024; xcd = L&7 selects (b,kvh) so all 128 blocks sharing one 2MB
// KV set land on ONE XCD -> set fits 4MB L2 (was 16MB working set/XCD = thrash).
// Longest qt still launches first within each XCD. Pure remap: correctness invariant.
__global__ __launch_bounds__(256) void k_attn(const bf16* __restrict__ Q, const bf16* __restrict__ Kg,
                                              const bf16* __restrict__ V, bf16* __restrict__ Out){
  int L = blockIdx.x;
  int xcd = L & 7;
  int j = L >> 3;            // 0..127
  int b = xcd >> 2;          // 0..1
  int kvh = xcd & 3;         // 0..3
  int h = kvh*4 + (j & 3);   // h>>2 == kvh
  int qt_ = (S_/64 - 1) - (j >> 2);
  const bf16* qb = Q + (size_t)b*S_*D_ + h*HD_;
  const bf16* kb = Kg + (size_t)b*S_*256 + kvh*HD_;
  const bf16* vb = V  + (size_t)b*S_*256 + kvh*HD_;
  __shared__ short Qs[64*TST];
  __shared__ short Ks[64*TST];
  __shared__ short Vt[64*TST];
  __shared__ short Ps[4][16*TST];
  int tid = threadIdx.x;
  int w = tid>>6, l = tid&63, lr = l&15, lg = l>>4;
  int sr = tid>>2, sc0 = (tid&3)*16;
  int vc = (((sr>>3)^(tid&3))<<3) + (sr&7);

  {
    const short8v* src = (const short8v*)(qb + (size_t)(qt_*64 + sr)*D_ + sc0);
    *(short8v*)&Qs[sr*TST + sc0]     = src[0];
    *(short8v*)&Qs[sr*TST + sc0 + 8] = src[1];
  }
  __syncthreads();
  short8v aQ0 = *(const short8v*)&Qs[(w*16+lr)*TST + lg*8];
  short8v aQ1 = *(const short8v*)&Qs[(w*16+lr)*TST + lg*8 + 32];

  short8v rK0, rK1, rV0, rV1;
  auto loadKV = [&](int kt){
    const short8v* ksrc = (const short8v*)(kb + (size_t)(kt*64 + sr)*256 + sc0);
    rK0 = ksrc[0]; rK1 = ksrc[1];
    const short8v* vsrc = (const short8v*)(vb + (size_t)(kt*64 + sr)*256 + sc0);
    rV0 = vsrc[0]; rV1 = vsrc[1];
  };
  auto writeKV = [&](){
    *(short8v*)&Ks[sr*TST + sc0]     = rK0;
    *(short8v*)&Ks[sr*TST + sc0 + 8] = rK1;
    #pragma unroll
    for(int i=0;i<8;i++){
      Vt[(sc0+i)*TST + vc]   = rV0[i];
      Vt[(sc0+8+i)*TST + vc] = rV1[i];
    }
  };

  float mreg[4], lreg[4];
  f32x4 accO[4] = {};
  #pragma unroll
  for(int r=0;r<4;r++){ mreg[r] = NEGBIG; lreg[r] = 0.f; }

  loadKV(0); writeKV();
  __syncthreads();
  for(int kt=0; kt<=qt_; ++kt){
    bool more = (kt < qt_);
    if(more) loadKV(kt+1);        // global latency hides under compute below
    f32x4 s[4];
    #pragma unroll
    for(int fj=0; fj<4; fj++){
      short8v b0 = *(const short8v*)&Ks[(fj*16+lr)*TST + lg*8];
      short8v b1 = *(const short8v*)&Ks[(fj*16+lr)*TST + lg*8 + 32];
      f32x4 z = {};
      z = mfma16(aQ0, b0, z);
      z = mfma16(aQ1, b1, z);
      s[fj] = z;
    }
    #pragma unroll
    for(int fj=0; fj<4; fj++)
      #pragma unroll
      for(int r=0;r<4;r++){
        float v = s[fj][r]*0.125f;
        if(kt==qt_ && (fj*16+lr) > (w*16+lg*4+r)) v = NEGBIG;
        s[fj][r] = v;
      }
    float p[4][4], sc[4];
    #pragma unroll
    for(int r=0;r<4;r++){
      float mx = fmaxf(fmaxf(s[0][r],s[1][r]), fmaxf(s[2][r],s[3][r]));
      mx = fmaxf(mx, __shfl_xor(mx,1,64));
      mx = fmaxf(mx, __shfl_xor(mx,2,64));
      mx = fmaxf(mx, __shfl_xor(mx,4,64));
      mx = fmaxf(mx, __shfl_xor(mx,8,64));
      float mn = fmaxf(mreg[r], mx);
      sc[r] = __expf(mreg[r]-mn);
      float ps = 0.f;
      #pragma unroll
      for(int fj=0;fj<4;fj++){ float pv = __expf(s[fj][r]-mn); p[fj][r] = pv; ps += pv; }
      ps += __shfl_xor(ps,1,64); ps += __shfl_xor(ps,2,64);
      ps += __shfl_xor(ps,4,64); ps += __shfl_xor(ps,8,64);
      lreg[r] = lreg[r]*sc[r] + ps;
      mreg[r] = mn;
    }
    #pragma unroll
    for(int fj=0;fj<4;fj++)
      #pragma unroll
      for(int r=0;r<4;r++)
        accO[fj][r] *= sc[r];
    #pragma unroll
    for(int fj=0;fj<4;fj++)
      #pragma unroll
      for(int r=0;r<4;r++)
        Ps[w][(lg*4+r)*TST + fj*16+lr] = f2bs(p[fj][r]);
    short8v a0 = *(const short8v*)&Ps[w][lr*TST + lg*8];
    short8v a1 = *(const short8v*)&Ps[w][lr*TST + lg*8 + 32];
    #pragma unroll
    for(int fj=0;fj<4;fj++){
      int row = fj*16+lr;
      short8v b0 = *(const short8v*)&Vt[row*TST + ((lg^fj)<<3)];
      short8v b1 = *(const short8v*)&Vt[row*TST + (((lg^fj)+4)<<3)];
      accO[fj] = mfma16(a0, b0, accO[fj]);
      accO[fj] = mfma16(a1, b1, accO[fj]);
    }
    __syncthreads();                 // all reads of Ks/Vt done
    if(more){ writeKV(); __syncthreads(); }   // publish tile kt+1
  }
  #pragma unroll
  for(int r=0;r<4;r++){
    int qr = qt_*64 + w*16 + lg*4 + r;
    float inv = (lreg[r] > 0.f) ? 1.f/lreg[r] : 0.f;
    #pragma unroll
    for(int fj=0;fj<4;fj++)
      Out[((size_t)(b*S_+qr))*D_ + h*HD_ + fj*16+lr] = f2b(accO[fj][r]*inv);
  }
}

__global__ __launch_bounds__(64) void k_router(const float* __restrict__ X, const void* __restrict__ W,
                                               float* __restrict__ probs, float* __restrict__ p01,
                                               int* __restrict__ idx0buf, int* __restrict__ list,
                                               int* __restrict__ cnt, const int* __restrict__ flag){
  int isbf = flag[0];
  int t = blockIdx.x; int lane = threadIdx.x;
  float pe[8] = {};
  if(isbf){
    const bf16* Wb = (const bf16*)W;
    for(int d = lane; d < D_; d += 64){
      float xv = X[(size_t)t*D_ + d];
      #pragma unroll
      for(int e=0;e<8;e++) pe[e] += xv*b2f(Wb[(size_t)d*E_+e]);
    }
  } else {
    const float* Wf = (const float*)W;
    for(int d = lane; d < D_; d += 64){
      float xv = X[(size_t)t*D_ + d];
      #pragma unroll
      for(int e=0;e<8;e++) pe[e] += xv*Wf[(size_t)d*E_+e];
    }
  }
  for(int msk=1;msk<64;msk<<=1)
    #pragma unroll
    for(int e=0;e<8;e++) pe[e] += __shfl_xor(pe[e], msk, 64);
  if(lane == 0){
    float mx = pe[0];
    #pragma unroll
    for(int e=1;e<8;e++) mx = fmaxf(mx, pe[e]);
    float pr[8], sum = 0.f;
    #pragma unroll
    for(int e=0;e<8;e++){ pr[e] = __expf(pe[e]-mx); sum += pr[e]; }
    #pragma unroll
    for(int e=0;e<8;e++){ pr[e] /= sum; probs[t*8+e] = pr[e]; }
    int i0 = 0;
    #pragma unroll
    for(int e=1;e<8;e++) if(pe[e] > pe[i0]) i0 = e;
    int i1 = -1;
    #pragma unroll
    for(int e=0;e<8;e++){ if(e==i0) continue; if(i1<0 || pe[e] > pe[i1]) i1 = e; }
    p01[t*2]   = pr[i0];
    p01[t*2+1] = pr[i1];
    idx0buf[t] = i0;
    int pos = atomicAdd(&cnt[i0], 1);
    if(pos >= 0 && pos < NT_) list[i0*NT_ + pos] = t*2;
    pos     = atomicAdd(&cnt[i1], 1);
    if(pos >= 0 && pos < NT_) list[i1*NT_ + pos] = t*2 + 1;
  }
}

__global__ __launch_bounds__(256) void k_stats(const float* __restrict__ probs, const int* __restrict__ idx0buf,
                                               float* __restrict__ cnt0f, float* __restrict__ psum){
  int e = blockIdx.x; int tid = threadIdx.x;
  float sp = 0.f, sc = 0.f;
  for(int n = tid; n < NT_; n += 256){ sp += probs[n*8+e]; sc += (idx0buf[n]==e) ? 1.f : 0.f; }
  __shared__ float r1[256], r2[256];
  r1[tid] = sp; r2[tid] = sc; __syncthreads();
  for(int st=128; st>0; st>>=1){ if(tid<st){ r1[tid]+=r1[tid+st]; r2[tid]+=r2[tid+st]; } __syncthreads(); }
  if(tid==0){ psum[e] = r1[0]; cnt0f[e] = r2[0]; }
}

__global__ void k_finish(const float* __restrict__ cnt0f, const float* __restrict__ psum,
                         const int* __restrict__ cnt, int* __restrict__ offs,
                         bf16* __restrict__ auxb, float* __restrict__ auxf, const int* __restrict__ flag){
  if(threadIdx.x==0 && blockIdx.x==0){
    int o = 0;
    for(int e=0;e<8;e++){ offs[e] = o; int c = cnt[e]; if(c < 0) c = 0; if(c > NT_) c = NT_; o += c; }
    float aux = 0.f;
    for(int e=0;e<8;e++) aux += (cnt0f[e]*(1.f/(float)NT_))*(psum[e]*(1.f/(float)NT_));
    float v = aux*0.01f*8.f;
    if(flag[0]) auxb[0] = f2b(v); else auxf[0] = v;
  }
}

__global__ __launch_bounds__(256) void k_combine(const float* __restrict__ hbuf, const bf16* __restrict__ eosl,
                                                 const float* __restrict__ p01,
                                                 bf16* __restrict__ outb, float* __restrict__ outf,
                                                 const int* __restrict__ flag){
  int t = blockIdx.x; int tid = threadIdx.x;
  int isbf = flag[0];
  float p0 = p01[t*2], p1 = p01[t*2+1];
  #pragma unroll
  for(int i=0;i<4;i++){
    int d = tid + i*256;
    float v = hbuf[(size_t)t*D_ + d]
            + p0*b2f(eosl[((size_t)(t*2))*D_ + d])
            + p1*b2f(eosl[((size_t)(t*2+1))*D_ + d]);
    size_t o = (size_t)t*D_ + d;
    if(isbf) outb[o] = f2b(v); else outf[o] = v;
  }
}

// ---------------- workspace (bytes), peak ~63.3 MB ----------------
static const size_t O_HBUF = 0;
static const size_t O_XNB  = 16777216;
static const size_t O_QLIN = 25165824;
static const size_t O_KLIN = 33554432;
static const size_t O_VLIN = 35651584;
static const size_t O_AOUT = 37748736;
static const size_t O_XN2B = 16777216;
static const size_t O_XN2F = 25165824;
static const size_t O_HEXP = 46137344;
static const size_t O_SHH  = 57344000;
static const size_t O_EOSL = 16777216;
static const size_t O_PROBS= 62947328;
static const size_t O_P01  = 63078400;
static const size_t O_IDX0 = 63111168;
static const size_t O_LIST = 63127552;
static const size_t O_CNT  = 63258624;
static const size_t O_CNT0 = 63258656;
static const size_t O_PSUM = 63258688;
static const size_t O_OFFS = 63258720;
static const size_t O_FLAG = 63258752;

extern "C" void kernel_launch(void* const* d_in, const int* in_sizes, int n_in,
                              void* d_out, int out_size, void* d_ws, size_t ws_size,
                              hipStream_t stream){
  (void)in_sizes; (void)n_in; (void)out_size; (void)ws_size;
  char* ws = (char*)d_ws;
  float* hbuf = (float*)(ws + O_HBUF);
  bf16* xnb   = (bf16*)(ws + O_XNB);
  bf16* qlin  = (bf16*)(ws + O_QLIN);
  bf16* klin  = (bf16*)(ws + O_KLIN);
  bf16* vlin  = (bf16*)(ws + O_VLIN);
  bf16* aout  = (bf16*)(ws + O_AOUT);
  bf16* xn2b  = (bf16*)(ws + O_XN2B);
  float* xn2f = (float*)(ws + O_XN2F);
  bf16* hexp  = (bf16*)(ws + O_HEXP);
  bf16* shh   = (bf16*)(ws + O_SHH);
  bf16* eosl  = (bf16*)(ws + O_EOSL);
  float* probs=(float*)(ws + O_PROBS);
  float* p01 = (float*)(ws + O_P01);
  int*  idx0 = (int*)(ws + O_IDX0);
  int*  list = (int*)(ws + O_LIST);
  int*  cnt  = (int*)(ws + O_CNT);
  float* cnt0f=(float*)(ws + O_CNT0);
  float* psum= (float*)(ws + O_PSUM);
  int*  offs = (int*)(ws + O_OFFS);
  int*  flg  = (int*)(ws + O_FLAG);

  bf16* outb = (bf16*)d_out;
  float* outf = (float*)d_out;
  bf16* auxb = outb + (size_t)NT_*D_;
  float* auxf = outf + (size_t)NT_*D_;

  k_detect<<<1, 64, 0, stream>>>((const uint32_t*)d_in[14], flg, cnt);

  // ---- attention block ----
  k_rms<<<NT_, 256, 0, stream>>>(d_in[0], d_in[14], xnb, nullptr, flg, 1);

  // merged QKV with fused RoPE (q: ct 0..15, k: 16..19, v: 20..23)
  k_qkv<<<dim3(24,32), 256, 0, stream>>>(xnb, d_in[3], d_in[4], d_in[5], qlin, klin, vlin,
                                         d_in[1], d_in[2], flg);

  // XCD-remapped 1D grid: 1024 blocks, (b,kvh) = L&7 -> per-XCD KV locality
  k_attn<<<dim3(S_/64 * H_ * B_), 256, 0, stream>>>(qlin, klin, vlin, aout);

  k_mgemm<0,1><<<dim3(16,32), 256, 0, stream>>>(aout, d_in[6], hbuf, d_in[0], NT_, D_, D_, D_, nullptr, nullptr, nullptr, flg);

  // ---- MoE block ----
  k_rms<<<NT_, 256, 0, stream>>>(hbuf, d_in[15], xn2b, xn2f, flg, 0);

  k_router<<<NT_, 64, 0, stream>>>(xn2f, d_in[7], probs, p01, idx0, list, cnt, flg);
  k_stats<<<E_, 256, 0, stream>>>(probs, idx0, cnt0f, psum);
  k_finish<<<1, 64, 0, stream>>>(cnt0f, psum, cnt, offs, auxb, auxf, flg);

  // merged FFN1: expert tiles (y<352, XCD affinity on x) + shared tiles (y>=352)
  k_ffn1m<<<dim3(E_, 352+44), 256, 0, stream>>>(xn2b, d_in[8], d_in[10], d_in[11], d_in[13],
                                                hexp, shh, cnt, offs, list, flg);

  // merged FFN2 (BN=128, single-buffer): expert tiles (y<256) + shared tiles (y>=256)
  k_ffn2m<<<dim3(E_, 256+32), 256, 0, stream>>>(hexp, shh, d_in[9], d_in[12],
                                                eosl, hbuf, cnt, offs, list, flg);

  k_combine<<<NT_, 256, 0, stream>>>(hbuf, eosl, p01, outb, outf, flg);
}

// Round 27
// 538.604 us; speedup vs baseline: 1.2185x; 1.0008x over previous
//
#include <hip/hip_runtime.h>
#include <hip/hip_bf16.h>
#include <cstdint>

#define B_ 2
#define S_ 2048
#define D_ 1024
#define H_ 16
#define HKV_ 4
#define HD_ 64
#define E_ 8
#define HIDDEN_ 684
#define NT_ (B_*S_)
#define NEGBIG (-1e30f)

using bf16 = __hip_bfloat16;
typedef __attribute__((ext_vector_type(8))) short short8v;
typedef __attribute__((ext_vector_type(4))) short short4v;
typedef __attribute__((ext_vector_type(4))) float f32x4;

static __device__ __forceinline__ float b2f(bf16 v){ return __bfloat162float(v); }
static __device__ __forceinline__ bf16 f2b(float v){ return __float2bfloat16(v); }
static __device__ __forceinline__ short f2bs(float v){ bf16 h = f2b(v); return *reinterpret_cast<short*>(&h); }
static __device__ __forceinline__ float dload(const void* p, size_t i, int isbf){
  return isbf ? b2f(((const bf16*)p)[i]) : ((const float*)p)[i];
}

__global__ void k_detect(const uint32_t* __restrict__ g, int* __restrict__ flag, int* __restrict__ cnt){
  if(threadIdx.x == 0 && blockIdx.x == 0){
    uint32_t w0 = g[0], w1 = g[1], w2 = g[2], w3 = g[3];
    int bf;
    if(w0==0x3F803F80u && w1==0x3F803F80u && w2==0x3F803F80u && w3==0x3F803F80u) bf = 1;
    else if(w0==0x3F800000u && w1==0x3F800000u && w2==0x3F800000u && w3==0x3F800000u) bf = 0;
    else bf = 1;
    flag[0] = bf;
  }
  if(threadIdx.x < E_ && blockIdx.x == 0) cnt[threadIdx.x] = 0;
}

// ---------------- RMSNorm -> bf16 out (+ optional f32 copy for router) ----------------
__global__ __launch_bounds__(256) void k_rms(const void* __restrict__ X, const void* __restrict__ g,
                                             bf16* __restrict__ outb, float* __restrict__ outf,
                                             const int* __restrict__ flag, int xdyn){
  int isbf = flag[0]; int xb = xdyn ? isbf : 0;
  int t = blockIdx.x; int tid = threadIdx.x;
  float v[4]; float ss = 0.f;
  #pragma unroll
  for(int i=0;i<4;i++){ v[i] = dload(X, (size_t)t*D_ + tid + i*256, xb); ss += v[i]*v[i]; }
  __shared__ float red[256];
  red[tid] = ss; __syncthreads();
  for(int st=128; st>0; st>>=1){ if(tid<st) red[tid] += red[tid+st]; __syncthreads(); }
  float r = rsqrtf(red[0]*(1.f/(float)D_) + 1e-5f);
  #pragma unroll
  for(int i=0;i<4;i++){
    int d = tid + i*256;
    float val = v[i]*r*dload(g, d, isbf);
    outb[(size_t)t*D_ + d] = f2b(val);
    if(outf) outf[(size_t)t*D_ + d] = val;
  }
}

// ============ GEMM scaffolding (BM=128 BN=64 BK=32, proven) ============
#define ASTRIDE 40

static __device__ __forceinline__ f32x4 mfma16(short8v a, short8v b, f32x4 c){
  return __builtin_amdgcn_mfma_f32_16x16x32_bf16(a, b, c, 0, 0, 0);
}

// ---------------- generic GEMM (used for wo) ----------------
// wo path (cnt==nullptr): XCD-chunked remap — each XCD gets 4 consecutive rt x all ct
// -> per-XCD working set = 1MB A + 2MB W fits 4MB L2.
template<int AMAP, int OMODE>
__global__ __launch_bounds__(256) void k_mgemm(
    const bf16* __restrict__ A, const void* __restrict__ Bw, void* __restrict__ Cout,
    const void* __restrict__ resid,
    int M, int N, int K, int ldc,
    const int* __restrict__ cnt, const int* __restrict__ offs, const int* __restrict__ list,
    const int* __restrict__ flag)
{
  int isbf = flag[0];
  int e, ct, rt;
  int base = 0; size_t eoff = 0;
  if(cnt){
    e = blockIdx.x;
    int nc = (N+63)>>6;
    ct = blockIdx.y % nc; rt = blockIdx.y / nc;
    M = cnt[e]; if(M<0) M=0; if(M>NT_) M=NT_;
    base = offs[e];
    eoff = (size_t)e*(size_t)K*(size_t)N;
  } else {
    e = 0;
    int L = blockIdx.x + blockIdx.y*gridDim.x;      // dispatch-linear index
    int wg = (L & 7)*((gridDim.x*gridDim.y)>>3) + (L >> 3);  // chunked per XCD
    ct = wg % gridDim.x; rt = wg / gridDim.x;
  }
  int m0 = rt*128; if(m0 >= M) return;
  int n0 = ct*64;

  __shared__ short As[2][128*ASTRIDE];
  __shared__ short Bs[2][64*ASTRIDE];
  __shared__ int rowA[128];

  int tid = threadIdx.x;
  int w = tid>>6, l = tid&63, lr = l&15, lg = l>>4;

  if(tid < 128){
    int rloc = m0 + tid;
    int ar = -1;
    if(rloc < M) ar = (AMAP==2) ? (list[e*NT_ + rloc]>>1) : (base + rloc);
    rowA[tid] = ar;
  }
  __syncthreads();

  int srow = tid>>1, skh = (tid&1)*16;
  int keya = (srow>>4)&3, kb0 = skh>>3;
  int bk = tid>>3, bnc = (tid&7)*8;
  int keyb = ((tid&7)>>1)&3;
  int bcol = (((bk>>3)^keyb)<<3) + (bk&7);
  int arow = rowA[srow];

  short8v rA0, rA1, rB;

  auto loadAB = [&](int kt){
    int k0 = kt*32;
    {
      short tmp[16];
      if(arow >= 0 && k0+skh+16 <= K){
        const short4v* src = (const short4v*)(A + (size_t)arow*K + k0 + skh);
        #pragma unroll
        for(int c=0;c<4;c++) *(short4v*)&tmp[c*4] = src[c];
      } else {
        #pragma unroll
        for(int i=0;i<16;i++){
          int gk = k0+skh+i;
          short v = 0;
          if(arow>=0 && gk<K) v = *(const short*)&A[(size_t)arow*K+gk];
          tmp[i] = v;
        }
      }
      #pragma unroll
      for(int i=0;i<8;i++){ rA0[i]=tmp[i]; rA1[i]=tmp[8+i]; }
    }
    {
      int gk = k0 + bk;
      short tmp[8];
      if(gk < K && n0+bnc+8 <= N){
        size_t bb = eoff + (size_t)gk*N + n0 + bnc;
        if(isbf){
          const short4v* src = (const short4v*)((const bf16*)Bw + bb);
          *(short4v*)&tmp[0] = src[0];
          *(short4v*)&tmp[4] = src[1];
        } else {
          const f32x4* src = (const f32x4*)((const float*)Bw + bb);
          f32x4 f0 = src[0], f1 = src[1];
          #pragma unroll
          for(int i=0;i<4;i++){ tmp[i]=f2bs(f0[i]); tmp[4+i]=f2bs(f1[i]); }
        }
      } else {
        #pragma unroll
        for(int i=0;i<8;i++){
          int gn = n0+bnc+i;
          float v = 0.f;
          if(gk<K && gn<N) v = dload(Bw, eoff + (size_t)gk*N + gn, isbf);
          tmp[i] = f2bs(v);
        }
      }
      #pragma unroll
      for(int i=0;i<8;i++) rB[i]=tmp[i];
    }
  };
  auto writeAB = [&](int buf){
    *(short8v*)&As[buf][srow*ASTRIDE + ((kb0^keya)<<3)]     = rA0;
    *(short8v*)&As[buf][srow*ASTRIDE + (((kb0+1)^keya)<<3)] = rA1;
    #pragma unroll
    for(int i=0;i<8;i++) Bs[buf][(bnc+i)*ASTRIDE + bcol] = rB[i];
  };

  f32x4 acc[2][4] = {};
  int KT = (K+31)>>5;

  loadAB(0); writeAB(0);
  __syncthreads();
  int cur = 0;
  for(int kt=0; kt<KT; ++kt){
    bool more = (kt+1 < KT);
    if(more) loadAB(kt+1);
    short8v a[2], b[4];
    #pragma unroll
    for(int fi=0;fi<2;fi++)
      a[fi] = *(const short8v*)&As[cur][(w*32+fi*16+lr)*ASTRIDE + ((lg^((w*2+fi)&3))<<3)];
    #pragma unroll
    for(int fj=0;fj<4;fj++)
      b[fj] = *(const short8v*)&Bs[cur][(fj*16+lr)*ASTRIDE + ((lg^fj)<<3)];
    #pragma unroll
    for(int fi=0;fi<2;fi++)
      #pragma unroll
      for(int fj=0;fj<4;fj++)
        acc[fi][fj] = mfma16(a[fi], b[fj], acc[fi][fj]);
    if(more){ writeAB(cur^1); cur ^= 1; }
    __syncthreads();
  }

  #pragma unroll
  for(int fi=0;fi<2;fi++){
    #pragma unroll
    for(int r=0;r<4;r++){
      int rl = m0 + w*32 + fi*16 + lg*4 + r;
      if(rl >= M) continue;
      int orow;
      if(OMODE==2){ orow = list[e*NT_ + rl]; if(orow<0||orow>=2*NT_) continue; }
      else orow = base + rl;
      #pragma unroll
      for(int fj=0;fj<4;fj++){
        int gcol = n0 + fj*16 + lr;
        if(gcol >= N) continue;
        float v = acc[fi][fj][r];
        size_t o = (size_t)orow*ldc + gcol;
        if(OMODE==1)      ((float*)Cout)[o] = v + dload(resid, o, isbf);
        else if(OMODE==2) ((bf16*)Cout)[o] = f2b(v);
        else if(OMODE==3) ((float*)Cout)[o] = ((float*)Cout)[o] + v;
        else              ((bf16*)Cout)[o] = f2b(v);
      }
    }
  }
}

// ---------------- merged QKV GEMM with fused RoPE epilogue ----------------
// XCD-chunked 1D grid (768): wg=(L&7)*96+L/8 -> each XCD owns rt in [4x,4x+4) x all ct.
// Per-XCD working set: A 1MB + Wq/Wk/Wv 3MB = 4MB (fits L2). Pure bijective remap.
__global__ __launch_bounds__(256) void k_qkv(
    const bf16* __restrict__ A, const void* __restrict__ Wq, const void* __restrict__ Wk,
    const void* __restrict__ Wv, bf16* __restrict__ Oq, bf16* __restrict__ Ok, bf16* __restrict__ Ov,
    const void* __restrict__ fc, const void* __restrict__ fs,
    const int* __restrict__ flag)
{
  int isbf = flag[0];
  int L = blockIdx.x;
  int wg = (L & 7)*96 + (L >> 3);
  int ct = wg % 24, rt = wg / 24;
  const void* Bw; bf16* Cout; int N, n0;
  if(ct < 16){ Bw = Wq; Cout = Oq; N = D_;  n0 = ct*64; }
  else if(ct < 20){ Bw = Wk; Cout = Ok; N = 256; n0 = (ct-16)*64; }
  else { Bw = Wv; Cout = Ov; N = 256; n0 = (ct-20)*64; }
  const int K = D_, M = NT_;
  int m0 = rt*128;
  int dorope = (ct < 20);

  __shared__ short As[2][128*ASTRIDE];
  __shared__ short Bs[2][64*ASTRIDE];

  int tid = threadIdx.x;
  int w = tid>>6, l = tid&63, lr = l&15, lg = l>>4;

  int srow = tid>>1, skh = (tid&1)*16;
  int keya = (srow>>4)&3, kb0 = skh>>3;
  int bk = tid>>3, bnc = (tid&7)*8;
  int keyb = ((tid&7)>>1)&3;
  int bcol = (((bk>>3)^keyb)<<3) + (bk&7);
  int arow = m0 + srow;

  short8v rA0, rA1, rB;

  auto loadAB = [&](int kt){
    int k0 = kt*32;
    {
      short tmp[16];
      const short4v* src = (const short4v*)(A + (size_t)arow*K + k0 + skh);
      #pragma unroll
      for(int c=0;c<4;c++) *(short4v*)&tmp[c*4] = src[c];
      #pragma unroll
      for(int i=0;i<8;i++){ rA0[i]=tmp[i]; rA1[i]=tmp[8+i]; }
    }
    {
      int gk = k0 + bk;
      short tmp[8];
      size_t bb = (size_t)gk*N + n0 + bnc;
      if(isbf){
        const short4v* src = (const short4v*)((const bf16*)Bw + bb);
        *(short4v*)&tmp[0] = src[0];
        *(short4v*)&tmp[4] = src[1];
      } else {
        const f32x4* src = (const f32x4*)((const float*)Bw + bb);
        f32x4 f0 = src[0], f1 = src[1];
        #pragma unroll
        for(int i=0;i<4;i++){ tmp[i]=f2bs(f0[i]); tmp[4+i]=f2bs(f1[i]); }
      }
      #pragma unroll
      for(int i=0;i<8;i++) rB[i]=tmp[i];
    }
  };
  auto writeAB = [&](int buf){
    *(short8v*)&As[buf][srow*ASTRIDE + ((kb0^keya)<<3)]     = rA0;
    *(short8v*)&As[buf][srow*ASTRIDE + (((kb0+1)^keya)<<3)] = rA1;
    #pragma unroll
    for(int i=0;i<8;i++) Bs[buf][(bnc+i)*ASTRIDE + bcol] = rB[i];
  };

  f32x4 acc[2][4] = {};
  int KT = K>>5;

  loadAB(0); writeAB(0);
  __syncthreads();
  int cur = 0;
  for(int kt=0; kt<KT; ++kt){
    bool more = (kt+1 < KT);
    if(more) loadAB(kt+1);
    short8v a[2], b[4];
    #pragma unroll
    for(int fi=0;fi<2;fi++)
      a[fi] = *(const short8v*)&As[cur][(w*32+fi*16+lr)*ASTRIDE + ((lg^((w*2+fi)&3))<<3)];
    #pragma unroll
    for(int fj=0;fj<4;fj++)
      b[fj] = *(const short8v*)&Bs[cur][(fj*16+lr)*ASTRIDE + ((lg^fj)<<3)];
    #pragma unroll
    for(int fi=0;fi<2;fi++)
      #pragma unroll
      for(int fj=0;fj<4;fj++)
        acc[fi][fj] = mfma16(a[fi], b[fj], acc[fi][fj]);
    if(more){ writeAB(cur^1); cur ^= 1; }
    __syncthreads();
  }

  // epilogue (+ fused RoPE). No guards fire (exact tiling) -> all 64 lanes active at shfl.
  #pragma unroll
  for(int fi=0;fi<2;fi++){
    #pragma unroll
    for(int r=0;r<4;r++){
      int rl = m0 + w*32 + fi*16 + lg*4 + r;
      int s = rl & (S_-1);
      #pragma unroll
      for(int fj=0;fj<4;fj++){
        int gcol = n0 + fj*16 + lr;
        float v = acc[fi][fj][r];
        if(dorope){
          float partner = __shfl_xor(v, 1, 64);
          int p = (gcol & 63) >> 1;
          float c = dload(fc, s*32 + p, isbf);
          float sn = dload(fs, s*32 + p, isbf);
          if((l & 1) == 0) v = v*c - partner*sn;
          else             v = partner*sn + v*c;
        }
        Cout[(size_t)rl*N + gcol] = f2b(v);
      }
    }
  }
}

// ---------------- merged FFN1 (ct-inner, fused silu) ----------------
// Shared tiles (y>=352): XCD-chunked s=e*44+(y-352) -> XCD e owns rt in [4e,4e+4)
// x all 11 ct for the shared GEMM: A 1MB + W1s+W3s 2.8MB fits L2.
__global__ __launch_bounds__(256) void k_ffn1m(
    const bf16* __restrict__ A, const void* __restrict__ W1e, const void* __restrict__ W3e,
    const void* __restrict__ W1s, const void* __restrict__ W3s,
    bf16* __restrict__ OutE, bf16* __restrict__ OutS,
    const int* __restrict__ cnt, const int* __restrict__ offs, const int* __restrict__ list,
    const int* __restrict__ flag)
{
  int isbf = flag[0];
  const int K = D_, N = HIDDEN_;
  int e = blockIdx.x, y = blockIdx.y;
  int ct, rt, M, base, gat;
  const void* W1; const void* W3; bf16* Out;
  size_t eoff;
  if(y < 352){
    ct = y % 11; rt = y / 11;
    M = cnt[e]; if(M<0) M=0; if(M>NT_) M=NT_;
    base = offs[e]; gat = 1;
    W1 = W1e; W3 = W3e; Out = OutE;
    eoff = (size_t)e*(size_t)K*(size_t)N;
  } else {
    int s = e*44 + (y-352);
    ct = s % 11; rt = s / 11;
    M = NT_; base = 0; gat = 0;
    W1 = W1s; W3 = W3s; Out = OutS;
    eoff = 0;
  }
  int m0 = rt*128; if(m0 >= M) return;
  int n0 = ct*64;

  __shared__ short As[2][128*ASTRIDE];
  __shared__ short B1s[2][64*ASTRIDE];
  __shared__ short B3s[2][64*ASTRIDE];
  __shared__ int rowA[128];

  int tid = threadIdx.x;
  int w = tid>>6, l = tid&63, lr = l&15, lg = l>>4;

  if(tid < 128){
    int rloc = m0 + tid;
    int ar = -1;
    if(rloc < M) ar = gat ? (list[e*NT_ + rloc]>>1) : rloc;
    rowA[tid] = ar;
  }
  __syncthreads();

  int srow = tid>>1, skh = (tid&1)*16;
  int keya = (srow>>4)&3, kb0 = skh>>3;
  int bk = tid>>3, bnc = (tid&7)*8;
  int keyb = ((tid&7)>>1)&3;
  int bcol = (((bk>>3)^keyb)<<3) + (bk&7);
  int arow = rowA[srow];

  short8v rA0, rA1, rB1, rB3;

  auto loadB = [&](const void* Bw, int kt, short8v& rB){
    int k0 = kt*32;
    int gk = k0 + bk;
    short tmp[8];
    if(gk < K && n0+bnc+8 <= N){
      size_t bb = eoff + (size_t)gk*N + n0 + bnc;
      if(isbf){
        const short4v* src = (const short4v*)((const bf16*)Bw + bb);
        *(short4v*)&tmp[0] = src[0];
        *(short4v*)&tmp[4] = src[1];
      } else {
        const f32x4* src = (const f32x4*)((const float*)Bw + bb);
        f32x4 f0 = src[0], f1 = src[1];
        #pragma unroll
        for(int i=0;i<4;i++){ tmp[i]=f2bs(f0[i]); tmp[4+i]=f2bs(f1[i]); }
      }
    } else {
      #pragma unroll
      for(int i=0;i<8;i++){
        int gn = n0+bnc+i;
        float v = 0.f;
        if(gk<K && gn<N) v = dload(Bw, eoff + (size_t)gk*N + gn, isbf);
        tmp[i] = f2bs(v);
      }
    }
    #pragma unroll
    for(int i=0;i<8;i++) rB[i]=tmp[i];
  };
  auto loadA = [&](int kt){
    int k0 = kt*32;
    short tmp[16];
    if(arow >= 0 && k0+skh+16 <= K){
      const short4v* src = (const short4v*)(A + (size_t)arow*K + k0 + skh);
      #pragma unroll
      for(int c=0;c<4;c++) *(short4v*)&tmp[c*4] = src[c];
    } else {
      #pragma unroll
      for(int i=0;i<16;i++){
        int gk = k0+skh+i;
        short v = 0;
        if(arow>=0 && gk<K) v = *(const short*)&A[(size_t)arow*K+gk];
        tmp[i] = v;
      }
    }
    #pragma unroll
    for(int i=0;i<8;i++){ rA0[i]=tmp[i]; rA1[i]=tmp[8+i]; }
  };
  auto writeAll = [&](int buf){
    *(short8v*)&As[buf][srow*ASTRIDE + ((kb0^keya)<<3)]     = rA0;
    *(short8v*)&As[buf][srow*ASTRIDE + (((kb0+1)^keya)<<3)] = rA1;
    #pragma unroll
    for(int i=0;i<8;i++){
      B1s[buf][(bnc+i)*ASTRIDE + bcol] = rB1[i];
      B3s[buf][(bnc+i)*ASTRIDE + bcol] = rB3[i];
    }
  };

  f32x4 a1[2][4] = {}, a3[2][4] = {};
  int KT = (K+31)>>5;

  loadA(0); loadB(W1, 0, rB1); loadB(W3, 0, rB3); writeAll(0);
  __syncthreads();
  int cur = 0;
  for(int kt=0; kt<KT; ++kt){
    bool more = (kt+1 < KT);
    if(more){ loadA(kt+1); loadB(W1, kt+1, rB1); loadB(W3, kt+1, rB3); }
    short8v a[2], b1[4], b3[4];
    #pragma unroll
    for(int fi=0;fi<2;fi++)
      a[fi] = *(const short8v*)&As[cur][(w*32+fi*16+lr)*ASTRIDE + ((lg^((w*2+fi)&3))<<3)];
    #pragma unroll
    for(int fj=0;fj<4;fj++){
      b1[fj] = *(const short8v*)&B1s[cur][(fj*16+lr)*ASTRIDE + ((lg^fj)<<3)];
      b3[fj] = *(const short8v*)&B3s[cur][(fj*16+lr)*ASTRIDE + ((lg^fj)<<3)];
    }
    #pragma unroll
    for(int fi=0;fi<2;fi++)
      #pragma unroll
      for(int fj=0;fj<4;fj++){
        a1[fi][fj] = mfma16(a[fi], b1[fj], a1[fi][fj]);
        a3[fi][fj] = mfma16(a[fi], b3[fj], a3[fi][fj]);
      }
    if(more){ writeAll(cur^1); cur ^= 1; }
    __syncthreads();
  }

  #pragma unroll
  for(int fi=0;fi<2;fi++){
    #pragma unroll
    for(int r=0;r<4;r++){
      int rl = m0 + w*32 + fi*16 + lg*4 + r;
      if(rl >= M) continue;
      int orow = base + rl;
      #pragma unroll
      for(int fj=0;fj<4;fj++){
        int gcol = n0 + fj*16 + lr;
        if(gcol >= N) continue;
        float sg = a1[fi][fj][r];
        float v = (sg/(1.f+__expf(-sg))) * a3[fi][fj][r];
        Out[(size_t)orow*N + gcol] = f2b(v);
      }
    }
  }
}

// ---------------- merged FFN2: BN=128, SINGLE buffer (20.5 KB LDS, 16 MFMA/wave/step) ----------------
// Shared tiles (y>=256): XCD-chunked s=e*32+(y-256) -> XCD e owns rt in [4e,4e+4)
// x all 8 ct: A 1MB + W2s 1.4MB fits L2.
__global__ __launch_bounds__(256) void k_ffn2m(
    const bf16* __restrict__ Ae, const bf16* __restrict__ Ash,
    const void* __restrict__ W2e, const void* __restrict__ W2s,
    bf16* __restrict__ OutE, float* __restrict__ OutS,
    const int* __restrict__ cnt, const int* __restrict__ offs, const int* __restrict__ list,
    const int* __restrict__ flag)
{
  int isbf = flag[0];
  const int K = HIDDEN_, N = D_;
  int e = blockIdx.x, y = blockIdx.y;
  int ct, rt, M, base, exm;
  const bf16* A; const void* Bw;
  size_t eoff;
  if(y < 256){            // expert: 8 ct x 32 rt (ct-inner like r13)
    ct = y % 8; rt = y / 8;
    M = cnt[e]; if(M<0) M=0; if(M>NT_) M=NT_;
    base = offs[e]; exm = 1;
    A = Ae; Bw = W2e;
    eoff = (size_t)e*(size_t)K*(size_t)N;
  } else {                // shared: XCD-chunked
    int s = e*32 + (y-256);
    ct = s % 8; rt = s / 8;
    M = NT_; base = 0; exm = 0;
    A = Ash; Bw = W2s;
    eoff = 0;
  }
  int m0 = rt*128; if(m0 >= M) return;
  int n0 = ct*128;

  __shared__ short As[128*ASTRIDE];
  __shared__ short Bs[128*ASTRIDE];   // [col][k], 128 cols

  int tid = threadIdx.x;
  int w = tid>>6, l = tid&63, lr = l&15, lg = l>>4;

  int srow = tid>>1, skh = (tid&1)*16;
  int keya = (srow>>4)&3, kb0 = skh>>3;
  int bk = tid>>3, bnc = (tid&7)*16;        // 16 cols per thread
  int keyb = (tid&7)&3;                     // = ((bnc+i)>>4)&3 for i<16
  int bcol = (((bk>>3)^keyb)<<3) + (bk&7);
  int arow = (m0 + srow < M) ? (base + m0 + srow) : -1;

  short8v rA0, rA1, rB0v, rB1v;

  auto loadAB = [&](int kt){
    int k0 = kt*32;
    { // A (bf16), 16 k-values
      short tmp[16];
      if(arow >= 0 && k0+skh+16 <= K){
        const short4v* src = (const short4v*)(A + (size_t)arow*K + k0 + skh);
        #pragma unroll
        for(int c=0;c<4;c++) *(short4v*)&tmp[c*4] = src[c];
      } else {
        #pragma unroll
        for(int i=0;i<16;i++){
          int gk = k0+skh+i;
          short v = 0;
          if(arow>=0 && gk<K) v = *(const short*)&A[(size_t)arow*K+gk];
          tmp[i] = v;
        }
      }
      #pragma unroll
      for(int i=0;i<8;i++){ rA0[i]=tmp[i]; rA1[i]=tmp[8+i]; }
    }
    { // B: 16 cols at one k  (n0+bnc+16 <= 1024 always; guard only gk)
      int gk = k0 + bk;
      short tmp[16];
      if(gk < K){
        size_t bb = eoff + (size_t)gk*N + n0 + bnc;
        if(isbf){
          const short4v* src = (const short4v*)((const bf16*)Bw + bb);
          #pragma unroll
          for(int c=0;c<4;c++) *(short4v*)&tmp[c*4] = src[c];
        } else {
          const f32x4* src = (const f32x4*)((const float*)Bw + bb);
          #pragma unroll
          for(int c=0;c<4;c++){
            f32x4 f = src[c];
            #pragma unroll
            for(int i=0;i<4;i++) tmp[c*4+i] = f2bs(f[i]);
          }
        }
      } else {
        #pragma unroll
        for(int i=0;i<16;i++) tmp[i] = 0;
      }
      #pragma unroll
      for(int i=0;i<8;i++){ rB0v[i]=tmp[i]; rB1v[i]=tmp[8+i]; }
    }
  };
  auto writeAB = [&](){
    *(short8v*)&As[srow*ASTRIDE + ((kb0^keya)<<3)]     = rA0;
    *(short8v*)&As[srow*ASTRIDE + (((kb0+1)^keya)<<3)] = rA1;
    #pragma unroll
    for(int i=0;i<8;i++) Bs[(bnc+i)*ASTRIDE + bcol]   = rB0v[i];
    #pragma unroll
    for(int i=0;i<8;i++) Bs[(bnc+8+i)*ASTRIDE + bcol] = rB1v[i];
  };

  f32x4 acc[2][8] = {};
  int KT = (K+31)>>5;

  loadAB(0); writeAB();
  __syncthreads();
  for(int kt=0; kt<KT; ++kt){
    bool more = (kt+1 < KT);
    if(more) loadAB(kt+1);
    short8v a[2], b[8];
    #pragma unroll
    for(int fi=0;fi<2;fi++)
      a[fi] = *(const short8v*)&As[(w*32+fi*16+lr)*ASTRIDE + ((lg^((w*2+fi)&3))<<3)];
    #pragma unroll
    for(int fj=0;fj<8;fj++)
      b[fj] = *(const short8v*)&Bs[(fj*16+lr)*ASTRIDE + ((lg^(fj&3))<<3)];   // key=(col>>4)&3=fj&3 matches write
    #pragma unroll
    for(int fi=0;fi<2;fi++)
      #pragma unroll
      for(int fj=0;fj<8;fj++)
        acc[fi][fj] = mfma16(a[fi], b[fj], acc[fi][fj]);
    __syncthreads();
    if(more){ writeAB(); __syncthreads(); }
  }

  #pragma unroll
  for(int fi=0;fi<2;fi++){
    #pragma unroll
    for(int r=0;r<4;r++){
      int rl = m0 + w*32 + fi*16 + lg*4 + r;
      if(rl >= M) continue;
      if(exm){
        int orow = list[e*NT_ + rl];
        if(orow<0||orow>=2*NT_) continue;
        #pragma unroll
        for(int fj=0;fj<8;fj++){
          int gcol = n0 + fj*16 + lr;
          OutE[(size_t)orow*N + gcol] = f2b(acc[fi][fj][r]);
        }
      } else {
        #pragma unroll
        for(int fj=0;fj<8;fj++){
          int gcol = n0 + fj*16 + lr;
          size_t o = (size_t)rl*N + gcol;
          OutS[o] = OutS[o] + acc[fi][fj][r];
        }
      }
    }
  }
}

#define TST 72

// K/V register-prefetch (r25 winner) + XCD-aware block remap (r26 winner).
__global__ __launch_bounds__(256) void k_attn(const bf16* __restrict__ Q, const bf16* __restrict__ Kg,
                                              const bf16* __restrict__ V, bf16* __restrict__ Out){
  int L = blockIdx.x;
  int xcd = L & 7;
  int j = L >> 3;            // 0..127
  int b = xcd >> 2;          // 0..1
  int kvh = xcd & 3;         // 0..3
  int h = kvh*4 + (j & 3);   // h>>2 == kvh
  int qt_ = (S_/64 - 1) - (j >> 2);
  const bf16* qb = Q + (size_t)b*S_*D_ + h*HD_;
  const bf16* kb = Kg + (size_t)b*S_*256 + kvh*HD_;
  const bf16* vb = V  + (size_t)b*S_*256 + kvh*HD_;
  __shared__ short Qs[64*TST];
  __shared__ short Ks[64*TST];
  __shared__ short Vt[64*TST];
  __shared__ short Ps[4][16*TST];
  int tid = threadIdx.x;
  int w = tid>>6, l = tid&63, lr = l&15, lg = l>>4;
  int sr = tid>>2, sc0 = (tid&3)*16;
  int vc = (((sr>>3)^(tid&3))<<3) + (sr&7);

  {
    const short8v* src = (const short8v*)(qb + (size_t)(qt_*64 + sr)*D_ + sc0);
    *(short8v*)&Qs[sr*TST + sc0]     = src[0];
    *(short8v*)&Qs[sr*TST + sc0 + 8] = src[1];
  }
  __syncthreads();
  short8v aQ0 = *(const short8v*)&Qs[(w*16+lr)*TST + lg*8];
  short8v aQ1 = *(const short8v*)&Qs[(w*16+lr)*TST + lg*8 + 32];

  short8v rK0, rK1, rV0, rV1;
  auto loadKV = [&](int kt){
    const short8v* ksrc = (const short8v*)(kb + (size_t)(kt*64 + sr)*256 + sc0);
    rK0 = ksrc[0]; rK1 = ksrc[1];
    const short8v* vsrc = (const short8v*)(vb + (size_t)(kt*64 + sr)*256 + sc0);
    rV0 = vsrc[0]; rV1 = vsrc[1];
  };
  auto writeKV = [&](){
    *(short8v*)&Ks[sr*TST + sc0]     = rK0;
    *(short8v*)&Ks[sr*TST + sc0 + 8] = rK1;
    #pragma unroll
    for(int i=0;i<8;i++){
      Vt[(sc0+i)*TST + vc]   = rV0[i];
      Vt[(sc0+8+i)*TST + vc] = rV1[i];
    }
  };

  float mreg[4], lreg[4];
  f32x4 accO[4] = {};
  #pragma unroll
  for(int r=0;r<4;r++){ mreg[r] = NEGBIG; lreg[r] = 0.f; }

  loadKV(0); writeKV();
  __syncthreads();
  for(int kt=0; kt<=qt_; ++kt){
    bool more = (kt < qt_);
    if(more) loadKV(kt+1);        // global latency hides under compute below
    f32x4 s[4];
    #pragma unroll
    for(int fj=0; fj<4; fj++){
      short8v b0 = *(const short8v*)&Ks[(fj*16+lr)*TST + lg*8];
      short8v b1 = *(const short8v*)&Ks[(fj*16+lr)*TST + lg*8 + 32];
      f32x4 z = {};
      z = mfma16(aQ0, b0, z);
      z = mfma16(aQ1, b1, z);
      s[fj] = z;
    }
    #pragma unroll
    for(int fj=0; fj<4; fj++)
      #pragma unroll
      for(int r=0;r<4;r++){
        float v = s[fj][r]*0.125f;
        if(kt==qt_ && (fj*16+lr) > (w*16+lg*4+r)) v = NEGBIG;
        s[fj][r] = v;
      }
    float p[4][4], sc[4];
    #pragma unroll
    for(int r=0;r<4;r++){
      float mx = fmaxf(fmaxf(s[0][r],s[1][r]), fmaxf(s[2][r],s[3][r]));
      mx = fmaxf(mx, __shfl_xor(mx,1,64));
      mx = fmaxf(mx, __shfl_xor(mx,2,64));
      mx = fmaxf(mx, __shfl_xor(mx,4,64));
      mx = fmaxf(mx, __shfl_xor(mx,8,64));
      float mn = fmaxf(mreg[r], mx);
      sc[r] = __expf(mreg[r]-mn);
      float ps = 0.f;
      #pragma unroll
      for(int fj=0;fj<4;fj++){ float pv = __expf(s[fj][r]-mn); p[fj][r] = pv; ps += pv; }
      ps += __shfl_xor(ps,1,64); ps += __shfl_xor(ps,2,64);
      ps += __shfl_xor(ps,4,64); ps += __shfl_xor(ps,8,64);
      lreg[r] = lreg[r]*sc[r] + ps;
      mreg[r] = mn;
    }
    #pragma unroll
    for(int fj=0;fj<4;fj++)
      #pragma unroll
      for(int r=0;r<4;r++)
        accO[fj][r] *= sc[r];
    #pragma unroll
    for(int fj=0;fj<4;fj++)
      #pragma unroll
      for(int r=0;r<4;r++)
        Ps[w][(lg*4+r)*TST + fj*16+lr] = f2bs(p[fj][r]);
    short8v a0 = *(const short8v*)&Ps[w][lr*TST + lg*8];
    short8v a1 = *(const short8v*)&Ps[w][lr*TST + lg*8 + 32];
    #pragma unroll
    for(int fj=0;fj<4;fj++){
      int row = fj*16+lr;
      short8v b0 = *(const short8v*)&Vt[row*TST + ((lg^fj)<<3)];
      short8v b1 = *(const short8v*)&Vt[row*TST + (((lg^fj)+4)<<3)];
      accO[fj] = mfma16(a0, b0, accO[fj]);
      accO[fj] = mfma16(a1, b1, accO[fj]);
    }
    __syncthreads();                 // all reads of Ks/Vt done
    if(more){ writeKV(); __syncthreads(); }   // publish tile kt+1
  }
  #pragma unroll
  for(int r=0;r<4;r++){
    int qr = qt_*64 + w*16 + lg*4 + r;
    float inv = (lreg[r] > 0.f) ? 1.f/lreg[r] : 0.f;
    #pragma unroll
    for(int fj=0;fj<4;fj++)
      Out[((size_t)(b*S_+qr))*D_ + h*HD_ + fj*16+lr] = f2b(accO[fj][r]*inv);
  }
}

__global__ __launch_bounds__(64) void k_router(const float* __restrict__ X, const void* __restrict__ W,
                                               float* __restrict__ probs, float* __restrict__ p01,
                                               int* __restrict__ idx0buf, int* __restrict__ list,
                                               int* __restrict__ cnt, const int* __restrict__ flag){
  int isbf = flag[0];
  int t = blockIdx.x; int lane = threadIdx.x;
  float pe[8] = {};
  if(isbf){
    const bf16* Wb = (const bf16*)W;
    for(int d = lane; d < D_; d += 64){
      float xv = X[(size_t)t*D_ + d];
      #pragma unroll
      for(int e=0;e<8;e++) pe[e] += xv*b2f(Wb[(size_t)d*E_+e]);
    }
  } else {
    const float* Wf = (const float*)W;
    for(int d = lane; d < D_; d += 64){
      float xv = X[(size_t)t*D_ + d];
      #pragma unroll
      for(int e=0;e<8;e++) pe[e] += xv*Wf[(size_t)d*E_+e];
    }
  }
  for(int msk=1;msk<64;msk<<=1)
    #pragma unroll
    for(int e=0;e<8;e++) pe[e] += __shfl_xor(pe[e], msk, 64);
  if(lane == 0){
    float mx = pe[0];
    #pragma unroll
    for(int e=1;e<8;e++) mx = fmaxf(mx, pe[e]);
    float pr[8], sum = 0.f;
    #pragma unroll
    for(int e=0;e<8;e++){ pr[e] = __expf(pe[e]-mx); sum += pr[e]; }
    #pragma unroll
    for(int e=0;e<8;e++){ pr[e] /= sum; probs[t*8+e] = pr[e]; }
    int i0 = 0;
    #pragma unroll
    for(int e=1;e<8;e++) if(pe[e] > pe[i0]) i0 = e;
    int i1 = -1;
    #pragma unroll
    for(int e=0;e<8;e++){ if(e==i0) continue; if(i1<0 || pe[e] > pe[i1]) i1 = e; }
    p01[t*2]   = pr[i0];
    p01[t*2+1] = pr[i1];
    idx0buf[t] = i0;
    int pos = atomicAdd(&cnt[i0], 1);
    if(pos >= 0 && pos < NT_) list[i0*NT_ + pos] = t*2;
    pos     = atomicAdd(&cnt[i1], 1);
    if(pos >= 0 && pos < NT_) list[i1*NT_ + pos] = t*2 + 1;
  }
}

__global__ __launch_bounds__(256) void k_stats(const float* __restrict__ probs, const int* __restrict__ idx0buf,
                                               float* __restrict__ cnt0f, float* __restrict__ psum){
  int e = blockIdx.x; int tid = threadIdx.x;
  float sp = 0.f, sc = 0.f;
  for(int n = tid; n < NT_; n += 256){ sp += probs[n*8+e]; sc += (idx0buf[n]==e) ? 1.f : 0.f; }
  __shared__ float r1[256], r2[256];
  r1[tid] = sp; r2[tid] = sc; __syncthreads();
  for(int st=128; st>0; st>>=1){ if(tid<st){ r1[tid]+=r1[tid+st]; r2[tid]+=r2[tid+st]; } __syncthreads(); }
  if(tid==0){ psum[e] = r1[0]; cnt0f[e] = r2[0]; }
}

__global__ void k_finish(const float* __restrict__ cnt0f, const float* __restrict__ psum,
                         const int* __restrict__ cnt, int* __restrict__ offs,
                         bf16* __restrict__ auxb, float* __restrict__ auxf, const int* __restrict__ flag){
  if(threadIdx.x==0 && blockIdx.x==0){
    int o = 0;
    for(int e=0;e<8;e++){ offs[e] = o; int c = cnt[e]; if(c < 0) c = 0; if(c > NT_) c = NT_; o += c; }
    float aux = 0.f;
    for(int e=0;e<8;e++) aux += (cnt0f[e]*(1.f/(float)NT_))*(psum[e]*(1.f/(float)NT_));
    float v = aux*0.01f*8.f;
    if(flag[0]) auxb[0] = f2b(v); else auxf[0] = v;
  }
}

__global__ __launch_bounds__(256) void k_combine(const float* __restrict__ hbuf, const bf16* __restrict__ eosl,
                                                 const float* __restrict__ p01,
                                                 bf16* __restrict__ outb, float* __restrict__ outf,
                                                 const int* __restrict__ flag){
  int t = blockIdx.x; int tid = threadIdx.x;
  int isbf = flag[0];
  float p0 = p01[t*2], p1 = p01[t*2+1];
  #pragma unroll
  for(int i=0;i<4;i++){
    int d = tid + i*256;
    float v = hbuf[(size_t)t*D_ + d]
            + p0*b2f(eosl[((size_t)(t*2))*D_ + d])
            + p1*b2f(eosl[((size_t)(t*2+1))*D_ + d]);
    size_t o = (size_t)t*D_ + d;
    if(isbf) outb[o] = f2b(v); else outf[o] = v;
  }
}

// ---------------- workspace (bytes), peak ~63.3 MB ----------------
static const size_t O_HBUF = 0;
static const size_t O_XNB  = 16777216;
static const size_t O_QLIN = 25165824;
static const size_t O_KLIN = 33554432;
static const size_t O_VLIN = 35651584;
static const size_t O_AOUT = 37748736;
static const size_t O_XN2B = 16777216;
static const size_t O_XN2F = 25165824;
static const size_t O_HEXP = 46137344;
static const size_t O_SHH  = 57344000;
static const size_t O_EOSL = 16777216;
static const size_t O_PROBS= 62947328;
static const size_t O_P01  = 63078400;
static const size_t O_IDX0 = 63111168;
static const size_t O_LIST = 63127552;
static const size_t O_CNT  = 63258624;
static const size_t O_CNT0 = 63258656;
static const size_t O_PSUM = 63258688;
static const size_t O_OFFS = 63258720;
static const size_t O_FLAG = 63258752;

extern "C" void kernel_launch(void* const* d_in, const int* in_sizes, int n_in,
                              void* d_out, int out_size, void* d_ws, size_t ws_size,
                              hipStream_t stream){
  (void)in_sizes; (void)n_in; (void)out_size; (void)ws_size;
  char* ws = (char*)d_ws;
  float* hbuf = (float*)(ws + O_HBUF);
  bf16* xnb   = (bf16*)(ws + O_XNB);
  bf16* qlin  = (bf16*)(ws + O_QLIN);
  bf16* klin  = (bf16*)(ws + O_KLIN);
  bf16* vlin  = (bf16*)(ws + O_VLIN);
  bf16* aout  = (bf16*)(ws + O_AOUT);
  bf16* xn2b  = (bf16*)(ws + O_XN2B);
  float* xn2f = (float*)(ws + O_XN2F);
  bf16* hexp  = (bf16*)(ws + O_HEXP);
  bf16* shh   = (bf16*)(ws + O_SHH);
  bf16* eosl  = (bf16*)(ws + O_EOSL);
  float* probs=(float*)(ws + O_PROBS);
  float* p01 = (float*)(ws + O_P01);
  int*  idx0 = (int*)(ws + O_IDX0);
  int*  list = (int*)(ws + O_LIST);
  int*  cnt  = (int*)(ws + O_CNT);
  float* cnt0f=(float*)(ws + O_CNT0);
  float* psum= (float*)(ws + O_PSUM);
  int*  offs = (int*)(ws + O_OFFS);
  int*  flg  = (int*)(ws + O_FLAG);

  bf16* outb = (bf16*)d_out;
  float* outf = (float*)d_out;
  bf16* auxb = outb + (size_t)NT_*D_;
  float* auxf = outf + (size_t)NT_*D_;

  k_detect<<<1, 64, 0, stream>>>((const uint32_t*)d_in[14], flg, cnt);

  // ---- attention block ----
  k_rms<<<NT_, 256, 0, stream>>>(d_in[0], d_in[14], xnb, nullptr, flg, 1);

  // merged QKV with fused RoPE, XCD-chunked 1D grid
  k_qkv<<<dim3(768), 256, 0, stream>>>(xnb, d_in[3], d_in[4], d_in[5], qlin, klin, vlin,
                                       d_in[1], d_in[2], flg);

  // XCD-remapped 1D grid: 1024 blocks, (b,kvh) = L&7 -> per-XCD KV locality
  k_attn<<<dim3(S_/64 * H_ * B_), 256, 0, stream>>>(qlin, klin, vlin, aout);

  k_mgemm<0,1><<<dim3(16,32), 256, 0, stream>>>(aout, d_in[6], hbuf, d_in[0], NT_, D_, D_, D_, nullptr, nullptr, nullptr, flg);

  // ---- MoE block ----
  k_rms<<<NT_, 256, 0, stream>>>(hbuf, d_in[15], xn2b, xn2f, flg, 0);

  k_router<<<NT_, 64, 0, stream>>>(xn2f, d_in[7], probs, p01, idx0, list, cnt, flg);
  k_stats<<<E_, 256, 0, stream>>>(probs, idx0, cnt0f, psum);
  k_finish<<<1, 64, 0, stream>>>(cnt0f, psum, cnt, offs, auxb, auxf, flg);

  // merged FFN1: expert tiles (y<352, e-affine) + shared tiles (y>=352, XCD-chunked)
  k_ffn1m<<<dim3(E_, 352+44), 256, 0, stream>>>(xn2b, d_in[8], d_in[10], d_in[11], d_in[13],
                                                hexp, shh, cnt, offs, list, flg);

  // merged FFN2 (BN=128, single-buffer): expert tiles (y<256) + shared tiles (y>=256, XCD-chunked)
  k_ffn2m<<<dim3(E_, 256+32), 256, 0, stream>>>(hexp, shh, d_in[9], d_in[12],
                                                eosl, hbuf, cnt, offs, list, flg);

  k_combine<<<NT_, 256, 0, stream>>>(hbuf, eosl, p01, outb, outf, flg);
}